// Round 2
// baseline (1914.141 us; speedup 1.0000x reference)
//
#include <hip/hip_runtime.h>
#include <hip/hip_bf16.h>
#include <hip/hip_fp8.h>

#define NU_ 100000
#define NT_ 200000
#define NE_ 1000000
#define HD  64
#define NL  3

// hist/dinv region offsets (node-keyed arrays)
#define OFF0 0                   // u2u dst (NU)  [selfloop]
#define OFF1 (NU_)               // t2t dst (NT)  [selfloop]
#define OFF2 (NU_ + NT_)         // u2t dst (NT)
#define OFF3 (NU_ + 2 * NT_)     // t2u dst (NU)
#define OFF4 (2 * NU_ + 2 * NT_) // u2t src (NU)
#define OFF5 (3 * NU_ + 2 * NT_) // t2u src (NT)
#define HTOT (3 * NU_ + 3 * NT_) // 900k
#define RPT2 (NU_ + NT_)         // merged rp/fill size (300k)

#define NXCD 8

// merged scan partition (256/block)
#define NBU 391
#define NBT 782
#define NBTOT2 (NBU + NBT)

// fused grids
#define HB4 5860           // ceil(6M/1024) hist blocks (4 edges/thread)
#define EU  4096           // embed user blocks
#define ET  8192           // embed txn blocks
#define GU  4096           // gemm_dual user blocks
#define GT  8192           // gemm_dual txn blocks
#define GBU 25000          // ceil(NU/4) gather blocks (user)
#define GBT 50000          // ceil(NT/4) gather blocks (txn)

typedef float floatx2 __attribute__((ext_vector_type(2)));

// ---------------- fp8 helpers ----------------
__device__ __forceinline__ unsigned char enc_fp8(float v) {
    return (unsigned char)__hip_cvt_float_to_fp8(v, __HIP_SATFINITE, __HIP_E4M3);
}

__device__ __forceinline__ float dec1_fp8(unsigned int u) {
    int e = (u >> 3) & 15;
    int m = u & 7;
    int mant = m | (e ? 8 : 0);
    if (u & 0x80) mant = -mant;
    int ex = (e ? e : 1) - 10;
    return (float)mant * __uint_as_float((unsigned int)(ex + 127) << 23);
}

__device__ __forceinline__ void dec4_fp8(unsigned int u, float* f) {
#if __has_builtin(__builtin_amdgcn_cvt_pk_f32_fp8)
    floatx2 lo = __builtin_amdgcn_cvt_pk_f32_fp8((int)u, false);
    floatx2 hi = __builtin_amdgcn_cvt_pk_f32_fp8((int)u, true);
    f[0] = lo.x; f[1] = lo.y; f[2] = hi.x; f[3] = hi.y;
#else
    f[0] = dec1_fp8(u & 0xff);
    f[1] = dec1_fp8((u >> 8) & 0xff);
    f[2] = dec1_fp8((u >> 16) & 0xff);
    f[3] = dec1_fp8((u >> 24) & 0xff);
#endif
}

// ---------------- xcd id ----------------
__device__ __forceinline__ int xcc_id() {
    unsigned int x;
    asm volatile("s_getreg_b32 %0, hwreg(HW_REG_XCC_ID)" : "=s"(x));
    return (int)(x & (NXCD - 1));
}

// ---------------- dtype detection ----------------
__global__ void detect_dtype(const unsigned short* __restrict__ x, int* __restrict__ flag, int n) {
    __shared__ int s_big;
    if (threadIdx.x == 0) s_big = 0;
    __syncthreads();
    int big = 0;
    for (int i = threadIdx.x; i < n; i += blockDim.x) {
        float v = __uint_as_float(((unsigned int)x[i]) << 16);
        if (!(fabsf(v) < 1.0e4f)) big = 1;
    }
    if (big) atomicAdd(&s_big, 1);
    __syncthreads();
    if (threadIdx.x == 0) flag[0] = (s_big > 0) ? 0 : 1;
}

// ---------------- fused weight conversion (+ gsum zero) ----------------
struct Ptr10 { const void* p[10]; };

__global__ void cvt_weights(Ptr10 src, float* __restrict__ dst, float* __restrict__ gsum,
                            const int* __restrict__ flag) {
    const int c[11] = {0, 2048, 2112, 6208, 6272, 55424, 56192, 60288, 60352, 60416, 60417};
    int i = blockIdx.x * blockDim.x + threadIdx.x;
    if (i < 64) gsum[i] = 0.f;
    if (i >= 60417) return;
    int r = 0;
#pragma unroll
    for (int k = 1; k < 10; ++k)
        if (i >= c[k]) r = k;
    int e = i - c[r];
    if (flag[0]) {
        unsigned short u = ((const unsigned short*)src.p[r])[e];
        dst[i] = __uint_as_float(((unsigned int)u) << 16);
    } else {
        dst[i] = ((const float*)src.p[r])[e];
    }
}

// ---------------- device bodies ----------------
// per-XCD replicated histogram: workgroup-scope atomics stay resident in the
// owning XCD's L2 (replica = 3.6 MB < 4 MB L2) instead of RMW at memory side.
__device__ __forceinline__ void hist_dev(int bid, const int* __restrict__ a0,
                                         const int* __restrict__ a1, const int* __restrict__ a2,
                                         const int* __restrict__ a3, const int* __restrict__ a4,
                                         const int* __restrict__ a5, int* __restrict__ hist8) {
    int* h = hist8 + (size_t)xcc_id() * HTOT;
    const int base0 = bid * 1024 + threadIdx.x;
#pragma unroll
    for (int i = 0; i < 4; ++i) {
        int g = base0 + i * 256;
        if (g < 6 * NE_) {
            int r = g / NE_;
            int e = g - r * NE_;
            const int* a;
            int base;
            switch (r) {
                case 0: a = a0; base = OFF0; break;
                case 1: a = a1; base = OFF1; break;
                case 2: a = a2; base = OFF2; break;
                case 3: a = a3; base = OFF3; break;
                case 4: a = a4; base = OFF4; break;
                default: a = a5; base = OFF5; break;
            }
            __hip_atomic_fetch_add(&h[base + a[e]], 1, __ATOMIC_RELAXED,
                                   __HIP_MEMORY_SCOPE_WORKGROUP);
        }
    }
}

template <int K>
__device__ __forceinline__ void embed_dev(int bid, int nblk, const void* __restrict__ x,
                                          const float* __restrict__ W,
                                          const float* __restrict__ bias,
                                          float* __restrict__ out, int N,
                                          const int* __restrict__ flag) {
    const int lane = threadIdx.x & 63;
    float w[K];
#pragma unroll
    for (int k = 0; k < K; ++k) w[k] = W[k * HD + lane];
    const float b = bias[lane];
    const bool isb = flag[0] != 0;
    const int wid = (bid << 2) + (threadIdx.x >> 6);
    const int stride = nblk << 2;
    const int le = lane & (K - 1);
    if (isb) {
        const unsigned short* xb = (const unsigned short*)x;
        for (int r = wid; r < N; r += stride) {
            float hv = __uint_as_float(((unsigned int)xb[(size_t)r * K + le]) << 16);
            float acc = b;
#pragma unroll
            for (int k = 0; k < K; ++k) acc = fmaf(__shfl(hv, k), w[k], acc);
            out[(size_t)r * HD + lane] = acc;
        }
    } else {
        const float* xf = (const float*)x;
        for (int r = wid; r < N; r += stride) {
            float hv = xf[(size_t)r * K + le];
            float acc = b;
#pragma unroll
            for (int k = 0; k < K; ++k) acc = fmaf(__shfl(hv, k), w[k], acc);
            out[(size_t)r * HD + lane] = acc;
        }
    }
}

__device__ __forceinline__ void gemm_dual_dev(int bid, int nblk, const float* __restrict__ h,
                                              const float* __restrict__ WA,
                                              const float* __restrict__ WB,
                                              const float* __restrict__ scA,
                                              const float* __restrict__ scB,
                                              unsigned char* __restrict__ mA,
                                              unsigned char* __restrict__ mB, int N) {
    const int lane = threadIdx.x & 63;
    float wa[HD], wb[HD];
#pragma unroll
    for (int k = 0; k < HD; ++k) wa[k] = WA[k * HD + lane];
#pragma unroll
    for (int k = 0; k < HD; ++k) wb[k] = WB[k * HD + lane];
    const int wid = (bid << 2) + (threadIdx.x >> 6);
    const int stride = nblk << 2;
    for (int r = wid; r < N; r += stride) {
        const float hv = h[(size_t)r * HD + lane];
        float accA = 0.f, accB = 0.f;
#pragma unroll
        for (int k = 0; k < HD; ++k) {
            float hk = __shfl(hv, k);
            accA = fmaf(hk, wa[k], accA);
            accB = fmaf(hk, wb[k], accB);
        }
        mA[(size_t)r * HD + lane] = enc_fp8(accA * scA[r]);
        mB[(size_t)r * HD + lane] = enc_fp8(accB * scB[r]);
    }
}

// R6-proven gather body + packed int4 metadata {rp, cnt, dA, dB}.
__device__ __forceinline__ void gather_dev(int blk, const unsigned char* __restrict__ mA,
                                           const unsigned char* __restrict__ mB,
                                           const int4* __restrict__ meta,
                                           const int* __restrict__ col,
                                           const float* __restrict__ ba,
                                           const float* __restrict__ bb,
                                           float* __restrict__ out, int N) {
    const int lane = threadIdx.x & 63;
    const int grp = lane >> 3;
    const int sub = lane & 7;
    const int d = (blk << 2) + (threadIdx.x >> 6);
    if (d >= N) return;

    const int4 mt = meta[d];
    const int st = mt.x;
    const int cnt = mt.y;
    const float dA = __int_as_float(mt.z);
    const float dB = __int_as_float(mt.w);
    float acc[8] = {0.f, 0.f, 0.f, 0.f, 0.f, 0.f, 0.f, 0.f};

    const uint2 uself = *(const uint2*)(mA + ((size_t)d << 6) + (sub << 3));

    int done = 0;
    while (done < cnt) {
        int rem = cnt - done;
        if (rem > 64) rem = 64;
        int cw = (lane < rem) ? col[st + done + lane] : 0;
        const int nch = (rem + 7) >> 3;

        uint2 ub0, ub1, ub2, ub3;
        float sc0, sc1, sc2, sc3;

        auto issue = [&](int p, uint2& ub, float& sc) {
            int j = (p << 3) + grp;
            unsigned int c = (unsigned int)__shfl(cw, j);
            const unsigned char* base = (c >> 31) ? mB : mA;
            float sv = (c >> 31) ? dB : dA;
            unsigned int idx = c & 0x7fffffffu;
            sc = (j < rem) ? sv : 0.f;
            ub = *(const uint2*)(base + ((size_t)idx << 6) + (sub << 3));
        };
        auto consume = [&](uint2 u, float s) {
            float f[8];
            dec4_fp8(u.x, f);
            dec4_fp8(u.y, f + 4);
#pragma unroll
            for (int k = 0; k < 8; ++k) acc[k] = fmaf(f[k], s, acc[k]);
        };

        issue(0, ub0, sc0);
        if (nch > 1) issue(1, ub1, sc1);
        if (nch > 2) issue(2, ub2, sc2);
        if (nch > 3) issue(3, ub3, sc3);

        consume(ub0, sc0);
        if (nch > 4) issue(4, ub0, sc0);
        if (nch > 1) consume(ub1, sc1);
        if (nch > 5) issue(5, ub1, sc1);
        if (nch > 2) consume(ub2, sc2);
        if (nch > 6) issue(6, ub2, sc2);
        if (nch > 3) consume(ub3, sc3);
        if (nch > 7) issue(7, ub3, sc3);
        if (nch > 4) consume(ub0, sc0);
        if (nch > 5) consume(ub1, sc1);
        if (nch > 6) consume(ub2, sc2);
        if (nch > 7) consume(ub3, sc3);

        done += rem;
    }

    {
        float f[8];
        dec4_fp8(uself.x, f);
        dec4_fp8(uself.y, f + 4);
        const float s = (grp == 0) ? dA : 0.f;
#pragma unroll
        for (int k = 0; k < 8; ++k) acc[k] = fmaf(f[k], s, acc[k]);
    }

#pragma unroll
    for (int k = 0; k < 8; ++k) {
        acc[k] += __shfl_xor(acc[k], 8);
        acc[k] += __shfl_xor(acc[k], 16);
        acc[k] += __shfl_xor(acc[k], 32);
    }

    if (grp == 0) {
        const int col0 = sub << 3;
        float o[8];
#pragma unroll
        for (int k = 0; k < 8; ++k)
            o[k] = fmaxf(0.5f * (acc[k] + ba[col0 + k] + bb[col0 + k]), 0.f);
        float4 v0 = {o[0], o[1], o[2], o[3]};
        float4 v1 = {o[4], o[5], o[6], o[7]};
        *(float4*)(out + ((size_t)d << 6) + col0) = v0;
        *(float4*)(out + ((size_t)d << 6) + col0 + 4) = v1;
    }
}

// ---------------- fused kernels ----------------
__global__ __launch_bounds__(256) void fused_hist_embed(
    const int* __restrict__ a0, const int* __restrict__ a1, const int* __restrict__ a2,
    const int* __restrict__ a3, const int* __restrict__ a4, const int* __restrict__ a5,
    int* __restrict__ hist8, const void* __restrict__ x_user, const void* __restrict__ x_txn,
    const float* __restrict__ Wembu, const float* __restrict__ bembu,
    const float* __restrict__ Wembt, const float* __restrict__ bembt,
    float* __restrict__ hu, float* __restrict__ ht, const int* __restrict__ flag) {
    int b = blockIdx.x;
    if (b < HB4) {
        hist_dev(b, a0, a1, a2, a3, a4, a5, hist8);
    } else if (b < HB4 + EU) {
        embed_dev<32>(b - HB4, EU, x_user, Wembu, bembu, hu, NU_, flag);
    } else {
        embed_dev<64>(b - HB4 - EU, ET, x_txn, Wembt, bembt, ht, NT_, flag);
    }
}

// standalone CSR placement (R6-proven: 8 VGPR, high occupancy)
__global__ __launch_bounds__(256) void place4m(const int* __restrict__ e_u2u,
                                               const int* __restrict__ e_t2t,
                                               const int* __restrict__ e_u2t,
                                               const int* __restrict__ e_t2u,
                                               const int* __restrict__ rp, int* __restrict__ fill,
                                               int* __restrict__ colU, int* __restrict__ colT) {
    int gid = blockIdx.x * 256 + threadIdx.x;
    if (gid >= 4 * NE_) return;
    int r = gid / NE_;
    int e = gid - r * NE_;
    const int* ei;
    int rpo;
    unsigned int tag;
    int* cl;
    switch (r) {
        case 0: ei = e_u2u; rpo = 0;   tag = 0u;          cl = colU; break;
        case 1: ei = e_t2u; rpo = 0;   tag = 0x80000000u; cl = colU; break;
        case 2: ei = e_t2t; rpo = NU_; tag = 0u;          cl = colT; break;
        default: ei = e_u2t; rpo = NU_; tag = 0x80000000u; cl = colT; break;
    }
    int s = ei[e];
    int d = ei[e + NE_];
    int pos = rp[rpo + d] + atomicAdd(&fill[rpo + d], 1);
    cl[pos] = (int)((unsigned int)s | tag);
}

__global__ __launch_bounds__(256) void gemm_dual_both(
    const float* __restrict__ hu, const float* __restrict__ ht,
    const float* __restrict__ W0, const float* __restrict__ Wu2t,
    const float* __restrict__ Wt, const float* __restrict__ Wt2u,
    const float* __restrict__ dinv,
    unsigned char* __restrict__ m_uu, unsigned char* __restrict__ m_ut,
    unsigned char* __restrict__ m_tt, unsigned char* __restrict__ m_tu) {
    int b = blockIdx.x;
    if (b < GU) {
        gemm_dual_dev(b, GU, hu, W0, Wu2t, dinv + OFF0, dinv + OFF4, m_uu, m_ut, NU_);
    } else {
        gemm_dual_dev(b - GU, GT, ht, Wt, Wt2u, dinv + OFF1, dinv + OFF5, m_tt, m_tu, NT_);
    }
}

__global__ __launch_bounds__(256) void gather_both(
    const unsigned char* __restrict__ m_uu, const unsigned char* __restrict__ m_tu,
    const unsigned char* __restrict__ m_tt, const unsigned char* __restrict__ m_ut,
    const int4* __restrict__ meta,
    const int* __restrict__ colU, const int* __restrict__ colT,
    const float* __restrict__ bU0, const float* __restrict__ bU1,
    const float* __restrict__ bT0, const float* __restrict__ bT1,
    float* __restrict__ hu, float* __restrict__ ht) {
    int b = blockIdx.x;
    if (b < GBU) {
        gather_dev(b, m_uu, m_tu, meta, colU, bU0, bU1, hu, NU_);
    } else {
        gather_dev(b - GBU, m_tt, m_ut, meta + NU_, colT, bT0, bT1, ht, NT_);
    }
}

// ---------------- CSR scan kernels (dinv folded in; sums 8 hist replicas) ----------------
__global__ __launch_bounds__(256) void scan1m(const int* __restrict__ hist8,
                                              int* __restrict__ hist, int* __restrict__ rp,
                                              int* __restrict__ bsums, float* __restrict__ dinv) {
    int b = blockIdx.x, t = threadIdx.x;
    int r, lb, n, rpbase, oA, oB, oS;
    if (b < NBU) { r = 0; lb = b;       n = NU_; rpbase = 0;   oA = OFF0; oB = OFF3; oS = OFF4; }
    else         { r = 1; lb = b - NBU; n = NT_; rpbase = NU_; oA = OFF1; oB = OFF2; oS = OFF5; }
    int i = lb * 256 + t;
    int hA = 0, hB = 0;
    if (i < n) {
        int hS = 0;
#pragma unroll
        for (int x = 0; x < NXCD; ++x) {
            const int* hx = hist8 + (size_t)x * HTOT;
            hA += hx[oA + i];
            hB += hx[oB + i];
            hS += hx[oS + i];
        }
        hist[oA + i] = hA;                                             // summed, for scan3m
        hist[oB + i] = hB;
        hist[oS + i] = hS;
        dinv[oA + i] = rsqrtf((float)hA + 1.0f);                       // self-loop type
        dinv[oB + i] = (hB > 0) ? rsqrtf((float)hB) : 0.f;             // bipartite dst
    }
    int v = hA + hB;
    __shared__ int s[256];
    s[t] = v;
    __syncthreads();
    for (int off = 1; off < 256; off <<= 1) {
        int x = (t >= off) ? s[t - off] : 0;
        __syncthreads();
        s[t] += x;
        __syncthreads();
    }
    if (i < n) rp[rpbase + i] = s[t] - v;
    if (t == 255) bsums[r * 1024 + lb] = s[255];
}

__global__ __launch_bounds__(1024) void scan2m(int* __restrict__ bsums) {
    int r = blockIdx.x, t = threadIdx.x;
    const int nb = r ? NBT : NBU;
    int v = (t < nb) ? bsums[r * 1024 + t] : 0;
    __shared__ int s[1024];
    s[t] = v;
    __syncthreads();
    for (int off = 1; off < 1024; off <<= 1) {
        int x = (t >= off) ? s[t - off] : 0;
        __syncthreads();
        s[t] += x;
        __syncthreads();
    }
    if (t < nb) bsums[r * 1024 + t] = s[t] - v;
}

// scan3m: finalize rp, src dinv, and pack gather metadata {rp, cnt, dA, dB}
__global__ void scan3m(int* __restrict__ rp, const int* __restrict__ bsums,
                       const int* __restrict__ hist, float* __restrict__ dinv,
                       int4* __restrict__ meta) {
    int gid = blockIdx.x * blockDim.x + threadIdx.x;
    if (gid >= RPT2) return;
    int r = (gid < NU_) ? 0 : 1;
    int base = r ? NU_ : 0;
    int lb = (gid - base) >> 8;
    int rpf = rp[gid] + bsums[r * 1024 + lb];
    rp[gid] = rpf;
    // src dinv (for GEMM scaling)
    int si = r ? (OFF5 + gid - NU_) : (OFF4 + gid);
    int h = hist[si];
    dinv[si] = (h > 0) ? rsqrtf((float)h) : 0.f;
    // packed gather meta
    int oA = r ? (OFF1 + gid - NU_) : (OFF0 + gid);
    int oB = r ? (OFF2 + gid - NU_) : (OFF3 + gid);
    int hA = hist[oA];
    int hB = hist[oB];
    float dA = rsqrtf((float)hA + 1.0f);
    float dB = (hB > 0) ? rsqrtf((float)hB) : 0.f;
    int4 mt;
    mt.x = rpf;
    mt.y = hA + hB;
    mt.z = __float_as_int(dA);
    mt.w = __float_as_int(dB);
    meta[gid] = mt;
}

// ---------------- readout ----------------
__global__ __launch_bounds__(256) void colmean_both(const float* __restrict__ hu,
                                                    const float* __restrict__ ht,
                                                    float* __restrict__ gsum) {
    const bool isU = blockIdx.x < 512;
    const float* h = isU ? hu : ht;
    const int n = isU ? NU_ : NT_;
    const float scale = isU ? 0.5f / NU_ : 0.5f / NT_;
    const int blk = isU ? blockIdx.x : blockIdx.x - 512;
    const int lane = threadIdx.x & 63;
    const int w = threadIdx.x >> 6;
    float s = 0.f;
    for (int r = blk * 4 + w; r < n; r += 512 * 4)
        s += h[(size_t)r * HD + lane];
    __shared__ float red[256];
    red[threadIdx.x] = s;
    __syncthreads();
    if (threadIdx.x < 64) {
        float t = red[threadIdx.x] + red[64 + threadIdx.x] + red[128 + threadIdx.x] +
                  red[192 + threadIdx.x];
        atomicAdd(&gsum[lane], t * scale);
    }
}

__global__ void head(const float* __restrict__ g, const float* __restrict__ W1,
                     const float* __restrict__ b1, const float* __restrict__ W2,
                     const float* __restrict__ b2, const int* __restrict__ flag,
                     void* __restrict__ out) {
    const int c = threadIdx.x;
    float x = b1[c];
    for (int k = 0; k < HD; ++k) x = fmaf(g[k], W1[k * HD + c], x);
    x = fmaxf(x, 0.f);
    float t = x * W2[c];
    for (int off = 32; off; off >>= 1) t += __shfl_down(t, off);
    if (c == 0) {
        float z = t + b2[0];
        float s = 1.f / (1.f + expf(-z));
        if (flag[0]) *(__hip_bfloat16*)out = __float2bfloat16(s);
        else *(float*)out = s;
    }
}

extern "C" void kernel_launch(void* const* d_in, const int* in_sizes, int n_in,
                              void* d_out, int out_size, void* d_ws, size_t ws_size,
                              hipStream_t stream) {
    const void* x_user = d_in[0];
    const void* x_txn  = d_in[1];
    const int* ei_u2u = (const int*)d_in[2];
    const int* ei_t2t = (const int*)d_in[3];
    const int* ei_u2t = (const int*)d_in[4];
    const int* ei_t2u = (const int*)d_in[5];

    // ---- workspace layout ----
    float* ws = (float*)d_ws;
    float* hu = ws;                                   // NU*64 f32
    float* ht = hu + (size_t)NU_ * HD;                // NT*64 f32
    float* dinv = ht + (size_t)NT_ * HD;              // HTOT
    float* wts = dinv + HTOT;                         // 60432 (padded)
    float* gsum = wts + 60432;                        // 64
    unsigned char* m_uu = (unsigned char*)(gsum + 64);  // NU*64 fp8
    unsigned char* m_ut = m_uu + (size_t)NU_ * HD;
    unsigned char* m_tt = m_ut + (size_t)NU_ * HD;
    unsigned char* m_tu = m_tt + (size_t)NT_ * HD;
    int* hist = (int*)(m_tu + (size_t)NT_ * HD);      // HTOT (summed)
    int* fill = hist + HTOT;                          // RPT2
    int* rp   = fill + RPT2;                          // RPT2
    int* bsums = rp + RPT2;                           // 2048
    int* colU = bsums + 2048;                         // 2M
    int* colT = colU + 2 * NE_;                       // 2M
    int4* meta = (int4*)(colT + 2 * NE_);             // RPT2 (16B each)
    int* dflag = (int*)(meta + RPT2);                 // 1

    // 8 per-XCD hist replicas alias the fp8 message buffers (dead until layer 0
    // gemm, which runs after scan1m has consumed the replicas): 28.8 MB <= 38.4 MB
    int* hist8 = (int*)m_uu;

    // fp32 weight sub-pointers
    float* Wembu = wts;              // 2048
    float* bembu = Wembu + 2048;     // 64
    float* Wembt = bembu + 64;       // 4096
    float* bembt = Wembt + 4096;     // 64
    float* convWf = bembt + 64;      // 49152
    float* convbf = convWf + 49152;  // 768
    float* W1f = convbf + 768;       // 4096
    float* b1f = W1f + 4096;         // 64
    float* W2f = b1f + 64;           // 64
    float* b2f = W2f + 64;           // 1

    hipMemsetAsync(hist8, 0, (size_t)NXCD * HTOT * sizeof(int), stream);
    hipMemsetAsync(fill, 0, (size_t)RPT2 * sizeof(int), stream);

    detect_dtype<<<1, 256, 0, stream>>>((const unsigned short*)x_user, dflag, 2048);
    {
        Ptr10 p;
        for (int k = 0; k < 10; ++k) p.p[k] = d_in[6 + k];
        cvt_weights<<<(60417 + 255) / 256, 256, 0, stream>>>(p, wts, gsum, dflag);
    }

    // ---- fused: histograms (per-XCD L2-resident) + embedding GEMMs ----
    fused_hist_embed<<<HB4 + EU + ET, 256, 0, stream>>>(
        ei_u2u + NE_, ei_t2t + NE_, ei_u2t + NE_, ei_t2u + NE_, ei_u2t, ei_t2u, hist8,
        x_user, x_txn, Wembu, bembu, Wembt, bembt, hu, ht, dflag);

    scan1m<<<NBTOT2, 256, 0, stream>>>(hist8, hist, rp, bsums, dinv);
    scan2m<<<2, 1024, 0, stream>>>(bsums);
    scan3m<<<(RPT2 + 255) / 256, 256, 0, stream>>>(rp, bsums, hist, dinv, meta);

    // ---- standalone CSR placement (low-VGPR, high occupancy) ----
    place4m<<<(4 * NE_ + 255) / 256, 256, 0, stream>>>(ei_u2u, ei_t2t, ei_u2t, ei_t2u,
                                                       rp, fill, colU, colT);

    for (int l = 0; l < NL; ++l) {
        const float* W0   = convWf + ((size_t)l * 4 + 0) * HD * HD;
        const float* Wt   = convWf + ((size_t)l * 4 + 1) * HD * HD;
        const float* Wu2t = convWf + ((size_t)l * 4 + 2) * HD * HD;
        const float* Wt2u = convWf + ((size_t)l * 4 + 3) * HD * HD;
        const float* B0   = convbf + ((size_t)l * 4 + 0) * HD;
        const float* Bt   = convbf + ((size_t)l * 4 + 1) * HD;
        const float* Bu2t = convbf + ((size_t)l * 4 + 2) * HD;
        const float* Bt2u = convbf + ((size_t)l * 4 + 3) * HD;

        gemm_dual_both<<<GU + GT, 256, 0, stream>>>(hu, ht, W0, Wu2t, Wt, Wt2u, dinv,
                                                    m_uu, m_ut, m_tt, m_tu);

        gather_both<<<GBU + GBT, 256, 0, stream>>>(m_uu, m_tu, m_tt, m_ut,
                                                   meta, colU, colT,
                                                   B0, Bt2u, Bt, Bu2t, hu, ht);
    }

    // ---- readout ----
    colmean_both<<<1024, 256, 0, stream>>>(hu, ht, gsum);
    head<<<1, 64, 0, stream>>>(gsum, W1f, b1f, W2f, b2f, dflag, d_out);
}

// Round 3
// 1604.235 us; speedup vs baseline: 1.1932x; 1.1932x over previous
//
#include <hip/hip_runtime.h>
#include <hip/hip_bf16.h>
#include <hip/hip_fp8.h>

#define NU_ 100000
#define NT_ 200000
#define NE_ 1000000
#define HD  64
#define NL  3

// hist/dinv region offsets (node-keyed arrays)
#define OFF0 0                   // u2u dst (NU)  [selfloop]
#define OFF1 (NU_)               // t2t dst (NT)  [selfloop]
#define OFF2 (NU_ + NT_)         // u2t dst (NT)
#define OFF3 (NU_ + 2 * NT_)     // t2u dst (NU)
#define OFF4 (2 * NU_ + 2 * NT_) // u2t src (NU)
#define OFF5 (3 * NU_ + 2 * NT_) // t2u src (NT)
#define HTOT (3 * NU_ + 3 * NT_) // 900k
#define RPT2 (NU_ + NT_)         // merged rp size (300k)

// merged scan partition (256/block)
#define NBU 391
#define NBT 782
#define NBTOT2 (NBU + NBT)

// bucket partition (no-far-atomic CSR build)
#define PB1  512           // partition blocks (256 threads each); p1/p2 must match
#define BKP  2048          // node-keys per bucket (key >> 11)
#define NBKC 147           // CSR buckets  (300k / 2048)
#define NBKS 147           // src buckets  (300k / 2048)
#define NBKT (NBKC + NBKS) // 294

// fused grids
#define EU  4096           // embed user blocks
#define ET  8192           // embed txn blocks
#define GU  4096           // gemm_dual user blocks
#define GT  8192           // gemm_dual txn blocks
#define GBU 25000          // ceil(NU/4) gather blocks (user)
#define GBT 50000          // ceil(NT/4) gather blocks (txn)

typedef float floatx2 __attribute__((ext_vector_type(2)));

// ---------------- fp8 helpers ----------------
__device__ __forceinline__ unsigned char enc_fp8(float v) {
    return (unsigned char)__hip_cvt_float_to_fp8(v, __HIP_SATFINITE, __HIP_E4M3);
}

__device__ __forceinline__ float dec1_fp8(unsigned int u) {
    int e = (u >> 3) & 15;
    int m = u & 7;
    int mant = m | (e ? 8 : 0);
    if (u & 0x80) mant = -mant;
    int ex = (e ? e : 1) - 10;
    return (float)mant * __uint_as_float((unsigned int)(ex + 127) << 23);
}

__device__ __forceinline__ void dec4_fp8(unsigned int u, float* f) {
#if __has_builtin(__builtin_amdgcn_cvt_pk_f32_fp8)
    floatx2 lo = __builtin_amdgcn_cvt_pk_f32_fp8((int)u, false);
    floatx2 hi = __builtin_amdgcn_cvt_pk_f32_fp8((int)u, true);
    f[0] = lo.x; f[1] = lo.y; f[2] = hi.x; f[3] = hi.y;
#else
    f[0] = dec1_fp8(u & 0xff);
    f[1] = dec1_fp8((u >> 8) & 0xff);
    f[2] = dec1_fp8((u >> 16) & 0xff);
    f[3] = dec1_fp8((u >> 24) & 0xff);
#endif
}

// ---------------- dtype detection ----------------
__global__ void detect_dtype(const unsigned short* __restrict__ x, int* __restrict__ flag, int n) {
    __shared__ int s_big;
    if (threadIdx.x == 0) s_big = 0;
    __syncthreads();
    int big = 0;
    for (int i = threadIdx.x; i < n; i += blockDim.x) {
        float v = __uint_as_float(((unsigned int)x[i]) << 16);
        if (!(fabsf(v) < 1.0e4f)) big = 1;
    }
    if (big) atomicAdd(&s_big, 1);
    __syncthreads();
    if (threadIdx.x == 0) flag[0] = (s_big > 0) ? 0 : 1;
}

// ---------------- fused weight conversion (+ gsum zero) ----------------
struct Ptr10 { const void* p[10]; };

__global__ void cvt_weights(Ptr10 src, float* __restrict__ dst, float* __restrict__ gsum,
                            const int* __restrict__ flag) {
    const int c[11] = {0, 2048, 2112, 6208, 6272, 55424, 56192, 60288, 60352, 60416, 60417};
    int i = blockIdx.x * blockDim.x + threadIdx.x;
    if (i < 64) gsum[i] = 0.f;
    if (i >= 60417) return;
    int r = 0;
#pragma unroll
    for (int k = 1; k < 10; ++k)
        if (i >= c[k]) r = k;
    int e = i - c[r];
    if (flag[0]) {
        unsigned short u = ((const unsigned short*)src.p[r])[e];
        dst[i] = __uint_as_float(((unsigned int)u) << 16);
    } else {
        dst[i] = ((const float*)src.p[r])[e];
    }
}

// ---------------- partition pass 1: per-block bucket counts (LDS) ----------------
// 6M items: [0,4M) CSR edges keyed by merged dst node m in [0,300k);
//           [4M,6M) src-degree items keyed by m2 in [0,300k) (bucket NBKC+).
// Far atomics: only the 294-per-block flush (NBKT*PB1 = 150k total).
__device__ __forceinline__ void p1_dev(int bid, const int* __restrict__ eu2u,
                                       const int* __restrict__ et2t,
                                       const int* __restrict__ eu2t,
                                       const int* __restrict__ et2u,
                                       int* __restrict__ gcnt, int* __restrict__ bofs) {
    __shared__ int cnt[NBKT];
    for (int j = threadIdx.x; j < NBKT; j += 256) cnt[j] = 0;
    __syncthreads();
    for (int i = bid * 256 + threadIdx.x; i < 6 * NE_; i += PB1 * 256) {
        int b;
        if (i < 4 * NE_) {
            int m;
            if (i < NE_)          m = eu2u[i + NE_];
            else if (i < 2 * NE_) m = NU_ + et2t[i];          // (i-NE_) + NE_
            else if (i < 3 * NE_) m = NU_ + eu2t[i - NE_];    // (i-2NE_) + NE_
            else                  m = et2u[i - 2 * NE_];      // (i-3NE_) + NE_
            b = m >> 11;
        } else {
            int m2 = (i < 5 * NE_) ? eu2t[i - 4 * NE_] : (NU_ + et2u[i - 5 * NE_]);
            b = NBKC + (m2 >> 11);
        }
        atomicAdd(&cnt[b], 1);
    }
    __syncthreads();
    for (int j = threadIdx.x; j < NBKT; j += 256) {
        bofs[bid * NBKT + j] = atomicAdd(&gcnt[j], cnt[j]);
    }
}

// ---------------- embed (shuffle-broadcast matvec) ----------------
template <int K>
__device__ __forceinline__ void embed_dev(int bid, int nblk, const void* __restrict__ x,
                                          const float* __restrict__ W,
                                          const float* __restrict__ bias,
                                          float* __restrict__ out, int N,
                                          const int* __restrict__ flag) {
    const int lane = threadIdx.x & 63;
    float w[K];
#pragma unroll
    for (int k = 0; k < K; ++k) w[k] = W[k * HD + lane];
    const float b = bias[lane];
    const bool isb = flag[0] != 0;
    const int wid = (bid << 2) + (threadIdx.x >> 6);
    const int stride = nblk << 2;
    const int le = lane & (K - 1);
    if (isb) {
        const unsigned short* xb = (const unsigned short*)x;
        for (int r = wid; r < N; r += stride) {
            float hv = __uint_as_float(((unsigned int)xb[(size_t)r * K + le]) << 16);
            float acc = b;
#pragma unroll
            for (int k = 0; k < K; ++k) acc = fmaf(__shfl(hv, k), w[k], acc);
            out[(size_t)r * HD + lane] = acc;
        }
    } else {
        const float* xf = (const float*)x;
        for (int r = wid; r < N; r += stride) {
            float hv = xf[(size_t)r * K + le];
            float acc = b;
#pragma unroll
            for (int k = 0; k < K; ++k) acc = fmaf(__shfl(hv, k), w[k], acc);
            out[(size_t)r * HD + lane] = acc;
        }
    }
}

__global__ __launch_bounds__(256) void fused_p1_embed(
    const int* __restrict__ eu2u, const int* __restrict__ et2t,
    const int* __restrict__ eu2t, const int* __restrict__ et2u,
    int* __restrict__ gcnt, int* __restrict__ bofs,
    const void* __restrict__ x_user, const void* __restrict__ x_txn,
    const float* __restrict__ Wembu, const float* __restrict__ bembu,
    const float* __restrict__ Wembt, const float* __restrict__ bembt,
    float* __restrict__ hu, float* __restrict__ ht, const int* __restrict__ flag) {
    int b = blockIdx.x;
    if (b < PB1) {
        p1_dev(b, eu2u, et2t, eu2t, et2u, gcnt, bofs);
    } else if (b < PB1 + EU) {
        embed_dev<32>(b - PB1, EU, x_user, Wembu, bembu, hu, NU_, flag);
    } else {
        embed_dev<64>(b - PB1 - EU, ET, x_txn, Wembt, bembt, ht, NT_, flag);
    }
}

// ---------------- bucket base scan (two independent segments) ----------------
__global__ void scan_buckets(const int* __restrict__ gcnt, int* __restrict__ gbase) {
    __shared__ int sc[NBKT];
    int t = threadIdx.x;
    if (t < NBKT) sc[t] = gcnt[t];
    __syncthreads();
    if (t == 0) {
        int s = 0;
        for (int j = 0; j < NBKC; ++j) { int c = sc[j]; sc[j] = s; s += c; }
        s = 0;
        for (int j = NBKC; j < NBKT; ++j) { int c = sc[j]; sc[j] = s; s += c; }
    }
    __syncthreads();
    if (t < NBKT) gbase[t] = sc[t];
}

// ---------------- partition pass 2: scatter (must mirror p1's item mapping) ----------------
__global__ __launch_bounds__(256) void p2_scatter(
    const int* __restrict__ eu2u, const int* __restrict__ et2t,
    const int* __restrict__ eu2t, const int* __restrict__ et2u,
    const int* __restrict__ gbase, const int* __restrict__ bofs,
    uint2* __restrict__ part_csr, unsigned int* __restrict__ part_src) {
    __shared__ int lofs[NBKT];
    for (int j = threadIdx.x; j < NBKT; j += 256) lofs[j] = 0;
    __syncthreads();
    const int bid = blockIdx.x;
    for (int i = bid * 256 + threadIdx.x; i < 6 * NE_; i += PB1 * 256) {
        if (i < 4 * NE_) {
            int m; unsigned int p;
            if (i < NE_)          { m = eu2u[i + NE_];           p = (unsigned int)eu2u[i]; }
            else if (i < 2 * NE_) { m = NU_ + et2t[i];           p = (unsigned int)et2t[i - NE_]; }
            else if (i < 3 * NE_) { m = NU_ + eu2t[i - NE_];     p = (unsigned int)eu2t[i - 2 * NE_] | 0x80000000u; }
            else                  { m = et2u[i - 2 * NE_];       p = (unsigned int)et2u[i - 3 * NE_] | 0x80000000u; }
            int b = m >> 11;
            int l = atomicAdd(&lofs[b], 1);
            int pos = gbase[b] + bofs[bid * NBKT + b] + l;
            part_csr[pos] = make_uint2((unsigned int)m, p);
        } else {
            int m2 = (i < 5 * NE_) ? eu2t[i - 4 * NE_] : (NU_ + et2u[i - 5 * NE_]);
            int b = NBKC + (m2 >> 11);
            int l = atomicAdd(&lofs[b], 1);
            int pos = gbase[b] + bofs[bid * NBKT + b] + l;
            part_src[pos] = (unsigned int)m2;
        }
    }
}

// ---------------- per-bucket exact counting (LDS atomics only) ----------------
// Writes EVERY hist entry (no prior memset needed).
__global__ __launch_bounds__(1024) void bucket_count(const uint2* __restrict__ part_csr,
                                                     const unsigned int* __restrict__ part_src,
                                                     const int* __restrict__ gcnt,
                                                     const int* __restrict__ gbase,
                                                     int* __restrict__ hist) {
    __shared__ int cA[BKP];
    __shared__ int cB[BKP];
    const int b = blockIdx.x;
    const int n = gcnt[b];
    const int base = gbase[b];
    const int t = threadIdx.x;
    for (int j = t; j < BKP; j += 1024) { cA[j] = 0; cB[j] = 0; }
    __syncthreads();
    if (b < NBKC) {
        for (int i = t; i < n; i += 1024) {
            uint2 it = part_csr[base + i];
            int l = (int)(it.x & (BKP - 1));
            if (it.y >> 31) atomicAdd(&cB[l], 1);
            else            atomicAdd(&cA[l], 1);
        }
        __syncthreads();
        const int m0 = b << 11;
        for (int j = t; j < BKP; j += 1024) {
            int m = m0 + j;
            if (m < NU_ + NT_) {
                int oA = (m < NU_) ? (OFF0 + m) : (OFF1 + (m - NU_));
                int oB = (m < NU_) ? (OFF3 + m) : (OFF2 + (m - NU_));
                hist[oA] = cA[j];
                hist[oB] = cB[j];
            }
        }
    } else {
        for (int i = t; i < n; i += 1024) {
            unsigned int m2 = part_src[base + i];
            atomicAdd(&cA[(int)(m2 & (BKP - 1))], 1);
        }
        __syncthreads();
        const int m0 = (b - NBKC) << 11;
        for (int j = t; j < BKP; j += 1024) {
            int m2 = m0 + j;
            if (m2 < NU_ + NT_) {
                int o = (m2 < NU_) ? (OFF4 + m2) : (OFF5 + (m2 - NU_));
                hist[o] = cA[j];
            }
        }
    }
}

// ---------------- per-bucket CSR placement (LDS bump allocators) ----------------
__global__ __launch_bounds__(1024) void bucket_place(const uint2* __restrict__ part_csr,
                                                     const int* __restrict__ gcnt,
                                                     const int* __restrict__ gbase,
                                                     const int* __restrict__ rp,
                                                     int* __restrict__ colU,
                                                     int* __restrict__ colT) {
    __shared__ int fl[BKP];
    const int b = blockIdx.x;
    const int n = gcnt[b];
    const int base = gbase[b];
    const int t = threadIdx.x;
    for (int j = t; j < BKP; j += 1024) fl[j] = 0;
    __syncthreads();
    for (int i = t; i < n; i += 1024) {
        uint2 it = part_csr[base + i];
        int m = (int)it.x;
        int ofs = atomicAdd(&fl[m & (BKP - 1)], 1);
        if (m < NU_) colU[rp[m] + ofs] = (int)it.y;
        else         colT[rp[m] + ofs] = (int)it.y;
    }
}

// ---------------- gemm + gather (proven bodies, unchanged) ----------------
__device__ __forceinline__ void gemm_dual_dev(int bid, int nblk, const float* __restrict__ h,
                                              const float* __restrict__ WA,
                                              const float* __restrict__ WB,
                                              const float* __restrict__ scA,
                                              const float* __restrict__ scB,
                                              unsigned char* __restrict__ mA,
                                              unsigned char* __restrict__ mB, int N) {
    const int lane = threadIdx.x & 63;
    float wa[HD], wb[HD];
#pragma unroll
    for (int k = 0; k < HD; ++k) wa[k] = WA[k * HD + lane];
#pragma unroll
    for (int k = 0; k < HD; ++k) wb[k] = WB[k * HD + lane];
    const int wid = (bid << 2) + (threadIdx.x >> 6);
    const int stride = nblk << 2;
    for (int r = wid; r < N; r += stride) {
        const float hv = h[(size_t)r * HD + lane];
        float accA = 0.f, accB = 0.f;
#pragma unroll
        for (int k = 0; k < HD; ++k) {
            float hk = __shfl(hv, k);
            accA = fmaf(hk, wa[k], accA);
            accB = fmaf(hk, wb[k], accB);
        }
        mA[(size_t)r * HD + lane] = enc_fp8(accA * scA[r]);
        mB[(size_t)r * HD + lane] = enc_fp8(accB * scB[r]);
    }
}

__device__ __forceinline__ void gather_dev(int blk, const unsigned char* __restrict__ mA,
                                           const unsigned char* __restrict__ mB,
                                           const int4* __restrict__ meta,
                                           const int* __restrict__ col,
                                           const float* __restrict__ ba,
                                           const float* __restrict__ bb,
                                           float* __restrict__ out, int N) {
    const int lane = threadIdx.x & 63;
    const int grp = lane >> 3;
    const int sub = lane & 7;
    const int d = (blk << 2) + (threadIdx.x >> 6);
    if (d >= N) return;

    const int4 mt = meta[d];
    const int st = mt.x;
    const int cnt = mt.y;
    const float dA = __int_as_float(mt.z);
    const float dB = __int_as_float(mt.w);
    float acc[8] = {0.f, 0.f, 0.f, 0.f, 0.f, 0.f, 0.f, 0.f};

    const uint2 uself = *(const uint2*)(mA + ((size_t)d << 6) + (sub << 3));

    int done = 0;
    while (done < cnt) {
        int rem = cnt - done;
        if (rem > 64) rem = 64;
        int cw = (lane < rem) ? col[st + done + lane] : 0;
        const int nch = (rem + 7) >> 3;

        uint2 ub0, ub1, ub2, ub3;
        float sc0, sc1, sc2, sc3;

        auto issue = [&](int p, uint2& ub, float& sc) {
            int j = (p << 3) + grp;
            unsigned int c = (unsigned int)__shfl(cw, j);
            const unsigned char* base = (c >> 31) ? mB : mA;
            float sv = (c >> 31) ? dB : dA;
            unsigned int idx = c & 0x7fffffffu;
            sc = (j < rem) ? sv : 0.f;
            ub = *(const uint2*)(base + ((size_t)idx << 6) + (sub << 3));
        };
        auto consume = [&](uint2 u, float s) {
            float f[8];
            dec4_fp8(u.x, f);
            dec4_fp8(u.y, f + 4);
#pragma unroll
            for (int k = 0; k < 8; ++k) acc[k] = fmaf(f[k], s, acc[k]);
        };

        issue(0, ub0, sc0);
        if (nch > 1) issue(1, ub1, sc1);
        if (nch > 2) issue(2, ub2, sc2);
        if (nch > 3) issue(3, ub3, sc3);

        consume(ub0, sc0);
        if (nch > 4) issue(4, ub0, sc0);
        if (nch > 1) consume(ub1, sc1);
        if (nch > 5) issue(5, ub1, sc1);
        if (nch > 2) consume(ub2, sc2);
        if (nch > 6) issue(6, ub2, sc2);
        if (nch > 3) consume(ub3, sc3);
        if (nch > 7) issue(7, ub3, sc3);
        if (nch > 4) consume(ub0, sc0);
        if (nch > 5) consume(ub1, sc1);
        if (nch > 6) consume(ub2, sc2);
        if (nch > 7) consume(ub3, sc3);

        done += rem;
    }

    {
        float f[8];
        dec4_fp8(uself.x, f);
        dec4_fp8(uself.y, f + 4);
        const float s = (grp == 0) ? dA : 0.f;
#pragma unroll
        for (int k = 0; k < 8; ++k) acc[k] = fmaf(f[k], s, acc[k]);
    }

#pragma unroll
    for (int k = 0; k < 8; ++k) {
        acc[k] += __shfl_xor(acc[k], 8);
        acc[k] += __shfl_xor(acc[k], 16);
        acc[k] += __shfl_xor(acc[k], 32);
    }

    if (grp == 0) {
        const int col0 = sub << 3;
        float o[8];
#pragma unroll
        for (int k = 0; k < 8; ++k)
            o[k] = fmaxf(0.5f * (acc[k] + ba[col0 + k] + bb[col0 + k]), 0.f);
        float4 v0 = {o[0], o[1], o[2], o[3]};
        float4 v1 = {o[4], o[5], o[6], o[7]};
        *(float4*)(out + ((size_t)d << 6) + col0) = v0;
        *(float4*)(out + ((size_t)d << 6) + col0 + 4) = v1;
    }
}

__global__ __launch_bounds__(256) void gemm_dual_both(
    const float* __restrict__ hu, const float* __restrict__ ht,
    const float* __restrict__ W0, const float* __restrict__ Wu2t,
    const float* __restrict__ Wt, const float* __restrict__ Wt2u,
    const float* __restrict__ dinv,
    unsigned char* __restrict__ m_uu, unsigned char* __restrict__ m_ut,
    unsigned char* __restrict__ m_tt, unsigned char* __restrict__ m_tu) {
    int b = blockIdx.x;
    if (b < GU) {
        gemm_dual_dev(b, GU, hu, W0, Wu2t, dinv + OFF0, dinv + OFF4, m_uu, m_ut, NU_);
    } else {
        gemm_dual_dev(b - GU, GT, ht, Wt, Wt2u, dinv + OFF1, dinv + OFF5, m_tt, m_tu, NT_);
    }
}

__global__ __launch_bounds__(256) void gather_both(
    const unsigned char* __restrict__ m_uu, const unsigned char* __restrict__ m_tu,
    const unsigned char* __restrict__ m_tt, const unsigned char* __restrict__ m_ut,
    const int4* __restrict__ meta,
    const int* __restrict__ colU, const int* __restrict__ colT,
    const float* __restrict__ bU0, const float* __restrict__ bU1,
    const float* __restrict__ bT0, const float* __restrict__ bT1,
    float* __restrict__ hu, float* __restrict__ ht) {
    int b = blockIdx.x;
    if (b < GBU) {
        gather_dev(b, m_uu, m_tu, meta, colU, bU0, bU1, hu, NU_);
    } else {
        gather_dev(b - GBU, m_tt, m_ut, meta + NU_, colT, bT0, bT1, ht, NT_);
    }
}

// ---------------- CSR scan kernels (round-0 proven; dinv folded in) ----------------
__global__ __launch_bounds__(256) void scan1m(const int* __restrict__ hist, int* __restrict__ rp,
                                              int* __restrict__ bsums, float* __restrict__ dinv) {
    int b = blockIdx.x, t = threadIdx.x;
    int r, lb, n, rpbase, oA, oB;
    if (b < NBU) { r = 0; lb = b;       n = NU_; rpbase = 0;   oA = OFF0; oB = OFF3; }
    else         { r = 1; lb = b - NBU; n = NT_; rpbase = NU_; oA = OFF1; oB = OFF2; }
    int i = lb * 256 + t;
    int hA = (i < n) ? hist[oA + i] : 0;
    int hB = (i < n) ? hist[oB + i] : 0;
    if (i < n) {
        dinv[oA + i] = rsqrtf((float)hA + 1.0f);                       // self-loop type
        dinv[oB + i] = (hB > 0) ? rsqrtf((float)hB) : 0.f;             // bipartite dst
    }
    int v = hA + hB;
    __shared__ int s[256];
    s[t] = v;
    __syncthreads();
    for (int off = 1; off < 256; off <<= 1) {
        int x = (t >= off) ? s[t - off] : 0;
        __syncthreads();
        s[t] += x;
        __syncthreads();
    }
    if (i < n) rp[rpbase + i] = s[t] - v;
    if (t == 255) bsums[r * 1024 + lb] = s[255];
}

__global__ __launch_bounds__(1024) void scan2m(int* __restrict__ bsums) {
    int r = blockIdx.x, t = threadIdx.x;
    const int nb = r ? NBT : NBU;
    int v = (t < nb) ? bsums[r * 1024 + t] : 0;
    __shared__ int s[1024];
    s[t] = v;
    __syncthreads();
    for (int off = 1; off < 1024; off <<= 1) {
        int x = (t >= off) ? s[t - off] : 0;
        __syncthreads();
        s[t] += x;
        __syncthreads();
    }
    if (t < nb) bsums[r * 1024 + t] = s[t] - v;
}

// scan3m: finalize rp, src dinv, and pack gather metadata {rp, cnt, dA, dB}
__global__ void scan3m(int* __restrict__ rp, const int* __restrict__ bsums,
                       const int* __restrict__ hist, float* __restrict__ dinv,
                       int4* __restrict__ meta) {
    int gid = blockIdx.x * blockDim.x + threadIdx.x;
    if (gid >= RPT2) return;
    int r = (gid < NU_) ? 0 : 1;
    int base = r ? NU_ : 0;
    int lb = (gid - base) >> 8;
    int rpf = rp[gid] + bsums[r * 1024 + lb];
    rp[gid] = rpf;
    // src dinv (for GEMM scaling)
    int si = r ? (OFF5 + gid - NU_) : (OFF4 + gid);
    int h = hist[si];
    dinv[si] = (h > 0) ? rsqrtf((float)h) : 0.f;
    // packed gather meta
    int oA = r ? (OFF1 + gid - NU_) : (OFF0 + gid);
    int oB = r ? (OFF2 + gid - NU_) : (OFF3 + gid);
    int hA = hist[oA];
    int hB = hist[oB];
    float dA = rsqrtf((float)hA + 1.0f);
    float dB = (hB > 0) ? rsqrtf((float)hB) : 0.f;
    int4 mt;
    mt.x = rpf;
    mt.y = hA + hB;
    mt.z = __float_as_int(dA);
    mt.w = __float_as_int(dB);
    meta[gid] = mt;
}

// ---------------- readout ----------------
__global__ __launch_bounds__(256) void colmean_both(const float* __restrict__ hu,
                                                    const float* __restrict__ ht,
                                                    float* __restrict__ gsum) {
    const bool isU = blockIdx.x < 512;
    const float* h = isU ? hu : ht;
    const int n = isU ? NU_ : NT_;
    const float scale = isU ? 0.5f / NU_ : 0.5f / NT_;
    const int blk = isU ? blockIdx.x : blockIdx.x - 512;
    const int lane = threadIdx.x & 63;
    const int w = threadIdx.x >> 6;
    float s = 0.f;
    for (int r = blk * 4 + w; r < n; r += 512 * 4)
        s += h[(size_t)r * HD + lane];
    __shared__ float red[256];
    red[threadIdx.x] = s;
    __syncthreads();
    if (threadIdx.x < 64) {
        float t = red[threadIdx.x] + red[64 + threadIdx.x] + red[128 + threadIdx.x] +
                  red[192 + threadIdx.x];
        atomicAdd(&gsum[lane], t * scale);
    }
}

__global__ void head(const float* __restrict__ g, const float* __restrict__ W1,
                     const float* __restrict__ b1, const float* __restrict__ W2,
                     const float* __restrict__ b2, const int* __restrict__ flag,
                     void* __restrict__ out) {
    const int c = threadIdx.x;
    float x = b1[c];
    for (int k = 0; k < HD; ++k) x = fmaf(g[k], W1[k * HD + c], x);
    x = fmaxf(x, 0.f);
    float t = x * W2[c];
    for (int off = 32; off; off >>= 1) t += __shfl_down(t, off);
    if (c == 0) {
        float z = t + b2[0];
        float s = 1.f / (1.f + expf(-z));
        if (flag[0]) *(__hip_bfloat16*)out = __float2bfloat16(s);
        else *(float*)out = s;
    }
}

extern "C" void kernel_launch(void* const* d_in, const int* in_sizes, int n_in,
                              void* d_out, int out_size, void* d_ws, size_t ws_size,
                              hipStream_t stream) {
    const void* x_user = d_in[0];
    const void* x_txn  = d_in[1];
    const int* ei_u2u = (const int*)d_in[2];
    const int* ei_t2t = (const int*)d_in[3];
    const int* ei_u2t = (const int*)d_in[4];
    const int* ei_t2u = (const int*)d_in[5];

    // ---- workspace layout ----
    float* ws = (float*)d_ws;
    float* hu = ws;                                   // NU*64 f32
    float* ht = hu + (size_t)NU_ * HD;                // NT*64 f32
    float* dinv = ht + (size_t)NT_ * HD;              // HTOT
    float* wts = dinv + HTOT;                         // 60432 (padded)
    float* gsum = wts + 60432;                        // 64
    unsigned char* m_uu = (unsigned char*)(gsum + 64);  // NU*64 fp8
    unsigned char* m_ut = m_uu + (size_t)NU_ * HD;
    unsigned char* m_tt = m_ut + (size_t)NU_ * HD;
    unsigned char* m_tu = m_tt + (size_t)NT_ * HD;
    int* hist = (int*)(m_tu + (size_t)NT_ * HD);      // HTOT
    int* aux  = hist + HTOT;                          // RPT2 region (old fill): gcnt/gbase/bofs
    int* rp   = aux + RPT2;                           // RPT2
    int* bsums = rp + RPT2;                           // 2048
    int* colU = bsums + 2048;                         // 2M
    int* colT = colU + 2 * NE_;                       // 2M
    int4* meta = (int4*)(colT + 2 * NE_);             // RPT2 (16B each)
    int* dflag = (int*)(meta + RPT2);                 // 1

    // partition bookkeeping in the old fill region (151,116 <= 300,000 ints)
    int* gcnt  = aux;               // NBKT
    int* gbase = gcnt + NBKT;       // NBKT
    int* bofs  = gbase + NBKT;      // PB1*NBKT = 150,528

    // partition payload aliases:
    //  part_csr (4M uint2 = 32 MB) over fp8 msgs (38.4 MB, dead until layer-0 gemm;
    //            consumed by bucket_count/bucket_place which run before it)
    //  part_src (2M u32 = 8 MB) over colU (dead until bucket_place, which runs
    //            after bucket_count consumed part_src)
    uint2* part_csr = (uint2*)m_uu;
    unsigned int* part_src = (unsigned int*)colU;

    // fp32 weight sub-pointers
    float* Wembu = wts;              // 2048
    float* bembu = Wembu + 2048;     // 64
    float* Wembt = bembu + 64;       // 4096
    float* bembt = Wembt + 4096;     // 64
    float* convWf = bembt + 64;      // 49152
    float* convbf = convWf + 49152;  // 768
    float* W1f = convbf + 768;       // 4096
    float* b1f = W1f + 4096;         // 64
    float* W2f = b1f + 64;           // 64
    float* b2f = W2f + 64;           // 1

    hipMemsetAsync(gcnt, 0, (size_t)NBKT * sizeof(int), stream);

    detect_dtype<<<1, 256, 0, stream>>>((const unsigned short*)x_user, dflag, 2048);
    {
        Ptr10 p;
        for (int k = 0; k < 10; ++k) p.p[k] = d_in[6 + k];
        cvt_weights<<<(60417 + 255) / 256, 256, 0, stream>>>(p, wts, gsum, dflag);
    }

    // ---- fused: partition pass 1 (LDS counts) + embedding GEMMs ----
    fused_p1_embed<<<PB1 + EU + ET, 256, 0, stream>>>(
        ei_u2u, ei_t2t, ei_u2t, ei_t2u, gcnt, bofs,
        x_user, x_txn, Wembu, bembu, Wembt, bembt, hu, ht, dflag);

    scan_buckets<<<1, 512, 0, stream>>>(gcnt, gbase);
    p2_scatter<<<PB1, 256, 0, stream>>>(ei_u2u, ei_t2t, ei_u2t, ei_t2u,
                                        gbase, bofs, part_csr, part_src);
    bucket_count<<<NBKT, 1024, 0, stream>>>(part_csr, part_src, gcnt, gbase, hist);

    scan1m<<<NBTOT2, 256, 0, stream>>>(hist, rp, bsums, dinv);
    scan2m<<<2, 1024, 0, stream>>>(bsums);
    scan3m<<<(RPT2 + 255) / 256, 256, 0, stream>>>(rp, bsums, hist, dinv, meta);

    bucket_place<<<NBKC, 1024, 0, stream>>>(part_csr, gcnt, gbase, rp, colU, colT);

    for (int l = 0; l < NL; ++l) {
        const float* W0   = convWf + ((size_t)l * 4 + 0) * HD * HD;
        const float* Wt   = convWf + ((size_t)l * 4 + 1) * HD * HD;
        const float* Wu2t = convWf + ((size_t)l * 4 + 2) * HD * HD;
        const float* Wt2u = convWf + ((size_t)l * 4 + 3) * HD * HD;
        const float* B0   = convbf + ((size_t)l * 4 + 0) * HD;
        const float* Bt   = convbf + ((size_t)l * 4 + 1) * HD;
        const float* Bu2t = convbf + ((size_t)l * 4 + 2) * HD;
        const float* Bt2u = convbf + ((size_t)l * 4 + 3) * HD;

        gemm_dual_both<<<GU + GT, 256, 0, stream>>>(hu, ht, W0, Wu2t, Wt, Wt2u, dinv,
                                                    m_uu, m_ut, m_tt, m_tu);

        gather_both<<<GBU + GBT, 256, 0, stream>>>(m_uu, m_tu, m_tt, m_ut,
                                                   meta, colU, colT,
                                                   B0, Bt2u, Bt, Bu2t, hu, ht);
    }

    // ---- readout ----
    colmean_both<<<1024, 256, 0, stream>>>(hu, ht, gsum);
    head<<<1, 64, 0, stream>>>(gsum, W1f, b1f, W2f, b2f, dflag, d_out);
}

// Round 4
// 1019.187 us; speedup vs baseline: 1.8781x; 1.5740x over previous
//
#include <hip/hip_runtime.h>
#include <hip/hip_bf16.h>
#include <hip/hip_fp8.h>

#define NU_ 100000
#define NT_ 200000
#define NE_ 1000000
#define HD  64
#define NL  3

// hist/dinv region offsets (node-keyed arrays)
#define OFF0 0                   // u2u dst (NU)  [selfloop]
#define OFF1 (NU_)               // t2t dst (NT)  [selfloop]
#define OFF2 (NU_ + NT_)         // u2t dst (NT)
#define OFF3 (NU_ + 2 * NT_)     // t2u dst (NU)
#define OFF4 (2 * NU_ + 2 * NT_) // u2t src (NU)
#define OFF5 (3 * NU_ + 2 * NT_) // t2u src (NT)
#define HTOT (3 * NU_ + 3 * NT_) // 900k
#define RPT2 (NU_ + NT_)         // merged rp size (300k)

// merged scan partition (256/block)
#define NBU 391
#define NBT 782
#define NBTOT2 (NBU + NBT)

// bucket partition (no-far-atomic CSR build)
#define PB1  512           // partition blocks (256 threads each); p1/p2 must match
#define BKP  2048          // node-keys per bucket (key >> 11)
#define NBKC 147           // CSR buckets  (300k / 2048)
#define NBKS 147           // src buckets  (300k / 2048)
#define NBKT (NBKC + NBKS) // 294

// fused grids
#define EU  4096           // embed user blocks
#define ET  8192           // embed txn blocks
#define GMU 512            // mfma gemm user blocks (2048 waves, 6250 tiles)
#define GMT 1024           // mfma gemm txn blocks (4096 waves, 12500 tiles)
#define GBU 25000          // ceil(NU/4) gather blocks (user)
#define GBT 50000          // ceil(NT/4) gather blocks (txn)

typedef float floatx2 __attribute__((ext_vector_type(2)));
typedef _Float16 f16x8 __attribute__((ext_vector_type(8)));
typedef float f32x4 __attribute__((ext_vector_type(4)));

// ---------------- fp8 helpers ----------------
__device__ __forceinline__ unsigned char enc_fp8(float v) {
    return (unsigned char)__hip_cvt_float_to_fp8(v, __HIP_SATFINITE, __HIP_E4M3);
}

__device__ __forceinline__ float dec1_fp8(unsigned int u) {
    int e = (u >> 3) & 15;
    int m = u & 7;
    int mant = m | (e ? 8 : 0);
    if (u & 0x80) mant = -mant;
    int ex = (e ? e : 1) - 10;
    return (float)mant * __uint_as_float((unsigned int)(ex + 127) << 23);
}

__device__ __forceinline__ void dec4_fp8(unsigned int u, float* f) {
#if __has_builtin(__builtin_amdgcn_cvt_pk_f32_fp8)
    floatx2 lo = __builtin_amdgcn_cvt_pk_f32_fp8((int)u, false);
    floatx2 hi = __builtin_amdgcn_cvt_pk_f32_fp8((int)u, true);
    f[0] = lo.x; f[1] = lo.y; f[2] = hi.x; f[3] = hi.y;
#else
    f[0] = dec1_fp8(u & 0xff);
    f[1] = dec1_fp8((u >> 8) & 0xff);
    f[2] = dec1_fp8((u >> 16) & 0xff);
    f[3] = dec1_fp8((u >> 24) & 0xff);
#endif
}

// ---------------- dtype detection ----------------
__global__ void detect_dtype(const unsigned short* __restrict__ x, int* __restrict__ flag, int n) {
    __shared__ int s_big;
    if (threadIdx.x == 0) s_big = 0;
    __syncthreads();
    int big = 0;
    for (int i = threadIdx.x; i < n; i += blockDim.x) {
        float v = __uint_as_float(((unsigned int)x[i]) << 16);
        if (!(fabsf(v) < 1.0e4f)) big = 1;
    }
    if (big) atomicAdd(&s_big, 1);
    __syncthreads();
    if (threadIdx.x == 0) flag[0] = (s_big > 0) ? 0 : 1;
}

// ---------------- fused weight conversion (+ gsum zero) ----------------
struct Ptr10 { const void* p[10]; };

__global__ void cvt_weights(Ptr10 src, float* __restrict__ dst, float* __restrict__ gsum,
                            const int* __restrict__ flag) {
    const int c[11] = {0, 2048, 2112, 6208, 6272, 55424, 56192, 60288, 60352, 60416, 60417};
    int i = blockIdx.x * blockDim.x + threadIdx.x;
    if (i < 64) gsum[i] = 0.f;
    if (i >= 60417) return;
    int r = 0;
#pragma unroll
    for (int k = 1; k < 10; ++k)
        if (i >= c[k]) r = k;
    int e = i - c[r];
    if (flag[0]) {
        unsigned short u = ((const unsigned short*)src.p[r])[e];
        dst[i] = __uint_as_float(((unsigned int)u) << 16);
    } else {
        dst[i] = ((const float*)src.p[r])[e];
    }
}

// ---------------- partition pass 1: per-block bucket counts (LDS) ----------------
__device__ __forceinline__ void p1_dev(int bid, const int* __restrict__ eu2u,
                                       const int* __restrict__ et2t,
                                       const int* __restrict__ eu2t,
                                       const int* __restrict__ et2u,
                                       int* __restrict__ gcnt, int* __restrict__ bofs) {
    __shared__ int cnt[NBKT];
    for (int j = threadIdx.x; j < NBKT; j += 256) cnt[j] = 0;
    __syncthreads();
    for (int i = bid * 256 + threadIdx.x; i < 6 * NE_; i += PB1 * 256) {
        int b;
        if (i < 4 * NE_) {
            int m;
            if (i < NE_)          m = eu2u[i + NE_];
            else if (i < 2 * NE_) m = NU_ + et2t[i];          // (i-NE_) + NE_
            else if (i < 3 * NE_) m = NU_ + eu2t[i - NE_];    // (i-2NE_) + NE_
            else                  m = et2u[i - 2 * NE_];      // (i-3NE_) + NE_
            b = m >> 11;
        } else {
            int m2 = (i < 5 * NE_) ? eu2t[i - 4 * NE_] : (NU_ + et2u[i - 5 * NE_]);
            b = NBKC + (m2 >> 11);
        }
        atomicAdd(&cnt[b], 1);
    }
    __syncthreads();
    for (int j = threadIdx.x; j < NBKT; j += 256) {
        bofs[bid * NBKT + j] = atomicAdd(&gcnt[j], cnt[j]);
    }
}

// ---------------- embed (shuffle-broadcast matvec) ----------------
template <int K>
__device__ __forceinline__ void embed_dev(int bid, int nblk, const void* __restrict__ x,
                                          const float* __restrict__ W,
                                          const float* __restrict__ bias,
                                          float* __restrict__ out, int N,
                                          const int* __restrict__ flag) {
    const int lane = threadIdx.x & 63;
    float w[K];
#pragma unroll
    for (int k = 0; k < K; ++k) w[k] = W[k * HD + lane];
    const float b = bias[lane];
    const bool isb = flag[0] != 0;
    const int wid = (bid << 2) + (threadIdx.x >> 6);
    const int stride = nblk << 2;
    const int le = lane & (K - 1);
    if (isb) {
        const unsigned short* xb = (const unsigned short*)x;
        for (int r = wid; r < N; r += stride) {
            float hv = __uint_as_float(((unsigned int)xb[(size_t)r * K + le]) << 16);
            float acc = b;
#pragma unroll
            for (int k = 0; k < K; ++k) acc = fmaf(__shfl(hv, k), w[k], acc);
            out[(size_t)r * HD + lane] = acc;
        }
    } else {
        const float* xf = (const float*)x;
        for (int r = wid; r < N; r += stride) {
            float hv = xf[(size_t)r * K + le];
            float acc = b;
#pragma unroll
            for (int k = 0; k < K; ++k) acc = fmaf(__shfl(hv, k), w[k], acc);
            out[(size_t)r * HD + lane] = acc;
        }
    }
}

__global__ __launch_bounds__(256) void fused_p1_embed(
    const int* __restrict__ eu2u, const int* __restrict__ et2t,
    const int* __restrict__ eu2t, const int* __restrict__ et2u,
    int* __restrict__ gcnt, int* __restrict__ bofs,
    const void* __restrict__ x_user, const void* __restrict__ x_txn,
    const float* __restrict__ Wembu, const float* __restrict__ bembu,
    const float* __restrict__ Wembt, const float* __restrict__ bembt,
    float* __restrict__ hu, float* __restrict__ ht, const int* __restrict__ flag) {
    int b = blockIdx.x;
    if (b < PB1) {
        p1_dev(b, eu2u, et2t, eu2t, et2u, gcnt, bofs);
    } else if (b < PB1 + EU) {
        embed_dev<32>(b - PB1, EU, x_user, Wembu, bembu, hu, NU_, flag);
    } else {
        embed_dev<64>(b - PB1 - EU, ET, x_txn, Wembt, bembt, ht, NT_, flag);
    }
}

// ---------------- bucket base scan (two independent segments) ----------------
__global__ void scan_buckets(const int* __restrict__ gcnt, int* __restrict__ gbase) {
    __shared__ int sc[NBKT];
    int t = threadIdx.x;
    if (t < NBKT) sc[t] = gcnt[t];
    __syncthreads();
    if (t == 0) {
        int s = 0;
        for (int j = 0; j < NBKC; ++j) { int c = sc[j]; sc[j] = s; s += c; }
        s = 0;
        for (int j = NBKC; j < NBKT; ++j) { int c = sc[j]; sc[j] = s; s += c; }
    }
    __syncthreads();
    if (t < NBKT) gbase[t] = sc[t];
}

// ---------------- partition pass 2: scatter (must mirror p1's item mapping) ----------------
__global__ __launch_bounds__(256) void p2_scatter(
    const int* __restrict__ eu2u, const int* __restrict__ et2t,
    const int* __restrict__ eu2t, const int* __restrict__ et2u,
    const int* __restrict__ gbase, const int* __restrict__ bofs,
    uint2* __restrict__ part_csr, unsigned int* __restrict__ part_src) {
    __shared__ int lofs[NBKT];
    for (int j = threadIdx.x; j < NBKT; j += 256) lofs[j] = 0;
    __syncthreads();
    const int bid = blockIdx.x;
    for (int i = bid * 256 + threadIdx.x; i < 6 * NE_; i += PB1 * 256) {
        if (i < 4 * NE_) {
            int m; unsigned int p;
            if (i < NE_)          { m = eu2u[i + NE_];           p = (unsigned int)eu2u[i]; }
            else if (i < 2 * NE_) { m = NU_ + et2t[i];           p = (unsigned int)et2t[i - NE_]; }
            else if (i < 3 * NE_) { m = NU_ + eu2t[i - NE_];     p = (unsigned int)eu2t[i - 2 * NE_] | 0x80000000u; }
            else                  { m = et2u[i - 2 * NE_];       p = (unsigned int)et2u[i - 3 * NE_] | 0x80000000u; }
            int b = m >> 11;
            int l = atomicAdd(&lofs[b], 1);
            int pos = gbase[b] + bofs[bid * NBKT + b] + l;
            part_csr[pos] = make_uint2((unsigned int)m, p);
        } else {
            int m2 = (i < 5 * NE_) ? eu2t[i - 4 * NE_] : (NU_ + et2u[i - 5 * NE_]);
            int b = NBKC + (m2 >> 11);
            int l = atomicAdd(&lofs[b], 1);
            int pos = gbase[b] + bofs[bid * NBKT + b] + l;
            part_src[pos] = (unsigned int)m2;
        }
    }
}

// ---------------- per-bucket exact counting (LDS atomics only) ----------------
__global__ __launch_bounds__(1024) void bucket_count(const uint2* __restrict__ part_csr,
                                                     const unsigned int* __restrict__ part_src,
                                                     const int* __restrict__ gcnt,
                                                     const int* __restrict__ gbase,
                                                     int* __restrict__ hist) {
    __shared__ int cA[BKP];
    __shared__ int cB[BKP];
    const int b = blockIdx.x;
    const int n = gcnt[b];
    const int base = gbase[b];
    const int t = threadIdx.x;
    for (int j = t; j < BKP; j += 1024) { cA[j] = 0; cB[j] = 0; }
    __syncthreads();
    if (b < NBKC) {
        for (int i = t; i < n; i += 1024) {
            uint2 it = part_csr[base + i];
            int l = (int)(it.x & (BKP - 1));
            if (it.y >> 31) atomicAdd(&cB[l], 1);
            else            atomicAdd(&cA[l], 1);
        }
        __syncthreads();
        const int m0 = b << 11;
        for (int j = t; j < BKP; j += 1024) {
            int m = m0 + j;
            if (m < NU_ + NT_) {
                int oA = (m < NU_) ? (OFF0 + m) : (OFF1 + (m - NU_));
                int oB = (m < NU_) ? (OFF3 + m) : (OFF2 + (m - NU_));
                hist[oA] = cA[j];
                hist[oB] = cB[j];
            }
        }
    } else {
        for (int i = t; i < n; i += 1024) {
            unsigned int m2 = part_src[base + i];
            atomicAdd(&cA[(int)(m2 & (BKP - 1))], 1);
        }
        __syncthreads();
        const int m0 = (b - NBKC) << 11;
        for (int j = t; j < BKP; j += 1024) {
            int m2 = m0 + j;
            if (m2 < NU_ + NT_) {
                int o = (m2 < NU_) ? (OFF4 + m2) : (OFF5 + (m2 - NU_));
                hist[o] = cA[j];
            }
        }
    }
}

// ---------------- per-bucket CSR placement (LDS bump allocators) ----------------
__global__ __launch_bounds__(1024) void bucket_place(const uint2* __restrict__ part_csr,
                                                     const int* __restrict__ gcnt,
                                                     const int* __restrict__ gbase,
                                                     const int* __restrict__ rp,
                                                     int* __restrict__ colU,
                                                     int* __restrict__ colT) {
    __shared__ int fl[BKP];
    const int b = blockIdx.x;
    const int n = gcnt[b];
    const int base = gbase[b];
    const int t = threadIdx.x;
    for (int j = t; j < BKP; j += 1024) fl[j] = 0;
    __syncthreads();
    for (int i = t; i < n; i += 1024) {
        uint2 it = part_csr[base + i];
        int m = (int)it.x;
        int ofs = atomicAdd(&fl[m & (BKP - 1)], 1);
        if (m < NU_) colU[rp[m] + ofs] = (int)it.y;
        else         colT[rp[m] + ofs] = (int)it.y;
    }
}

// ---------------- MFMA dual GEMM ----------------
// Per 16-row tile: C[16x64] = H[16x64] @ W[64x64] for BOTH weight matrices,
// 16x16x32_f16 MFMA, fragments: A row=lane&15, k=8*(lane>>4)+j; B col=lane&15;
// C col=lane&15, row=(lane>>4)*4+reg (m89-verified layout).
__device__ __forceinline__ void gemm_mfma_dev(int t0, int tstride, int ntiles,
                                              const float* __restrict__ h,
                                              const float* __restrict__ WA,
                                              const float* __restrict__ WB,
                                              const float* __restrict__ scA,
                                              const float* __restrict__ scB,
                                              unsigned char* __restrict__ mA,
                                              unsigned char* __restrict__ mB) {
    const int lane = threadIdx.x & 63;
    const int rq = lane & 15;
    const int oct = lane >> 4;

    // preload 16 weight fragments (f32 -> f16): [mat][coltile][kstep]
    f16x8 bf[2][4][2];
#pragma unroll
    for (int m = 0; m < 2; ++m) {
        const float* W = m ? WB : WA;
#pragma unroll
        for (int ct = 0; ct < 4; ++ct)
#pragma unroll
            for (int s = 0; s < 2; ++s) {
                const float* wp = W + (size_t)(32 * s + 8 * oct) * HD + 16 * ct + rq;
                f16x8 v;
#pragma unroll
                for (int j = 0; j < 8; ++j) v[j] = (_Float16)wp[(size_t)j * HD];
                bf[m][ct][s] = v;
            }
    }

    for (int t = t0; t < ntiles; t += tstride) {
        const int r0 = t << 4;
        const float* hr = h + (size_t)(r0 + rq) * HD + 8 * oct;
        float4 x0 = *(const float4*)(hr);
        float4 x1 = *(const float4*)(hr + 4);
        float4 y0 = *(const float4*)(hr + 32);
        float4 y1 = *(const float4*)(hr + 36);
        f16x8 a0, a1;
        a0[0] = (_Float16)x0.x; a0[1] = (_Float16)x0.y;
        a0[2] = (_Float16)x0.z; a0[3] = (_Float16)x0.w;
        a0[4] = (_Float16)x1.x; a0[5] = (_Float16)x1.y;
        a0[6] = (_Float16)x1.z; a0[7] = (_Float16)x1.w;
        a1[0] = (_Float16)y0.x; a1[1] = (_Float16)y0.y;
        a1[2] = (_Float16)y0.z; a1[3] = (_Float16)y0.w;
        a1[4] = (_Float16)y1.x; a1[5] = (_Float16)y1.y;
        a1[6] = (_Float16)y1.z; a1[7] = (_Float16)y1.w;

        f32x4 acc[2][4];
#pragma unroll
        for (int m = 0; m < 2; ++m)
#pragma unroll
            for (int ct = 0; ct < 4; ++ct) acc[m][ct] = (f32x4){0.f, 0.f, 0.f, 0.f};

#pragma unroll
        for (int m = 0; m < 2; ++m)
#pragma unroll
            for (int ct = 0; ct < 4; ++ct) {
                acc[m][ct] = __builtin_amdgcn_mfma_f32_16x16x32_f16(a0, bf[m][ct][0],
                                                                   acc[m][ct], 0, 0, 0);
                acc[m][ct] = __builtin_amdgcn_mfma_f32_16x16x32_f16(a1, bf[m][ct][1],
                                                                   acc[m][ct], 0, 0, 0);
            }

        const int rb = r0 + (oct << 2);
        float sa[4], sb[4];
#pragma unroll
        for (int g = 0; g < 4; ++g) { sa[g] = scA[rb + g]; sb[g] = scB[rb + g]; }
#pragma unroll
        for (int ct = 0; ct < 4; ++ct)
#pragma unroll
            for (int g = 0; g < 4; ++g) {
                mA[(size_t)(rb + g) * HD + 16 * ct + rq] = enc_fp8(acc[0][ct][g] * sa[g]);
                mB[(size_t)(rb + g) * HD + 16 * ct + rq] = enc_fp8(acc[1][ct][g] * sb[g]);
            }
    }
}

__global__ __launch_bounds__(256) void gemm_dual_both(
    const float* __restrict__ hu, const float* __restrict__ ht,
    const float* __restrict__ W0, const float* __restrict__ Wu2t,
    const float* __restrict__ Wt, const float* __restrict__ Wt2u,
    const float* __restrict__ dinv,
    unsigned char* __restrict__ m_uu, unsigned char* __restrict__ m_ut,
    unsigned char* __restrict__ m_tt, unsigned char* __restrict__ m_tu) {
    int b = blockIdx.x;
    int wid = threadIdx.x >> 6;
    if (b < GMU) {
        gemm_mfma_dev(b * 4 + wid, GMU * 4, NU_ / 16, hu, W0, Wu2t,
                      dinv + OFF0, dinv + OFF4, m_uu, m_ut);
    } else {
        gemm_mfma_dev((b - GMU) * 4 + wid, GMT * 4, NT_ / 16, ht, Wt, Wt2u,
                      dinv + OFF1, dinv + OFF5, m_tt, m_tu);
    }
}

// ---------------- gather (proven body, unchanged) ----------------
__device__ __forceinline__ void gather_dev(int blk, const unsigned char* __restrict__ mA,
                                           const unsigned char* __restrict__ mB,
                                           const int4* __restrict__ meta,
                                           const int* __restrict__ col,
                                           const float* __restrict__ ba,
                                           const float* __restrict__ bb,
                                           float* __restrict__ out, int N) {
    const int lane = threadIdx.x & 63;
    const int grp = lane >> 3;
    const int sub = lane & 7;
    const int d = (blk << 2) + (threadIdx.x >> 6);
    if (d >= N) return;

    const int4 mt = meta[d];
    const int st = mt.x;
    const int cnt = mt.y;
    const float dA = __int_as_float(mt.z);
    const float dB = __int_as_float(mt.w);
    float acc[8] = {0.f, 0.f, 0.f, 0.f, 0.f, 0.f, 0.f, 0.f};

    const uint2 uself = *(const uint2*)(mA + ((size_t)d << 6) + (sub << 3));

    int done = 0;
    while (done < cnt) {
        int rem = cnt - done;
        if (rem > 64) rem = 64;
        int cw = (lane < rem) ? col[st + done + lane] : 0;
        const int nch = (rem + 7) >> 3;

        uint2 ub0, ub1, ub2, ub3;
        float sc0, sc1, sc2, sc3;

        auto issue = [&](int p, uint2& ub, float& sc) {
            int j = (p << 3) + grp;
            unsigned int c = (unsigned int)__shfl(cw, j);
            const unsigned char* base = (c >> 31) ? mB : mA;
            float sv = (c >> 31) ? dB : dA;
            unsigned int idx = c & 0x7fffffffu;
            sc = (j < rem) ? sv : 0.f;
            ub = *(const uint2*)(base + ((size_t)idx << 6) + (sub << 3));
        };
        auto consume = [&](uint2 u, float s) {
            float f[8];
            dec4_fp8(u.x, f);
            dec4_fp8(u.y, f + 4);
#pragma unroll
            for (int k = 0; k < 8; ++k) acc[k] = fmaf(f[k], s, acc[k]);
        };

        issue(0, ub0, sc0);
        if (nch > 1) issue(1, ub1, sc1);
        if (nch > 2) issue(2, ub2, sc2);
        if (nch > 3) issue(3, ub3, sc3);

        consume(ub0, sc0);
        if (nch > 4) issue(4, ub0, sc0);
        if (nch > 1) consume(ub1, sc1);
        if (nch > 5) issue(5, ub1, sc1);
        if (nch > 2) consume(ub2, sc2);
        if (nch > 6) issue(6, ub2, sc2);
        if (nch > 3) consume(ub3, sc3);
        if (nch > 7) issue(7, ub3, sc3);
        if (nch > 4) consume(ub0, sc0);
        if (nch > 5) consume(ub1, sc1);
        if (nch > 6) consume(ub2, sc2);
        if (nch > 7) consume(ub3, sc3);

        done += rem;
    }

    {
        float f[8];
        dec4_fp8(uself.x, f);
        dec4_fp8(uself.y, f + 4);
        const float s = (grp == 0) ? dA : 0.f;
#pragma unroll
        for (int k = 0; k < 8; ++k) acc[k] = fmaf(f[k], s, acc[k]);
    }

#pragma unroll
    for (int k = 0; k < 8; ++k) {
        acc[k] += __shfl_xor(acc[k], 8);
        acc[k] += __shfl_xor(acc[k], 16);
        acc[k] += __shfl_xor(acc[k], 32);
    }

    if (grp == 0) {
        const int col0 = sub << 3;
        float o[8];
#pragma unroll
        for (int k = 0; k < 8; ++k)
            o[k] = fmaxf(0.5f * (acc[k] + ba[col0 + k] + bb[col0 + k]), 0.f);
        float4 v0 = {o[0], o[1], o[2], o[3]};
        float4 v1 = {o[4], o[5], o[6], o[7]};
        *(float4*)(out + ((size_t)d << 6) + col0) = v0;
        *(float4*)(out + ((size_t)d << 6) + col0 + 4) = v1;
    }
}

__global__ __launch_bounds__(256) void gather_both(
    const unsigned char* __restrict__ m_uu, const unsigned char* __restrict__ m_tu,
    const unsigned char* __restrict__ m_tt, const unsigned char* __restrict__ m_ut,
    const int4* __restrict__ meta,
    const int* __restrict__ colU, const int* __restrict__ colT,
    const float* __restrict__ bU0, const float* __restrict__ bU1,
    const float* __restrict__ bT0, const float* __restrict__ bT1,
    float* __restrict__ hu, float* __restrict__ ht) {
    int b = blockIdx.x;
    if (b < GBU) {
        gather_dev(b, m_uu, m_tu, meta, colU, bU0, bU1, hu, NU_);
    } else {
        gather_dev(b - GBU, m_tt, m_ut, meta + NU_, colT, bT0, bT1, ht, NT_);
    }
}

// ---------------- CSR scan kernels (dinv folded in) ----------------
__global__ __launch_bounds__(256) void scan1m(const int* __restrict__ hist, int* __restrict__ rp,
                                              int* __restrict__ bsums, float* __restrict__ dinv) {
    int b = blockIdx.x, t = threadIdx.x;
    int r, lb, n, rpbase, oA, oB;
    if (b < NBU) { r = 0; lb = b;       n = NU_; rpbase = 0;   oA = OFF0; oB = OFF3; }
    else         { r = 1; lb = b - NBU; n = NT_; rpbase = NU_; oA = OFF1; oB = OFF2; }
    int i = lb * 256 + t;
    int hA = (i < n) ? hist[oA + i] : 0;
    int hB = (i < n) ? hist[oB + i] : 0;
    if (i < n) {
        dinv[oA + i] = rsqrtf((float)hA + 1.0f);                       // self-loop type
        dinv[oB + i] = (hB > 0) ? rsqrtf((float)hB) : 0.f;             // bipartite dst
    }
    int v = hA + hB;
    __shared__ int s[256];
    s[t] = v;
    __syncthreads();
    for (int off = 1; off < 256; off <<= 1) {
        int x = (t >= off) ? s[t - off] : 0;
        __syncthreads();
        s[t] += x;
        __syncthreads();
    }
    if (i < n) rp[rpbase + i] = s[t] - v;
    if (t == 255) bsums[r * 1024 + lb] = s[255];
}

__global__ __launch_bounds__(1024) void scan2m(int* __restrict__ bsums) {
    int r = blockIdx.x, t = threadIdx.x;
    const int nb = r ? NBT : NBU;
    int v = (t < nb) ? bsums[r * 1024 + t] : 0;
    __shared__ int s[1024];
    s[t] = v;
    __syncthreads();
    for (int off = 1; off < 1024; off <<= 1) {
        int x = (t >= off) ? s[t - off] : 0;
        __syncthreads();
        s[t] += x;
        __syncthreads();
    }
    if (t < nb) bsums[r * 1024 + t] = s[t] - v;
}

// scan3m: finalize rp, src dinv, and pack gather metadata {rp, cnt, dA, dB}
__global__ void scan3m(int* __restrict__ rp, const int* __restrict__ bsums,
                       const int* __restrict__ hist, float* __restrict__ dinv,
                       int4* __restrict__ meta) {
    int gid = blockIdx.x * blockDim.x + threadIdx.x;
    if (gid >= RPT2) return;
    int r = (gid < NU_) ? 0 : 1;
    int base = r ? NU_ : 0;
    int lb = (gid - base) >> 8;
    int rpf = rp[gid] + bsums[r * 1024 + lb];
    rp[gid] = rpf;
    // src dinv (for GEMM scaling)
    int si = r ? (OFF5 + gid - NU_) : (OFF4 + gid);
    int h = hist[si];
    dinv[si] = (h > 0) ? rsqrtf((float)h) : 0.f;
    // packed gather meta
    int oA = r ? (OFF1 + gid - NU_) : (OFF0 + gid);
    int oB = r ? (OFF2 + gid - NU_) : (OFF3 + gid);
    int hA = hist[oA];
    int hB = hist[oB];
    float dA = rsqrtf((float)hA + 1.0f);
    float dB = (hB > 0) ? rsqrtf((float)hB) : 0.f;
    int4 mt;
    mt.x = rpf;
    mt.y = hA + hB;
    mt.z = __float_as_int(dA);
    mt.w = __float_as_int(dB);
    meta[gid] = mt;
}

// ---------------- readout ----------------
__global__ __launch_bounds__(256) void colmean_both(const float* __restrict__ hu,
                                                    const float* __restrict__ ht,
                                                    float* __restrict__ gsum) {
    const bool isU = blockIdx.x < 512;
    const float* h = isU ? hu : ht;
    const int n = isU ? NU_ : NT_;
    const float scale = isU ? 0.5f / NU_ : 0.5f / NT_;
    const int blk = isU ? blockIdx.x : blockIdx.x - 512;
    const int lane = threadIdx.x & 63;
    const int w = threadIdx.x >> 6;
    float s = 0.f;
    for (int r = blk * 4 + w; r < n; r += 512 * 4)
        s += h[(size_t)r * HD + lane];
    __shared__ float red[256];
    red[threadIdx.x] = s;
    __syncthreads();
    if (threadIdx.x < 64) {
        float t = red[threadIdx.x] + red[64 + threadIdx.x] + red[128 + threadIdx.x] +
                  red[192 + threadIdx.x];
        atomicAdd(&gsum[lane], t * scale);
    }
}

__global__ void head(const float* __restrict__ g, const float* __restrict__ W1,
                     const float* __restrict__ b1, const float* __restrict__ W2,
                     const float* __restrict__ b2, const int* __restrict__ flag,
                     void* __restrict__ out) {
    const int c = threadIdx.x;
    float x = b1[c];
    for (int k = 0; k < HD; ++k) x = fmaf(g[k], W1[k * HD + c], x);
    x = fmaxf(x, 0.f);
    float t = x * W2[c];
    for (int off = 32; off; off >>= 1) t += __shfl_down(t, off);
    if (c == 0) {
        float z = t + b2[0];
        float s = 1.f / (1.f + expf(-z));
        if (flag[0]) *(__hip_bfloat16*)out = __float2bfloat16(s);
        else *(float*)out = s;
    }
}

extern "C" void kernel_launch(void* const* d_in, const int* in_sizes, int n_in,
                              void* d_out, int out_size, void* d_ws, size_t ws_size,
                              hipStream_t stream) {
    const void* x_user = d_in[0];
    const void* x_txn  = d_in[1];
    const int* ei_u2u = (const int*)d_in[2];
    const int* ei_t2t = (const int*)d_in[3];
    const int* ei_u2t = (const int*)d_in[4];
    const int* ei_t2u = (const int*)d_in[5];

    // ---- workspace layout ----
    float* ws = (float*)d_ws;
    float* hu = ws;                                   // NU*64 f32
    float* ht = hu + (size_t)NU_ * HD;                // NT*64 f32
    float* dinv = ht + (size_t)NT_ * HD;              // HTOT
    float* wts = dinv + HTOT;                         // 60432 (padded)
    float* gsum = wts + 60432;                        // 64
    unsigned char* m_uu = (unsigned char*)(gsum + 64);  // NU*64 fp8
    unsigned char* m_ut = m_uu + (size_t)NU_ * HD;
    unsigned char* m_tt = m_ut + (size_t)NU_ * HD;
    unsigned char* m_tu = m_tt + (size_t)NT_ * HD;
    int* hist = (int*)(m_tu + (size_t)NT_ * HD);      // HTOT
    int* aux  = hist + HTOT;                          // RPT2 region: gcnt/gbase/bofs
    int* rp   = aux + RPT2;                           // RPT2
    int* bsums = rp + RPT2;                           // 2048
    int* colU = bsums + 2048;                         // 2M
    int* colT = colU + 2 * NE_;                       // 2M
    int4* meta = (int4*)(colT + 2 * NE_);             // RPT2 (16B each)
    int* dflag = (int*)(meta + RPT2);                 // 1

    // partition bookkeeping in the old fill region (151,116 <= 300,000 ints)
    int* gcnt  = aux;               // NBKT
    int* gbase = gcnt + NBKT;       // NBKT
    int* bofs  = gbase + NBKT;      // PB1*NBKT = 150,528

    // partition payload aliases (consumed before layer-0 gemm/place writes)
    uint2* part_csr = (uint2*)m_uu;
    unsigned int* part_src = (unsigned int*)colU;

    // fp32 weight sub-pointers
    float* Wembu = wts;              // 2048
    float* bembu = Wembu + 2048;     // 64
    float* Wembt = bembu + 64;       // 4096
    float* bembt = Wembt + 4096;     // 64
    float* convWf = bembt + 64;      // 49152
    float* convbf = convWf + 49152;  // 768
    float* W1f = convbf + 768;       // 4096
    float* b1f = W1f + 4096;         // 64
    float* W2f = b1f + 64;           // 64
    float* b2f = W2f + 64;           // 1

    hipMemsetAsync(gcnt, 0, (size_t)NBKT * sizeof(int), stream);

    detect_dtype<<<1, 256, 0, stream>>>((const unsigned short*)x_user, dflag, 2048);
    {
        Ptr10 p;
        for (int k = 0; k < 10; ++k) p.p[k] = d_in[6 + k];
        cvt_weights<<<(60417 + 255) / 256, 256, 0, stream>>>(p, wts, gsum, dflag);
    }

    // ---- fused: partition pass 1 (LDS counts) + embedding GEMMs ----
    fused_p1_embed<<<PB1 + EU + ET, 256, 0, stream>>>(
        ei_u2u, ei_t2t, ei_u2t, ei_t2u, gcnt, bofs,
        x_user, x_txn, Wembu, bembu, Wembt, bembt, hu, ht, dflag);

    scan_buckets<<<1, 512, 0, stream>>>(gcnt, gbase);
    p2_scatter<<<PB1, 256, 0, stream>>>(ei_u2u, ei_t2t, ei_u2t, ei_t2u,
                                        gbase, bofs, part_csr, part_src);
    bucket_count<<<NBKT, 1024, 0, stream>>>(part_csr, part_src, gcnt, gbase, hist);

    scan1m<<<NBTOT2, 256, 0, stream>>>(hist, rp, bsums, dinv);
    scan2m<<<2, 1024, 0, stream>>>(bsums);
    scan3m<<<(RPT2 + 255) / 256, 256, 0, stream>>>(rp, bsums, hist, dinv, meta);

    bucket_place<<<NBKC, 1024, 0, stream>>>(part_csr, gcnt, gbase, rp, colU, colT);

    for (int l = 0; l < NL; ++l) {
        const float* W0   = convWf + ((size_t)l * 4 + 0) * HD * HD;
        const float* Wt   = convWf + ((size_t)l * 4 + 1) * HD * HD;
        const float* Wu2t = convWf + ((size_t)l * 4 + 2) * HD * HD;
        const float* Wt2u = convWf + ((size_t)l * 4 + 3) * HD * HD;
        const float* B0   = convbf + ((size_t)l * 4 + 0) * HD;
        const float* Bt   = convbf + ((size_t)l * 4 + 1) * HD;
        const float* Bu2t = convbf + ((size_t)l * 4 + 2) * HD;
        const float* Bt2u = convbf + ((size_t)l * 4 + 3) * HD;

        gemm_dual_both<<<GMU + GMT, 256, 0, stream>>>(hu, ht, W0, Wu2t, Wt, Wt2u, dinv,
                                                      m_uu, m_ut, m_tt, m_tu);

        gather_both<<<GBU + GBT, 256, 0, stream>>>(m_uu, m_tu, m_tt, m_ut,
                                                   meta, colU, colT,
                                                   B0, Bt2u, Bt, Bu2t, hu, ht);
    }

    // ---- readout ----
    colmean_both<<<1024, 256, 0, stream>>>(hu, ht, gsum);
    head<<<1, 64, 0, stream>>>(gsum, W1f, b1f, W2f, b2f, dflag, d_out);
}

// Round 5
// 843.838 us; speedup vs baseline: 2.2684x; 1.2078x over previous
//
#include <hip/hip_runtime.h>
#include <hip/hip_bf16.h>
#include <hip/hip_fp8.h>

#define NU_ 100000
#define NT_ 200000
#define NE_ 1000000
#define HD  64
#define NL  3

// hist/dinv region offsets (node-keyed arrays)
#define OFF0 0                   // u2u dst (NU)  [selfloop]
#define OFF1 (NU_)               // t2t dst (NT)  [selfloop]
#define OFF2 (NU_ + NT_)         // u2t dst (NT)
#define OFF3 (NU_ + 2 * NT_)     // t2u dst (NU)
#define OFF4 (2 * NU_ + 2 * NT_) // u2t src (NU)
#define OFF5 (3 * NU_ + 2 * NT_) // t2u src (NT)
#define HTOT (3 * NU_ + 3 * NT_) // 900k
#define RPT2 (NU_ + NT_)         // merged rp size (300k)

// merged scan partition (256/block)
#define NBU 391
#define NBT 782
#define NBTOT2 (NBU + NBT)

// bucket partition (no-far-atomic CSR build)
#define PB1  512           // partition blocks (256 threads each); p1/p2 must match
#define BKP  2048          // node-keys per bucket (key >> 11)
#define NBKC 147           // CSR buckets  (300k / 2048)
#define NBKS 147           // src buckets  (300k / 2048)
#define NBKT (NBKC + NBKS) // 294

// fused grids
#define EMU 512            // mfma embed user blocks (2048 waves, 6250 tiles)
#define EMT 1024           // mfma embed txn blocks (4096 waves, 12500 tiles)
#define GMU 512            // mfma gemm user blocks
#define GMT 1024           // mfma gemm txn blocks
#define GBU 25000          // ceil(NU/4) gather blocks (user)
#define GBT 50000          // ceil(NT/4) gather blocks (txn)

typedef float floatx2 __attribute__((ext_vector_type(2)));
typedef _Float16 f16x8 __attribute__((ext_vector_type(8)));
typedef float f32x4 __attribute__((ext_vector_type(4)));
typedef unsigned short u16x8 __attribute__((ext_vector_type(8)));

// ---------------- fp8 helpers ----------------
__device__ __forceinline__ unsigned char enc_fp8(float v) {
    return (unsigned char)__hip_cvt_float_to_fp8(v, __HIP_SATFINITE, __HIP_E4M3);
}

__device__ __forceinline__ float dec1_fp8(unsigned int u) {
    int e = (u >> 3) & 15;
    int m = u & 7;
    int mant = m | (e ? 8 : 0);
    if (u & 0x80) mant = -mant;
    int ex = (e ? e : 1) - 10;
    return (float)mant * __uint_as_float((unsigned int)(ex + 127) << 23);
}

__device__ __forceinline__ void dec4_fp8(unsigned int u, float* f) {
#if __has_builtin(__builtin_amdgcn_cvt_pk_f32_fp8)
    floatx2 lo = __builtin_amdgcn_cvt_pk_f32_fp8((int)u, false);
    floatx2 hi = __builtin_amdgcn_cvt_pk_f32_fp8((int)u, true);
    f[0] = lo.x; f[1] = lo.y; f[2] = hi.x; f[3] = hi.y;
#else
    f[0] = dec1_fp8(u & 0xff);
    f[1] = dec1_fp8((u >> 8) & 0xff);
    f[2] = dec1_fp8((u >> 16) & 0xff);
    f[3] = dec1_fp8((u >> 24) & 0xff);
#endif
}

// ---------------- dtype detection ----------------
__global__ void detect_dtype(const unsigned short* __restrict__ x, int* __restrict__ flag, int n) {
    __shared__ int s_big;
    if (threadIdx.x == 0) s_big = 0;
    __syncthreads();
    int big = 0;
    for (int i = threadIdx.x; i < n; i += blockDim.x) {
        float v = __uint_as_float(((unsigned int)x[i]) << 16);
        if (!(fabsf(v) < 1.0e4f)) big = 1;
    }
    if (big) atomicAdd(&s_big, 1);
    __syncthreads();
    if (threadIdx.x == 0) flag[0] = (s_big > 0) ? 0 : 1;
}

// ---------------- fused weight conversion (+ gsum zero) ----------------
struct Ptr10 { const void* p[10]; };

__global__ void cvt_weights(Ptr10 src, float* __restrict__ dst, float* __restrict__ gsum,
                            const int* __restrict__ flag) {
    const int c[11] = {0, 2048, 2112, 6208, 6272, 55424, 56192, 60288, 60352, 60416, 60417};
    int i = blockIdx.x * blockDim.x + threadIdx.x;
    if (i < 64) gsum[i] = 0.f;
    if (i >= 60417) return;
    int r = 0;
#pragma unroll
    for (int k = 1; k < 10; ++k)
        if (i >= c[k]) r = k;
    int e = i - c[r];
    if (flag[0]) {
        unsigned short u = ((const unsigned short*)src.p[r])[e];
        dst[i] = __uint_as_float(((unsigned int)u) << 16);
    } else {
        dst[i] = ((const float*)src.p[r])[e];
    }
}

// ---------------- partition pass 1: per-block bucket counts (LDS) ----------------
__device__ __forceinline__ void p1_dev(int bid, const int* __restrict__ eu2u,
                                       const int* __restrict__ et2t,
                                       const int* __restrict__ eu2t,
                                       const int* __restrict__ et2u,
                                       int* __restrict__ gcnt, int* __restrict__ bofs) {
    __shared__ int cnt[NBKT];
    for (int j = threadIdx.x; j < NBKT; j += 256) cnt[j] = 0;
    __syncthreads();
    for (int i = bid * 256 + threadIdx.x; i < 6 * NE_; i += PB1 * 256) {
        int b;
        if (i < 4 * NE_) {
            int m;
            if (i < NE_)          m = eu2u[i + NE_];
            else if (i < 2 * NE_) m = NU_ + et2t[i];          // (i-NE_) + NE_
            else if (i < 3 * NE_) m = NU_ + eu2t[i - NE_];    // (i-2NE_) + NE_
            else                  m = et2u[i - 2 * NE_];      // (i-3NE_) + NE_
            b = m >> 11;
        } else {
            int m2 = (i < 5 * NE_) ? eu2t[i - 4 * NE_] : (NU_ + et2u[i - 5 * NE_]);
            b = NBKC + (m2 >> 11);
        }
        atomicAdd(&cnt[b], 1);
    }
    __syncthreads();
    for (int j = threadIdx.x; j < NBKT; j += 256) {
        bofs[bid * NBKT + j] = atomicAdd(&gcnt[j], cnt[j]);
    }
}

// ---------------- MFMA embed: out[16x64] = X[16xK] @ W[Kx64] + bias ----------------
// Fragment layout (m89-verified, identical to gemm_mfma_dev):
// A row=lane&15, k=8*(lane>>4)+j (+32s); B col=lane&15; C col=lane&15, row=4*(lane>>4)+reg.
template <int K>
__device__ __forceinline__ void embed_mfma_dev(int t0, int tstride, int ntiles,
                                               const void* __restrict__ x,
                                               const float* __restrict__ W,
                                               const float* __restrict__ bias,
                                               float* __restrict__ out,
                                               const int* __restrict__ flag) {
    constexpr int KS = K / 32;
    const int lane = threadIdx.x & 63;
    const int rq = lane & 15;
    const int oct = lane >> 4;

    f16x8 bf[4][KS];
#pragma unroll
    for (int ct = 0; ct < 4; ++ct)
#pragma unroll
        for (int s = 0; s < KS; ++s) {
            const float* wp = W + (size_t)(32 * s + 8 * oct) * HD + 16 * ct + rq;
            f16x8 v;
#pragma unroll
            for (int j = 0; j < 8; ++j) v[j] = (_Float16)wp[(size_t)j * HD];
            bf[ct][s] = v;
        }
    float bv[4];
#pragma unroll
    for (int ct = 0; ct < 4; ++ct) bv[ct] = bias[16 * ct + rq];

    const bool isb = flag[0] != 0;

    for (int t = t0; t < ntiles; t += tstride) {
        const int r0 = t << 4;
        f16x8 a[KS];
        if (isb) {
            const unsigned short* xr = (const unsigned short*)x + (size_t)(r0 + rq) * K + 8 * oct;
#pragma unroll
            for (int s = 0; s < KS; ++s) {
                u16x8 uv = *(const u16x8*)(xr + 32 * s);
                f16x8 v;
#pragma unroll
                for (int j = 0; j < 8; ++j)
                    v[j] = (_Float16)__uint_as_float(((unsigned int)uv[j]) << 16);
                a[s] = v;
            }
        } else {
            const float* xr = (const float*)x + (size_t)(r0 + rq) * K + 8 * oct;
#pragma unroll
            for (int s = 0; s < KS; ++s) {
                float4 x0 = *(const float4*)(xr + 32 * s);
                float4 x1 = *(const float4*)(xr + 32 * s + 4);
                f16x8 v;
                v[0] = (_Float16)x0.x; v[1] = (_Float16)x0.y;
                v[2] = (_Float16)x0.z; v[3] = (_Float16)x0.w;
                v[4] = (_Float16)x1.x; v[5] = (_Float16)x1.y;
                v[6] = (_Float16)x1.z; v[7] = (_Float16)x1.w;
                a[s] = v;
            }
        }

        f32x4 acc[4];
#pragma unroll
        for (int ct = 0; ct < 4; ++ct) acc[ct] = (f32x4){0.f, 0.f, 0.f, 0.f};
#pragma unroll
        for (int ct = 0; ct < 4; ++ct)
#pragma unroll
            for (int s = 0; s < KS; ++s)
                acc[ct] = __builtin_amdgcn_mfma_f32_16x16x32_f16(a[s], bf[ct][s], acc[ct], 0, 0, 0);

        const int rb = r0 + (oct << 2);
#pragma unroll
        for (int ct = 0; ct < 4; ++ct)
#pragma unroll
            for (int g = 0; g < 4; ++g)
                out[(size_t)(rb + g) * HD + 16 * ct + rq] = acc[ct][g] + bv[ct];
    }
}

__global__ __launch_bounds__(256) void fused_p1_embed(
    const int* __restrict__ eu2u, const int* __restrict__ et2t,
    const int* __restrict__ eu2t, const int* __restrict__ et2u,
    int* __restrict__ gcnt, int* __restrict__ bofs,
    const void* __restrict__ x_user, const void* __restrict__ x_txn,
    const float* __restrict__ Wembu, const float* __restrict__ bembu,
    const float* __restrict__ Wembt, const float* __restrict__ bembt,
    float* __restrict__ hu, float* __restrict__ ht, const int* __restrict__ flag) {
    int b = blockIdx.x;
    int wid = threadIdx.x >> 6;
    if (b < PB1) {
        p1_dev(b, eu2u, et2t, eu2t, et2u, gcnt, bofs);
    } else if (b < PB1 + EMU) {
        embed_mfma_dev<32>((b - PB1) * 4 + wid, EMU * 4, NU_ / 16, x_user, Wembu, bembu,
                           hu, flag);
    } else {
        embed_mfma_dev<64>((b - PB1 - EMU) * 4 + wid, EMT * 4, NT_ / 16, x_txn, Wembt, bembt,
                           ht, flag);
    }
}

// ---------------- bucket base scan (two independent segments) ----------------
__global__ void scan_buckets(const int* __restrict__ gcnt, int* __restrict__ gbase) {
    __shared__ int sc[NBKT];
    int t = threadIdx.x;
    if (t < NBKT) sc[t] = gcnt[t];
    __syncthreads();
    if (t == 0) {
        int s = 0;
        for (int j = 0; j < NBKC; ++j) { int c = sc[j]; sc[j] = s; s += c; }
        s = 0;
        for (int j = NBKC; j < NBKT; ++j) { int c = sc[j]; sc[j] = s; s += c; }
    }
    __syncthreads();
    if (t < NBKT) gbase[t] = sc[t];
}

// ---------------- partition pass 2: scatter (must mirror p1's item mapping) ----------------
__global__ __launch_bounds__(256) void p2_scatter(
    const int* __restrict__ eu2u, const int* __restrict__ et2t,
    const int* __restrict__ eu2t, const int* __restrict__ et2u,
    const int* __restrict__ gbase, const int* __restrict__ bofs,
    uint2* __restrict__ part_csr, unsigned int* __restrict__ part_src) {
    __shared__ int lofs[NBKT];
    for (int j = threadIdx.x; j < NBKT; j += 256) lofs[j] = 0;
    __syncthreads();
    const int bid = blockIdx.x;
    for (int i = bid * 256 + threadIdx.x; i < 6 * NE_; i += PB1 * 256) {
        if (i < 4 * NE_) {
            int m; unsigned int p;
            if (i < NE_)          { m = eu2u[i + NE_];           p = (unsigned int)eu2u[i]; }
            else if (i < 2 * NE_) { m = NU_ + et2t[i];           p = (unsigned int)et2t[i - NE_]; }
            else if (i < 3 * NE_) { m = NU_ + eu2t[i - NE_];     p = (unsigned int)eu2t[i - 2 * NE_] | 0x80000000u; }
            else                  { m = et2u[i - 2 * NE_];       p = (unsigned int)et2u[i - 3 * NE_] | 0x80000000u; }
            int b = m >> 11;
            int l = atomicAdd(&lofs[b], 1);
            int pos = gbase[b] + bofs[bid * NBKT + b] + l;
            part_csr[pos] = make_uint2((unsigned int)m, p);
        } else {
            int m2 = (i < 5 * NE_) ? eu2t[i - 4 * NE_] : (NU_ + et2u[i - 5 * NE_]);
            int b = NBKC + (m2 >> 11);
            int l = atomicAdd(&lofs[b], 1);
            int pos = gbase[b] + bofs[bid * NBKT + b] + l;
            part_src[pos] = (unsigned int)m2;
        }
    }
}

// ---------------- per-bucket exact counting (LDS atomics only) ----------------
__global__ __launch_bounds__(1024) void bucket_count(const uint2* __restrict__ part_csr,
                                                     const unsigned int* __restrict__ part_src,
                                                     const int* __restrict__ gcnt,
                                                     const int* __restrict__ gbase,
                                                     int* __restrict__ hist) {
    __shared__ int cA[BKP];
    __shared__ int cB[BKP];
    const int b = blockIdx.x;
    const int n = gcnt[b];
    const int base = gbase[b];
    const int t = threadIdx.x;
    for (int j = t; j < BKP; j += 1024) { cA[j] = 0; cB[j] = 0; }
    __syncthreads();
    if (b < NBKC) {
        for (int i = t; i < n; i += 1024) {
            uint2 it = part_csr[base + i];
            int l = (int)(it.x & (BKP - 1));
            if (it.y >> 31) atomicAdd(&cB[l], 1);
            else            atomicAdd(&cA[l], 1);
        }
        __syncthreads();
        const int m0 = b << 11;
        for (int j = t; j < BKP; j += 1024) {
            int m = m0 + j;
            if (m < NU_ + NT_) {
                int oA = (m < NU_) ? (OFF0 + m) : (OFF1 + (m - NU_));
                int oB = (m < NU_) ? (OFF3 + m) : (OFF2 + (m - NU_));
                hist[oA] = cA[j];
                hist[oB] = cB[j];
            }
        }
    } else {
        for (int i = t; i < n; i += 1024) {
            unsigned int m2 = part_src[base + i];
            atomicAdd(&cA[(int)(m2 & (BKP - 1))], 1);
        }
        __syncthreads();
        const int m0 = (b - NBKC) << 11;
        for (int j = t; j < BKP; j += 1024) {
            int m2 = m0 + j;
            if (m2 < NU_ + NT_) {
                int o = (m2 < NU_) ? (OFF4 + m2) : (OFF5 + (m2 - NU_));
                hist[o] = cA[j];
            }
        }
    }
}

// ---------------- per-bucket CSR placement (LDS bump allocators) ----------------
__global__ __launch_bounds__(1024) void bucket_place(const uint2* __restrict__ part_csr,
                                                     const int* __restrict__ gcnt,
                                                     const int* __restrict__ gbase,
                                                     const int* __restrict__ rp,
                                                     int* __restrict__ colU,
                                                     int* __restrict__ colT) {
    __shared__ int fl[BKP];
    const int b = blockIdx.x;
    const int n = gcnt[b];
    const int base = gbase[b];
    const int t = threadIdx.x;
    for (int j = t; j < BKP; j += 1024) fl[j] = 0;
    __syncthreads();
    for (int i = t; i < n; i += 1024) {
        uint2 it = part_csr[base + i];
        int m = (int)it.x;
        int ofs = atomicAdd(&fl[m & (BKP - 1)], 1);
        if (m < NU_) colU[rp[m] + ofs] = (int)it.y;
        else         colT[rp[m] + ofs] = (int)it.y;
    }
}

// ---------------- MFMA dual GEMM ----------------
__device__ __forceinline__ void gemm_mfma_dev(int t0, int tstride, int ntiles,
                                              const float* __restrict__ h,
                                              const float* __restrict__ WA,
                                              const float* __restrict__ WB,
                                              const float* __restrict__ scA,
                                              const float* __restrict__ scB,
                                              unsigned char* __restrict__ mA,
                                              unsigned char* __restrict__ mB) {
    const int lane = threadIdx.x & 63;
    const int rq = lane & 15;
    const int oct = lane >> 4;

    // preload 16 weight fragments (f32 -> f16): [mat][coltile][kstep]
    f16x8 bf[2][4][2];
#pragma unroll
    for (int m = 0; m < 2; ++m) {
        const float* W = m ? WB : WA;
#pragma unroll
        for (int ct = 0; ct < 4; ++ct)
#pragma unroll
            for (int s = 0; s < 2; ++s) {
                const float* wp = W + (size_t)(32 * s + 8 * oct) * HD + 16 * ct + rq;
                f16x8 v;
#pragma unroll
                for (int j = 0; j < 8; ++j) v[j] = (_Float16)wp[(size_t)j * HD];
                bf[m][ct][s] = v;
            }
    }

    for (int t = t0; t < ntiles; t += tstride) {
        const int r0 = t << 4;
        const float* hr = h + (size_t)(r0 + rq) * HD + 8 * oct;
        float4 x0 = *(const float4*)(hr);
        float4 x1 = *(const float4*)(hr + 4);
        float4 y0 = *(const float4*)(hr + 32);
        float4 y1 = *(const float4*)(hr + 36);
        f16x8 a0, a1;
        a0[0] = (_Float16)x0.x; a0[1] = (_Float16)x0.y;
        a0[2] = (_Float16)x0.z; a0[3] = (_Float16)x0.w;
        a0[4] = (_Float16)x1.x; a0[5] = (_Float16)x1.y;
        a0[6] = (_Float16)x1.z; a0[7] = (_Float16)x1.w;
        a1[0] = (_Float16)y0.x; a1[1] = (_Float16)y0.y;
        a1[2] = (_Float16)y0.z; a1[3] = (_Float16)y0.w;
        a1[4] = (_Float16)y1.x; a1[5] = (_Float16)y1.y;
        a1[6] = (_Float16)y1.z; a1[7] = (_Float16)y1.w;

        f32x4 acc[2][4];
#pragma unroll
        for (int m = 0; m < 2; ++m)
#pragma unroll
            for (int ct = 0; ct < 4; ++ct) acc[m][ct] = (f32x4){0.f, 0.f, 0.f, 0.f};

#pragma unroll
        for (int m = 0; m < 2; ++m)
#pragma unroll
            for (int ct = 0; ct < 4; ++ct) {
                acc[m][ct] = __builtin_amdgcn_mfma_f32_16x16x32_f16(a0, bf[m][ct][0],
                                                                   acc[m][ct], 0, 0, 0);
                acc[m][ct] = __builtin_amdgcn_mfma_f32_16x16x32_f16(a1, bf[m][ct][1],
                                                                   acc[m][ct], 0, 0, 0);
            }

        const int rb = r0 + (oct << 2);
        float sa[4], sb[4];
#pragma unroll
        for (int g = 0; g < 4; ++g) { sa[g] = scA[rb + g]; sb[g] = scB[rb + g]; }
#pragma unroll
        for (int ct = 0; ct < 4; ++ct)
#pragma unroll
            for (int g = 0; g < 4; ++g) {
                mA[(size_t)(rb + g) * HD + 16 * ct + rq] = enc_fp8(acc[0][ct][g] * sa[g]);
                mB[(size_t)(rb + g) * HD + 16 * ct + rq] = enc_fp8(acc[1][ct][g] * sb[g]);
            }
    }
}

__global__ __launch_bounds__(256) void gemm_dual_both(
    const float* __restrict__ hu, const float* __restrict__ ht,
    const float* __restrict__ W0, const float* __restrict__ Wu2t,
    const float* __restrict__ Wt, const float* __restrict__ Wt2u,
    const float* __restrict__ dinv,
    unsigned char* __restrict__ m_uu, unsigned char* __restrict__ m_ut,
    unsigned char* __restrict__ m_tt, unsigned char* __restrict__ m_tu) {
    int b = blockIdx.x;
    int wid = threadIdx.x >> 6;
    if (b < GMU) {
        gemm_mfma_dev(b * 4 + wid, GMU * 4, NU_ / 16, hu, W0, Wu2t,
                      dinv + OFF0, dinv + OFF4, m_uu, m_ut);
    } else {
        gemm_mfma_dev((b - GMU) * 4 + wid, GMT * 4, NT_ / 16, ht, Wt, Wt2u,
                      dinv + OFF1, dinv + OFF5, m_tt, m_tu);
    }
}

// ---------------- gather (proven body, unchanged) ----------------
__device__ __forceinline__ void gather_dev(int blk, const unsigned char* __restrict__ mA,
                                           const unsigned char* __restrict__ mB,
                                           const int4* __restrict__ meta,
                                           const int* __restrict__ col,
                                           const float* __restrict__ ba,
                                           const float* __restrict__ bb,
                                           float* __restrict__ out, int N) {
    const int lane = threadIdx.x & 63;
    const int grp = lane >> 3;
    const int sub = lane & 7;
    const int d = (blk << 2) + (threadIdx.x >> 6);
    if (d >= N) return;

    const int4 mt = meta[d];
    const int st = mt.x;
    const int cnt = mt.y;
    const float dA = __int_as_float(mt.z);
    const float dB = __int_as_float(mt.w);
    float acc[8] = {0.f, 0.f, 0.f, 0.f, 0.f, 0.f, 0.f, 0.f};

    const uint2 uself = *(const uint2*)(mA + ((size_t)d << 6) + (sub << 3));

    int done = 0;
    while (done < cnt) {
        int rem = cnt - done;
        if (rem > 64) rem = 64;
        int cw = (lane < rem) ? col[st + done + lane] : 0;
        const int nch = (rem + 7) >> 3;

        uint2 ub0, ub1, ub2, ub3;
        float sc0, sc1, sc2, sc3;

        auto issue = [&](int p, uint2& ub, float& sc) {
            int j = (p << 3) + grp;
            unsigned int c = (unsigned int)__shfl(cw, j);
            const unsigned char* base = (c >> 31) ? mB : mA;
            float sv = (c >> 31) ? dB : dA;
            unsigned int idx = c & 0x7fffffffu;
            sc = (j < rem) ? sv : 0.f;
            ub = *(const uint2*)(base + ((size_t)idx << 6) + (sub << 3));
        };
        auto consume = [&](uint2 u, float s) {
            float f[8];
            dec4_fp8(u.x, f);
            dec4_fp8(u.y, f + 4);
#pragma unroll
            for (int k = 0; k < 8; ++k) acc[k] = fmaf(f[k], s, acc[k]);
        };

        issue(0, ub0, sc0);
        if (nch > 1) issue(1, ub1, sc1);
        if (nch > 2) issue(2, ub2, sc2);
        if (nch > 3) issue(3, ub3, sc3);

        consume(ub0, sc0);
        if (nch > 4) issue(4, ub0, sc0);
        if (nch > 1) consume(ub1, sc1);
        if (nch > 5) issue(5, ub1, sc1);
        if (nch > 2) consume(ub2, sc2);
        if (nch > 6) issue(6, ub2, sc2);
        if (nch > 3) consume(ub3, sc3);
        if (nch > 7) issue(7, ub3, sc3);
        if (nch > 4) consume(ub0, sc0);
        if (nch > 5) consume(ub1, sc1);
        if (nch > 6) consume(ub2, sc2);
        if (nch > 7) consume(ub3, sc3);

        done += rem;
    }

    {
        float f[8];
        dec4_fp8(uself.x, f);
        dec4_fp8(uself.y, f + 4);
        const float s = (grp == 0) ? dA : 0.f;
#pragma unroll
        for (int k = 0; k < 8; ++k) acc[k] = fmaf(f[k], s, acc[k]);
    }

#pragma unroll
    for (int k = 0; k < 8; ++k) {
        acc[k] += __shfl_xor(acc[k], 8);
        acc[k] += __shfl_xor(acc[k], 16);
        acc[k] += __shfl_xor(acc[k], 32);
    }

    if (grp == 0) {
        const int col0 = sub << 3;
        float o[8];
#pragma unroll
        for (int k = 0; k < 8; ++k)
            o[k] = fmaxf(0.5f * (acc[k] + ba[col0 + k] + bb[col0 + k]), 0.f);
        float4 v0 = {o[0], o[1], o[2], o[3]};
        float4 v1 = {o[4], o[5], o[6], o[7]};
        *(float4*)(out + ((size_t)d << 6) + col0) = v0;
        *(float4*)(out + ((size_t)d << 6) + col0 + 4) = v1;
    }
}

__global__ __launch_bounds__(256) void gather_both(
    const unsigned char* __restrict__ m_uu, const unsigned char* __restrict__ m_tu,
    const unsigned char* __restrict__ m_tt, const unsigned char* __restrict__ m_ut,
    const int4* __restrict__ meta,
    const int* __restrict__ colU, const int* __restrict__ colT,
    const float* __restrict__ bU0, const float* __restrict__ bU1,
    const float* __restrict__ bT0, const float* __restrict__ bT1,
    float* __restrict__ hu, float* __restrict__ ht) {
    int b = blockIdx.x;
    if (b < GBU) {
        gather_dev(b, m_uu, m_tu, meta, colU, bU0, bU1, hu, NU_);
    } else {
        gather_dev(b - GBU, m_tt, m_ut, meta + NU_, colT, bT0, bT1, ht, NT_);
    }
}

// ---------------- CSR scan kernels (dinv folded in) ----------------
__global__ __launch_bounds__(256) void scan1m(const int* __restrict__ hist, int* __restrict__ rp,
                                              int* __restrict__ bsums, float* __restrict__ dinv) {
    int b = blockIdx.x, t = threadIdx.x;
    int r, lb, n, rpbase, oA, oB;
    if (b < NBU) { r = 0; lb = b;       n = NU_; rpbase = 0;   oA = OFF0; oB = OFF3; }
    else         { r = 1; lb = b - NBU; n = NT_; rpbase = NU_; oA = OFF1; oB = OFF2; }
    int i = lb * 256 + t;
    int hA = (i < n) ? hist[oA + i] : 0;
    int hB = (i < n) ? hist[oB + i] : 0;
    if (i < n) {
        dinv[oA + i] = rsqrtf((float)hA + 1.0f);                       // self-loop type
        dinv[oB + i] = (hB > 0) ? rsqrtf((float)hB) : 0.f;             // bipartite dst
    }
    int v = hA + hB;
    __shared__ int s[256];
    s[t] = v;
    __syncthreads();
    for (int off = 1; off < 256; off <<= 1) {
        int x = (t >= off) ? s[t - off] : 0;
        __syncthreads();
        s[t] += x;
        __syncthreads();
    }
    if (i < n) rp[rpbase + i] = s[t] - v;
    if (t == 255) bsums[r * 1024 + lb] = s[255];
}

__global__ __launch_bounds__(1024) void scan2m(int* __restrict__ bsums) {
    int r = blockIdx.x, t = threadIdx.x;
    const int nb = r ? NBT : NBU;
    int v = (t < nb) ? bsums[r * 1024 + t] : 0;
    __shared__ int s[1024];
    s[t] = v;
    __syncthreads();
    for (int off = 1; off < 1024; off <<= 1) {
        int x = (t >= off) ? s[t - off] : 0;
        __syncthreads();
        s[t] += x;
        __syncthreads();
    }
    if (t < nb) bsums[r * 1024 + t] = s[t] - v;
}

// scan3m: finalize rp, src dinv, and pack gather metadata {rp, cnt, dA, dB}
__global__ void scan3m(int* __restrict__ rp, const int* __restrict__ bsums,
                       const int* __restrict__ hist, float* __restrict__ dinv,
                       int4* __restrict__ meta) {
    int gid = blockIdx.x * blockDim.x + threadIdx.x;
    if (gid >= RPT2) return;
    int r = (gid < NU_) ? 0 : 1;
    int base = r ? NU_ : 0;
    int lb = (gid - base) >> 8;
    int rpf = rp[gid] + bsums[r * 1024 + lb];
    rp[gid] = rpf;
    // src dinv (for GEMM scaling)
    int si = r ? (OFF5 + gid - NU_) : (OFF4 + gid);
    int h = hist[si];
    dinv[si] = (h > 0) ? rsqrtf((float)h) : 0.f;
    // packed gather meta
    int oA = r ? (OFF1 + gid - NU_) : (OFF0 + gid);
    int oB = r ? (OFF2 + gid - NU_) : (OFF3 + gid);
    int hA = hist[oA];
    int hB = hist[oB];
    float dA = rsqrtf((float)hA + 1.0f);
    float dB = (hB > 0) ? rsqrtf((float)hB) : 0.f;
    int4 mt;
    mt.x = rpf;
    mt.y = hA + hB;
    mt.z = __float_as_int(dA);
    mt.w = __float_as_int(dB);
    meta[gid] = mt;
}

// ---------------- readout ----------------
__global__ __launch_bounds__(256) void colmean_both(const float* __restrict__ hu,
                                                    const float* __restrict__ ht,
                                                    float* __restrict__ gsum) {
    const bool isU = blockIdx.x < 512;
    const float* h = isU ? hu : ht;
    const int n = isU ? NU_ : NT_;
    const float scale = isU ? 0.5f / NU_ : 0.5f / NT_;
    const int blk = isU ? blockIdx.x : blockIdx.x - 512;
    const int lane = threadIdx.x & 63;
    const int w = threadIdx.x >> 6;
    float s = 0.f;
    for (int r = blk * 4 + w; r < n; r += 512 * 4)
        s += h[(size_t)r * HD + lane];
    __shared__ float red[256];
    red[threadIdx.x] = s;
    __syncthreads();
    if (threadIdx.x < 64) {
        float t = red[threadIdx.x] + red[64 + threadIdx.x] + red[128 + threadIdx.x] +
                  red[192 + threadIdx.x];
        atomicAdd(&gsum[lane], t * scale);
    }
}

__global__ void head(const float* __restrict__ g, const float* __restrict__ W1,
                     const float* __restrict__ b1, const float* __restrict__ W2,
                     const float* __restrict__ b2, const int* __restrict__ flag,
                     void* __restrict__ out) {
    const int c = threadIdx.x;
    float x = b1[c];
    for (int k = 0; k < HD; ++k) x = fmaf(g[k], W1[k * HD + c], x);
    x = fmaxf(x, 0.f);
    float t = x * W2[c];
    for (int off = 32; off; off >>= 1) t += __shfl_down(t, off);
    if (c == 0) {
        float z = t + b2[0];
        float s = 1.f / (1.f + expf(-z));
        if (flag[0]) *(__hip_bfloat16*)out = __float2bfloat16(s);
        else *(float*)out = s;
    }
}

extern "C" void kernel_launch(void* const* d_in, const int* in_sizes, int n_in,
                              void* d_out, int out_size, void* d_ws, size_t ws_size,
                              hipStream_t stream) {
    const void* x_user = d_in[0];
    const void* x_txn  = d_in[1];
    const int* ei_u2u = (const int*)d_in[2];
    const int* ei_t2t = (const int*)d_in[3];
    const int* ei_u2t = (const int*)d_in[4];
    const int* ei_t2u = (const int*)d_in[5];

    // ---- workspace layout ----
    float* ws = (float*)d_ws;
    float* hu = ws;                                   // NU*64 f32
    float* ht = hu + (size_t)NU_ * HD;                // NT*64 f32
    float* dinv = ht + (size_t)NT_ * HD;              // HTOT
    float* wts = dinv + HTOT;                         // 60432 (padded)
    float* gsum = wts + 60432;                        // 64
    unsigned char* m_uu = (unsigned char*)(gsum + 64);  // NU*64 fp8
    unsigned char* m_ut = m_uu + (size_t)NU_ * HD;
    unsigned char* m_tt = m_ut + (size_t)NU_ * HD;
    unsigned char* m_tu = m_tt + (size_t)NT_ * HD;
    int* hist = (int*)(m_tu + (size_t)NT_ * HD);      // HTOT
    int* aux  = hist + HTOT;                          // RPT2 region: gcnt/gbase/bofs
    int* rp   = aux + RPT2;                           // RPT2
    int* bsums = rp + RPT2;                           // 2048
    int* colU = bsums + 2048;                         // 2M
    int* colT = colU + 2 * NE_;                       // 2M
    int4* meta = (int4*)(colT + 2 * NE_);             // RPT2 (16B each)
    int* dflag = (int*)(meta + RPT2);                 // 1

    // partition bookkeeping in the old fill region (151,116 <= 300,000 ints)
    int* gcnt  = aux;               // NBKT
    int* gbase = gcnt + NBKT;       // NBKT
    int* bofs  = gbase + NBKT;      // PB1*NBKT = 150,528

    // partition payload aliases (consumed before layer-0 gemm/place writes)
    uint2* part_csr = (uint2*)m_uu;
    unsigned int* part_src = (unsigned int*)colU;

    // fp32 weight sub-pointers
    float* Wembu = wts;              // 2048
    float* bembu = Wembu + 2048;     // 64
    float* Wembt = bembu + 64;       // 4096
    float* bembt = Wembt + 4096;     // 64
    float* convWf = bembt + 64;      // 49152
    float* convbf = convWf + 49152;  // 768
    float* W1f = convbf + 768;       // 4096
    float* b1f = W1f + 4096;         // 64
    float* W2f = b1f + 64;           // 64
    float* b2f = W2f + 64;           // 1

    hipMemsetAsync(gcnt, 0, (size_t)NBKT * sizeof(int), stream);

    detect_dtype<<<1, 256, 0, stream>>>((const unsigned short*)x_user, dflag, 2048);
    {
        Ptr10 p;
        for (int k = 0; k < 10; ++k) p.p[k] = d_in[6 + k];
        cvt_weights<<<(60417 + 255) / 256, 256, 0, stream>>>(p, wts, gsum, dflag);
    }

    // ---- fused: partition pass 1 (LDS counts) + MFMA embedding GEMMs ----
    fused_p1_embed<<<PB1 + EMU + EMT, 256, 0, stream>>>(
        ei_u2u, ei_t2t, ei_u2t, ei_t2u, gcnt, bofs,
        x_user, x_txn, Wembu, bembu, Wembt, bembt, hu, ht, dflag);

    scan_buckets<<<1, 512, 0, stream>>>(gcnt, gbase);
    p2_scatter<<<PB1, 256, 0, stream>>>(ei_u2u, ei_t2t, ei_u2t, ei_t2u,
                                        gbase, bofs, part_csr, part_src);
    bucket_count<<<NBKT, 1024, 0, stream>>>(part_csr, part_src, gcnt, gbase, hist);

    scan1m<<<NBTOT2, 256, 0, stream>>>(hist, rp, bsums, dinv);
    scan2m<<<2, 1024, 0, stream>>>(bsums);
    scan3m<<<(RPT2 + 255) / 256, 256, 0, stream>>>(rp, bsums, hist, dinv, meta);

    bucket_place<<<NBKC, 1024, 0, stream>>>(part_csr, gcnt, gbase, rp, colU, colT);

    for (int l = 0; l < NL; ++l) {
        const float* W0   = convWf + ((size_t)l * 4 + 0) * HD * HD;
        const float* Wt   = convWf + ((size_t)l * 4 + 1) * HD * HD;
        const float* Wu2t = convWf + ((size_t)l * 4 + 2) * HD * HD;
        const float* Wt2u = convWf + ((size_t)l * 4 + 3) * HD * HD;
        const float* B0   = convbf + ((size_t)l * 4 + 0) * HD;
        const float* Bt   = convbf + ((size_t)l * 4 + 1) * HD;
        const float* Bu2t = convbf + ((size_t)l * 4 + 2) * HD;
        const float* Bt2u = convbf + ((size_t)l * 4 + 3) * HD;

        gemm_dual_both<<<GMU + GMT, 256, 0, stream>>>(hu, ht, W0, Wu2t, Wt, Wt2u, dinv,
                                                      m_uu, m_ut, m_tt, m_tu);

        gather_both<<<GBU + GBT, 256, 0, stream>>>(m_uu, m_tu, m_tt, m_ut,
                                                   meta, colU, colT,
                                                   B0, Bt2u, Bt, Bu2t, hu, ht);
    }

    // ---- readout ----
    colmean_both<<<1024, 256, 0, stream>>>(hu, ht, gsum);
    head<<<1, 64, 0, stream>>>(gsum, W1f, b1f, W2f, b2f, dflag, d_out);
}

// Round 6
// 841.978 us; speedup vs baseline: 2.2734x; 1.0022x over previous
//
#include <hip/hip_runtime.h>
#include <hip/hip_bf16.h>
#include <hip/hip_fp8.h>

#define NU_ 100000
#define NT_ 200000
#define NE_ 1000000
#define HD  64
#define NL  3

// hist/dinv region offsets (node-keyed arrays)
#define OFF0 0                   // u2u dst (NU)  [selfloop]
#define OFF1 (NU_)               // t2t dst (NT)  [selfloop]
#define OFF2 (NU_ + NT_)         // u2t dst (NT)
#define OFF3 (NU_ + 2 * NT_)     // t2u dst (NU)
#define OFF4 (2 * NU_ + 2 * NT_) // u2t src (NU)
#define OFF5 (3 * NU_ + 2 * NT_) // t2u src (NT)
#define HTOT (3 * NU_ + 3 * NT_) // 900k
#define RPT2 (NU_ + NT_)         // merged rp size (300k)

// merged scan partition (256/block)
#define NBU 391
#define NBT 782
#define NBTOT2 (NBU + NBT)

// bucket partition (no-far-atomic CSR build)
#define PB1  512           // partition blocks (256 threads each); p1/p2 must match
#define BKP  2048          // node-keys per bucket (key >> 11)
#define NBKC 147           // CSR buckets  (300k / 2048)
#define NBKS 147           // src buckets  (300k / 2048)
#define NBKT (NBKC + NBKS) // 294

// fused grids
#define EMU 512            // mfma embed user blocks
#define EMT 1024           // mfma embed txn blocks
#define GMU 512            // mfma gemm user blocks
#define GMT 1024           // mfma gemm txn blocks
#define GBU 25000          // ceil(NU/4) gather blocks (user)
#define GBT 50000          // ceil(NT/4) gather blocks (txn)

typedef float floatx2 __attribute__((ext_vector_type(2)));
typedef _Float16 f16x8 __attribute__((ext_vector_type(8)));
typedef float f32x4 __attribute__((ext_vector_type(4)));
typedef unsigned short u16x8 __attribute__((ext_vector_type(8)));

// ---------------- fp8 helpers ----------------
__device__ __forceinline__ unsigned char enc_fp8(float v) {
    return (unsigned char)__hip_cvt_float_to_fp8(v, __HIP_SATFINITE, __HIP_E4M3);
}

__device__ __forceinline__ float dec1_fp8(unsigned int u) {
    int e = (u >> 3) & 15;
    int m = u & 7;
    int mant = m | (e ? 8 : 0);
    if (u & 0x80) mant = -mant;
    int ex = (e ? e : 1) - 10;
    return (float)mant * __uint_as_float((unsigned int)(ex + 127) << 23);
}

__device__ __forceinline__ void dec4_fp8(unsigned int u, float* f) {
#if __has_builtin(__builtin_amdgcn_cvt_pk_f32_fp8)
    floatx2 lo = __builtin_amdgcn_cvt_pk_f32_fp8((int)u, false);
    floatx2 hi = __builtin_amdgcn_cvt_pk_f32_fp8((int)u, true);
    f[0] = lo.x; f[1] = lo.y; f[2] = hi.x; f[3] = hi.y;
#else
    f[0] = dec1_fp8(u & 0xff);
    f[1] = dec1_fp8((u >> 8) & 0xff);
    f[2] = dec1_fp8((u >> 16) & 0xff);
    f[3] = dec1_fp8((u >> 24) & 0xff);
#endif
}

// ---------------- dtype detection ----------------
__global__ void detect_dtype(const unsigned short* __restrict__ x, int* __restrict__ flag, int n) {
    __shared__ int s_big;
    if (threadIdx.x == 0) s_big = 0;
    __syncthreads();
    int big = 0;
    for (int i = threadIdx.x; i < n; i += blockDim.x) {
        float v = __uint_as_float(((unsigned int)x[i]) << 16);
        if (!(fabsf(v) < 1.0e4f)) big = 1;
    }
    if (big) atomicAdd(&s_big, 1);
    __syncthreads();
    if (threadIdx.x == 0) flag[0] = (s_big > 0) ? 0 : 1;
}

// ---------------- fused weight conversion (+ gsum zero) ----------------
struct Ptr10 { const void* p[10]; };

__global__ void cvt_weights(Ptr10 src, float* __restrict__ dst, float* __restrict__ gsum,
                            const int* __restrict__ flag) {
    const int c[11] = {0, 2048, 2112, 6208, 6272, 55424, 56192, 60288, 60352, 60416, 60417};
    int i = blockIdx.x * blockDim.x + threadIdx.x;
    if (i < 64) gsum[i] = 0.f;
    if (i >= 60417) return;
    int r = 0;
#pragma unroll
    for (int k = 1; k < 10; ++k)
        if (i >= c[k]) r = k;
    int e = i - c[r];
    if (flag[0]) {
        unsigned short u = ((const unsigned short*)src.p[r])[e];
        dst[i] = __uint_as_float(((unsigned int)u) << 16);
    } else {
        dst[i] = ((const float*)src.p[r])[e];
    }
}

// ---------------- partition pass 1: per-block bucket counts (LDS) ----------------
__device__ __forceinline__ void p1_dev(int bid, const int* __restrict__ eu2u,
                                       const int* __restrict__ et2t,
                                       const int* __restrict__ eu2t,
                                       const int* __restrict__ et2u,
                                       int* __restrict__ gcnt, int* __restrict__ bofs) {
    __shared__ int cnt[NBKT];
    for (int j = threadIdx.x; j < NBKT; j += 256) cnt[j] = 0;
    __syncthreads();
    for (int i = bid * 256 + threadIdx.x; i < 6 * NE_; i += PB1 * 256) {
        int b;
        if (i < 4 * NE_) {
            int m;
            if (i < NE_)          m = eu2u[i + NE_];
            else if (i < 2 * NE_) m = NU_ + et2t[i];          // (i-NE_) + NE_
            else if (i < 3 * NE_) m = NU_ + eu2t[i - NE_];    // (i-2NE_) + NE_
            else                  m = et2u[i - 2 * NE_];      // (i-3NE_) + NE_
            b = m >> 11;
        } else {
            int m2 = (i < 5 * NE_) ? eu2t[i - 4 * NE_] : (NU_ + et2u[i - 5 * NE_]);
            b = NBKC + (m2 >> 11);
        }
        atomicAdd(&cnt[b], 1);
    }
    __syncthreads();
    for (int j = threadIdx.x; j < NBKT; j += 256) {
        bofs[bid * NBKT + j] = atomicAdd(&gcnt[j], cnt[j]);
    }
}

// ---------------- MFMA embed: out[16x64] = X[16xK] @ W[Kx64] + bias ----------------
template <int K>
__device__ __forceinline__ void embed_mfma_dev(int t0, int tstride, int ntiles,
                                               const void* __restrict__ x,
                                               const float* __restrict__ W,
                                               const float* __restrict__ bias,
                                               float* __restrict__ out,
                                               const int* __restrict__ flag) {
    constexpr int KS = K / 32;
    const int lane = threadIdx.x & 63;
    const int rq = lane & 15;
    const int oct = lane >> 4;

    f16x8 bf[4][KS];
#pragma unroll
    for (int ct = 0; ct < 4; ++ct)
#pragma unroll
        for (int s = 0; s < KS; ++s) {
            const float* wp = W + (size_t)(32 * s + 8 * oct) * HD + 16 * ct + rq;
            f16x8 v;
#pragma unroll
            for (int j = 0; j < 8; ++j) v[j] = (_Float16)wp[(size_t)j * HD];
            bf[ct][s] = v;
        }
    float bv[4];
#pragma unroll
    for (int ct = 0; ct < 4; ++ct) bv[ct] = bias[16 * ct + rq];

    const bool isb = flag[0] != 0;

    for (int t = t0; t < ntiles; t += tstride) {
        const int r0 = t << 4;
        f16x8 a[KS];
        if (isb) {
            const unsigned short* xr = (const unsigned short*)x + (size_t)(r0 + rq) * K + 8 * oct;
#pragma unroll
            for (int s = 0; s < KS; ++s) {
                u16x8 uv = *(const u16x8*)(xr + 32 * s);
                f16x8 v;
#pragma unroll
                for (int j = 0; j < 8; ++j)
                    v[j] = (_Float16)__uint_as_float(((unsigned int)uv[j]) << 16);
                a[s] = v;
            }
        } else {
            const float* xr = (const float*)x + (size_t)(r0 + rq) * K + 8 * oct;
#pragma unroll
            for (int s = 0; s < KS; ++s) {
                float4 x0 = *(const float4*)(xr + 32 * s);
                float4 x1 = *(const float4*)(xr + 32 * s + 4);
                f16x8 v;
                v[0] = (_Float16)x0.x; v[1] = (_Float16)x0.y;
                v[2] = (_Float16)x0.z; v[3] = (_Float16)x0.w;
                v[4] = (_Float16)x1.x; v[5] = (_Float16)x1.y;
                v[6] = (_Float16)x1.z; v[7] = (_Float16)x1.w;
                a[s] = v;
            }
        }

        f32x4 acc[4];
#pragma unroll
        for (int ct = 0; ct < 4; ++ct) acc[ct] = (f32x4){0.f, 0.f, 0.f, 0.f};
#pragma unroll
        for (int ct = 0; ct < 4; ++ct)
#pragma unroll
            for (int s = 0; s < KS; ++s)
                acc[ct] = __builtin_amdgcn_mfma_f32_16x16x32_f16(a[s], bf[ct][s], acc[ct], 0, 0, 0);

        const int rb = r0 + (oct << 2);
#pragma unroll
        for (int ct = 0; ct < 4; ++ct)
#pragma unroll
            for (int g = 0; g < 4; ++g)
                out[(size_t)(rb + g) * HD + 16 * ct + rq] = acc[ct][g] + bv[ct];
    }
}

__global__ __launch_bounds__(256) void fused_p1_embed(
    const int* __restrict__ eu2u, const int* __restrict__ et2t,
    const int* __restrict__ eu2t, const int* __restrict__ et2u,
    int* __restrict__ gcnt, int* __restrict__ bofs,
    const void* __restrict__ x_user, const void* __restrict__ x_txn,
    const float* __restrict__ Wembu, const float* __restrict__ bembu,
    const float* __restrict__ Wembt, const float* __restrict__ bembt,
    float* __restrict__ hu, float* __restrict__ ht, const int* __restrict__ flag) {
    int b = blockIdx.x;
    int wid = threadIdx.x >> 6;
    if (b < PB1) {
        p1_dev(b, eu2u, et2t, eu2t, et2u, gcnt, bofs);
    } else if (b < PB1 + EMU) {
        embed_mfma_dev<32>((b - PB1) * 4 + wid, EMU * 4, NU_ / 16, x_user, Wembu, bembu,
                           hu, flag);
    } else {
        embed_mfma_dev<64>((b - PB1 - EMU) * 4 + wid, EMT * 4, NT_ / 16, x_txn, Wembt, bembt,
                           ht, flag);
    }
}

// ---------------- bucket base scan (two independent segments) ----------------
__global__ void scan_buckets(const int* __restrict__ gcnt, int* __restrict__ gbase) {
    __shared__ int sc[NBKT];
    int t = threadIdx.x;
    if (t < NBKT) sc[t] = gcnt[t];
    __syncthreads();
    if (t == 0) {
        int s = 0;
        for (int j = 0; j < NBKC; ++j) { int c = sc[j]; sc[j] = s; s += c; }
        s = 0;
        for (int j = NBKC; j < NBKT; ++j) { int c = sc[j]; sc[j] = s; s += c; }
    }
    __syncthreads();
    if (t < NBKT) gbase[t] = sc[t];
}

// ---------------- partition pass 2: scatter (must mirror p1's item mapping) ----------------
// CSR payload pre-encoded as BYTE offset: (src<<6) | tag(bit31)
__global__ __launch_bounds__(256) void p2_scatter(
    const int* __restrict__ eu2u, const int* __restrict__ et2t,
    const int* __restrict__ eu2t, const int* __restrict__ et2u,
    const int* __restrict__ gbase, const int* __restrict__ bofs,
    uint2* __restrict__ part_csr, unsigned int* __restrict__ part_src) {
    __shared__ int lofs[NBKT];
    for (int j = threadIdx.x; j < NBKT; j += 256) lofs[j] = 0;
    __syncthreads();
    const int bid = blockIdx.x;
    for (int i = bid * 256 + threadIdx.x; i < 6 * NE_; i += PB1 * 256) {
        if (i < 4 * NE_) {
            int m; unsigned int p;
            if (i < NE_)          { m = eu2u[i + NE_];           p = ((unsigned int)eu2u[i]) << 6; }
            else if (i < 2 * NE_) { m = NU_ + et2t[i];           p = ((unsigned int)et2t[i - NE_]) << 6; }
            else if (i < 3 * NE_) { m = NU_ + eu2t[i - NE_];     p = (((unsigned int)eu2t[i - 2 * NE_]) << 6) | 0x80000000u; }
            else                  { m = et2u[i - 2 * NE_];       p = (((unsigned int)et2u[i - 3 * NE_]) << 6) | 0x80000000u; }
            int b = m >> 11;
            int l = atomicAdd(&lofs[b], 1);
            int pos = gbase[b] + bofs[bid * NBKT + b] + l;
            part_csr[pos] = make_uint2((unsigned int)m, p);
        } else {
            int m2 = (i < 5 * NE_) ? eu2t[i - 4 * NE_] : (NU_ + et2u[i - 5 * NE_]);
            int b = NBKC + (m2 >> 11);
            int l = atomicAdd(&lofs[b], 1);
            int pos = gbase[b] + bofs[bid * NBKT + b] + l;
            part_src[pos] = (unsigned int)m2;
        }
    }
}

// ---------------- per-bucket exact counting (LDS atomics only) ----------------
__global__ __launch_bounds__(1024) void bucket_count(const uint2* __restrict__ part_csr,
                                                     const unsigned int* __restrict__ part_src,
                                                     const int* __restrict__ gcnt,
                                                     const int* __restrict__ gbase,
                                                     int* __restrict__ hist) {
    __shared__ int cA[BKP];
    __shared__ int cB[BKP];
    const int b = blockIdx.x;
    const int n = gcnt[b];
    const int base = gbase[b];
    const int t = threadIdx.x;
    for (int j = t; j < BKP; j += 1024) { cA[j] = 0; cB[j] = 0; }
    __syncthreads();
    if (b < NBKC) {
        for (int i = t; i < n; i += 1024) {
            uint2 it = part_csr[base + i];
            int l = (int)(it.x & (BKP - 1));
            if (it.y >> 31) atomicAdd(&cB[l], 1);
            else            atomicAdd(&cA[l], 1);
        }
        __syncthreads();
        const int m0 = b << 11;
        for (int j = t; j < BKP; j += 1024) {
            int m = m0 + j;
            if (m < NU_ + NT_) {
                int oA = (m < NU_) ? (OFF0 + m) : (OFF1 + (m - NU_));
                int oB = (m < NU_) ? (OFF3 + m) : (OFF2 + (m - NU_));
                hist[oA] = cA[j];
                hist[oB] = cB[j];
            }
        }
    } else {
        for (int i = t; i < n; i += 1024) {
            unsigned int m2 = part_src[base + i];
            atomicAdd(&cA[(int)(m2 & (BKP - 1))], 1);
        }
        __syncthreads();
        const int m0 = (b - NBKC) << 11;
        for (int j = t; j < BKP; j += 1024) {
            int m2 = m0 + j;
            if (m2 < NU_ + NT_) {
                int o = (m2 < NU_) ? (OFF4 + m2) : (OFF5 + (m2 - NU_));
                hist[o] = cA[j];
            }
        }
    }
}

// ---------------- per-bucket CSR placement (LDS bump allocators) ----------------
__global__ __launch_bounds__(1024) void bucket_place(const uint2* __restrict__ part_csr,
                                                     const int* __restrict__ gcnt,
                                                     const int* __restrict__ gbase,
                                                     const int* __restrict__ rp,
                                                     int* __restrict__ colU,
                                                     int* __restrict__ colT) {
    __shared__ int fl[BKP];
    const int b = blockIdx.x;
    const int n = gcnt[b];
    const int base = gbase[b];
    const int t = threadIdx.x;
    for (int j = t; j < BKP; j += 1024) fl[j] = 0;
    __syncthreads();
    for (int i = t; i < n; i += 1024) {
        uint2 it = part_csr[base + i];
        int m = (int)it.x;
        int ofs = atomicAdd(&fl[m & (BKP - 1)], 1);
        if (m < NU_) colU[rp[m] + ofs] = (int)it.y;
        else         colT[rp[m] + ofs] = (int)it.y;
    }
}

// ---------------- MFMA dual GEMM ----------------
__device__ __forceinline__ void gemm_mfma_dev(int t0, int tstride, int ntiles,
                                              const float* __restrict__ h,
                                              const float* __restrict__ WA,
                                              const float* __restrict__ WB,
                                              const float* __restrict__ scA,
                                              const float* __restrict__ scB,
                                              unsigned char* __restrict__ mA,
                                              unsigned char* __restrict__ mB) {
    const int lane = threadIdx.x & 63;
    const int rq = lane & 15;
    const int oct = lane >> 4;

    f16x8 bf[2][4][2];
#pragma unroll
    for (int m = 0; m < 2; ++m) {
        const float* W = m ? WB : WA;
#pragma unroll
        for (int ct = 0; ct < 4; ++ct)
#pragma unroll
            for (int s = 0; s < 2; ++s) {
                const float* wp = W + (size_t)(32 * s + 8 * oct) * HD + 16 * ct + rq;
                f16x8 v;
#pragma unroll
                for (int j = 0; j < 8; ++j) v[j] = (_Float16)wp[(size_t)j * HD];
                bf[m][ct][s] = v;
            }
    }

    for (int t = t0; t < ntiles; t += tstride) {
        const int r0 = t << 4;
        const float* hr = h + (size_t)(r0 + rq) * HD + 8 * oct;
        float4 x0 = *(const float4*)(hr);
        float4 x1 = *(const float4*)(hr + 4);
        float4 y0 = *(const float4*)(hr + 32);
        float4 y1 = *(const float4*)(hr + 36);
        f16x8 a0, a1;
        a0[0] = (_Float16)x0.x; a0[1] = (_Float16)x0.y;
        a0[2] = (_Float16)x0.z; a0[3] = (_Float16)x0.w;
        a0[4] = (_Float16)x1.x; a0[5] = (_Float16)x1.y;
        a0[6] = (_Float16)x1.z; a0[7] = (_Float16)x1.w;
        a1[0] = (_Float16)y0.x; a1[1] = (_Float16)y0.y;
        a1[2] = (_Float16)y0.z; a1[3] = (_Float16)y0.w;
        a1[4] = (_Float16)y1.x; a1[5] = (_Float16)y1.y;
        a1[6] = (_Float16)y1.z; a1[7] = (_Float16)y1.w;

        f32x4 acc[2][4];
#pragma unroll
        for (int m = 0; m < 2; ++m)
#pragma unroll
            for (int ct = 0; ct < 4; ++ct) acc[m][ct] = (f32x4){0.f, 0.f, 0.f, 0.f};

#pragma unroll
        for (int m = 0; m < 2; ++m)
#pragma unroll
            for (int ct = 0; ct < 4; ++ct) {
                acc[m][ct] = __builtin_amdgcn_mfma_f32_16x16x32_f16(a0, bf[m][ct][0],
                                                                   acc[m][ct], 0, 0, 0);
                acc[m][ct] = __builtin_amdgcn_mfma_f32_16x16x32_f16(a1, bf[m][ct][1],
                                                                   acc[m][ct], 0, 0, 0);
            }

        const int rb = r0 + (oct << 2);
        float sa[4], sb[4];
#pragma unroll
        for (int g = 0; g < 4; ++g) { sa[g] = scA[rb + g]; sb[g] = scB[rb + g]; }
#pragma unroll
        for (int ct = 0; ct < 4; ++ct)
#pragma unroll
            for (int g = 0; g < 4; ++g) {
                mA[(size_t)(rb + g) * HD + 16 * ct + rq] = enc_fp8(acc[0][ct][g] * sa[g]);
                mB[(size_t)(rb + g) * HD + 16 * ct + rq] = enc_fp8(acc[1][ct][g] * sb[g]);
            }
    }
}

__global__ __launch_bounds__(256) void gemm_dual_both(
    const float* __restrict__ hu, const float* __restrict__ ht,
    const float* __restrict__ W0, const float* __restrict__ Wu2t,
    const float* __restrict__ Wt, const float* __restrict__ Wt2u,
    const float* __restrict__ dinv,
    unsigned char* __restrict__ m_uu, unsigned char* __restrict__ m_ut,
    unsigned char* __restrict__ m_tt, unsigned char* __restrict__ m_tu) {
    int b = blockIdx.x;
    int wid = threadIdx.x >> 6;
    if (b < GMU) {
        gemm_mfma_dev(b * 4 + wid, GMU * 4, NU_ / 16, hu, W0, Wu2t,
                      dinv + OFF0, dinv + OFF4, m_uu, m_ut);
    } else {
        gemm_mfma_dev((b - GMU) * 4 + wid, GMT * 4, NT_ / 16, ht, Wt, Wt2u,
                      dinv + OFF1, dinv + OFF5, m_tt, m_tu);
    }
}

// ---------------- gather: 32-bit offsets, packed f32 accumulate ----------------
// col entries pre-encoded as (src<<6)|tag; msg = side base (A table, B at +offB).
// meta dA/dB carry the HeteroConv 0.5 factor.
__device__ __forceinline__ void gather_dev(int blk, const unsigned char* __restrict__ msg,
                                           unsigned int offB,
                                           const int4* __restrict__ meta,
                                           const int* __restrict__ col,
                                           const float* __restrict__ ba,
                                           const float* __restrict__ bb,
                                           float* __restrict__ out, int N) {
    const int lane = threadIdx.x & 63;
    const int grp = lane >> 3;
    const int sub = lane & 7;
    const int d = (blk << 2) + (threadIdx.x >> 6);
    if (d >= N) return;

    const int4 mt = meta[d];
    const int st = mt.x;
    const int cnt = mt.y;
    const float dA = __int_as_float(mt.z);   // 0.5 * dinv folded in
    const float dB = __int_as_float(mt.w);
    const unsigned char* msgL = msg + (sub << 3);

    floatx2 acc[4];
#pragma unroll
    for (int q = 0; q < 4; ++q) acc[q] = (floatx2){0.f, 0.f};

    const uint2 uself = *(const uint2*)(msgL + ((unsigned int)d << 6));

    auto consume = [&](uint2 u, float s) {
        floatx2 s2; s2.x = s; s2.y = s;
#if __has_builtin(__builtin_amdgcn_cvt_pk_f32_fp8)
        acc[0] += __builtin_amdgcn_cvt_pk_f32_fp8((int)u.x, false) * s2;
        acc[1] += __builtin_amdgcn_cvt_pk_f32_fp8((int)u.x, true) * s2;
        acc[2] += __builtin_amdgcn_cvt_pk_f32_fp8((int)u.y, false) * s2;
        acc[3] += __builtin_amdgcn_cvt_pk_f32_fp8((int)u.y, true) * s2;
#else
        float f[8];
        dec4_fp8(u.x, f);
        dec4_fp8(u.y, f + 4);
        acc[0].x += f[0] * s; acc[0].y += f[1] * s;
        acc[1].x += f[2] * s; acc[1].y += f[3] * s;
        acc[2].x += f[4] * s; acc[2].y += f[5] * s;
        acc[3].x += f[6] * s; acc[3].y += f[7] * s;
#endif
    };

    int done = 0;
    while (done < cnt) {
        int rem = cnt - done;
        if (rem > 64) rem = 64;
        int cw = (lane < rem) ? col[st + done + lane] : 0;
        const int nch = (rem + 7) >> 3;

        uint2 ub0, ub1, ub2, ub3;
        float sc0, sc1, sc2, sc3;

        auto issue = [&](int p, uint2& ub, float& sc) {
            int j = (p << 3) + grp;
            int c = __shfl(cw, j);
            unsigned int off = ((unsigned int)c & 0x7fffffffu) + ((c < 0) ? offB : 0u);
            float sv = (c < 0) ? dB : dA;
            sc = (j < rem) ? sv : 0.f;
            ub = *(const uint2*)(msgL + off);
        };

        issue(0, ub0, sc0);
        if (nch > 1) issue(1, ub1, sc1);
        if (nch > 2) issue(2, ub2, sc2);
        if (nch > 3) issue(3, ub3, sc3);

        consume(ub0, sc0);
        if (nch > 4) issue(4, ub0, sc0);
        if (nch > 1) consume(ub1, sc1);
        if (nch > 5) issue(5, ub1, sc1);
        if (nch > 2) consume(ub2, sc2);
        if (nch > 6) issue(6, ub2, sc2);
        if (nch > 3) consume(ub3, sc3);
        if (nch > 7) issue(7, ub3, sc3);
        if (nch > 4) consume(ub0, sc0);
        if (nch > 5) consume(ub1, sc1);
        if (nch > 6) consume(ub2, sc2);
        if (nch > 7) consume(ub3, sc3);

        done += rem;
    }

    consume(uself, (grp == 0) ? dA : 0.f);

#pragma unroll
    for (int q = 0; q < 4; ++q) {
        floatx2 v = acc[q];
#pragma unroll
        for (int m = 8; m <= 32; m <<= 1) {
            floatx2 o;
            o.x = __shfl_xor(v.x, m);
            o.y = __shfl_xor(v.y, m);
            v += o;
        }
        acc[q] = v;
    }

    if (grp == 0) {
        const int col0 = sub << 3;
        float4 a0 = *(const float4*)(ba + col0);
        float4 a1 = *(const float4*)(ba + col0 + 4);
        float4 c0 = *(const float4*)(bb + col0);
        float4 c1 = *(const float4*)(bb + col0 + 4);
        float af[8] = {acc[0].x, acc[0].y, acc[1].x, acc[1].y,
                       acc[2].x, acc[2].y, acc[3].x, acc[3].y};
        float bf[8] = {a0.x + c0.x, a0.y + c0.y, a0.z + c0.z, a0.w + c0.w,
                       a1.x + c1.x, a1.y + c1.y, a1.z + c1.z, a1.w + c1.w};
        float o[8];
#pragma unroll
        for (int k = 0; k < 8; ++k)
            o[k] = fmaxf(af[k] + 0.5f * bf[k], 0.f);
        float4 v0 = {o[0], o[1], o[2], o[3]};
        float4 v1 = {o[4], o[5], o[6], o[7]};
        *(float4*)(out + ((size_t)d << 6) + col0) = v0;
        *(float4*)(out + ((size_t)d << 6) + col0 + 4) = v1;
    }
}

__global__ __launch_bounds__(256) void gather_both(
    const unsigned char* __restrict__ msgU, const unsigned char* __restrict__ msgT,
    const int4* __restrict__ meta,
    const int* __restrict__ colU, const int* __restrict__ colT,
    const float* __restrict__ bU0, const float* __restrict__ bU1,
    const float* __restrict__ bT0, const float* __restrict__ bT1,
    float* __restrict__ hu, float* __restrict__ ht) {
    int b = blockIdx.x;
    if (b < GBU) {
        gather_dev(b, msgU, (unsigned int)NU_ * HD, meta, colU, bU0, bU1, hu, NU_);
    } else {
        gather_dev(b - GBU, msgT, (unsigned int)NT_ * HD, meta + NU_, colT, bT0, bT1, ht, NT_);
    }
}

// ---------------- CSR scan kernels (dinv folded in) ----------------
__global__ __launch_bounds__(256) void scan1m(const int* __restrict__ hist, int* __restrict__ rp,
                                              int* __restrict__ bsums, float* __restrict__ dinv) {
    int b = blockIdx.x, t = threadIdx.x;
    int r, lb, n, rpbase, oA, oB;
    if (b < NBU) { r = 0; lb = b;       n = NU_; rpbase = 0;   oA = OFF0; oB = OFF3; }
    else         { r = 1; lb = b - NBU; n = NT_; rpbase = NU_; oA = OFF1; oB = OFF2; }
    int i = lb * 256 + t;
    int hA = (i < n) ? hist[oA + i] : 0;
    int hB = (i < n) ? hist[oB + i] : 0;
    if (i < n) {
        dinv[oA + i] = rsqrtf((float)hA + 1.0f);                       // self-loop type
        dinv[oB + i] = (hB > 0) ? rsqrtf((float)hB) : 0.f;             // bipartite dst
    }
    int v = hA + hB;
    __shared__ int s[256];
    s[t] = v;
    __syncthreads();
    for (int off = 1; off < 256; off <<= 1) {
        int x = (t >= off) ? s[t - off] : 0;
        __syncthreads();
        s[t] += x;
        __syncthreads();
    }
    if (i < n) rp[rpbase + i] = s[t] - v;
    if (t == 255) bsums[r * 1024 + lb] = s[255];
}

__global__ __launch_bounds__(1024) void scan2m(int* __restrict__ bsums) {
    int r = blockIdx.x, t = threadIdx.x;
    const int nb = r ? NBT : NBU;
    int v = (t < nb) ? bsums[r * 1024 + t] : 0;
    __shared__ int s[1024];
    s[t] = v;
    __syncthreads();
    for (int off = 1; off < 1024; off <<= 1) {
        int x = (t >= off) ? s[t - off] : 0;
        __syncthreads();
        s[t] += x;
        __syncthreads();
    }
    if (t < nb) bsums[r * 1024 + t] = s[t] - v;
}

// scan3m: finalize rp, src dinv, and pack gather metadata {rp, cnt, 0.5dA, 0.5dB}
__global__ void scan3m(int* __restrict__ rp, const int* __restrict__ bsums,
                       const int* __restrict__ hist, float* __restrict__ dinv,
                       int4* __restrict__ meta) {
    int gid = blockIdx.x * blockDim.x + threadIdx.x;
    if (gid >= RPT2) return;
    int r = (gid < NU_) ? 0 : 1;
    int base = r ? NU_ : 0;
    int lb = (gid - base) >> 8;
    int rpf = rp[gid] + bsums[r * 1024 + lb];
    rp[gid] = rpf;
    // src dinv (for GEMM scaling)
    int si = r ? (OFF5 + gid - NU_) : (OFF4 + gid);
    int h = hist[si];
    dinv[si] = (h > 0) ? rsqrtf((float)h) : 0.f;
    // packed gather meta (0.5 HeteroConv-mean factor folded in)
    int oA = r ? (OFF1 + gid - NU_) : (OFF0 + gid);
    int oB = r ? (OFF2 + gid - NU_) : (OFF3 + gid);
    int hA = hist[oA];
    int hB = hist[oB];
    float dA = 0.5f * rsqrtf((float)hA + 1.0f);
    float dB = (hB > 0) ? 0.5f * rsqrtf((float)hB) : 0.f;
    int4 mt;
    mt.x = rpf;
    mt.y = hA + hB;
    mt.z = __float_as_int(dA);
    mt.w = __float_as_int(dB);
    meta[gid] = mt;
}

// ---------------- readout ----------------
__global__ __launch_bounds__(256) void colmean_both(const float* __restrict__ hu,
                                                    const float* __restrict__ ht,
                                                    float* __restrict__ gsum) {
    const bool isU = blockIdx.x < 512;
    const float* h = isU ? hu : ht;
    const int n = isU ? NU_ : NT_;
    const float scale = isU ? 0.5f / NU_ : 0.5f / NT_;
    const int blk = isU ? blockIdx.x : blockIdx.x - 512;
    const int lane = threadIdx.x & 63;
    const int w = threadIdx.x >> 6;
    float s = 0.f;
    for (int r = blk * 4 + w; r < n; r += 512 * 4)
        s += h[(size_t)r * HD + lane];
    __shared__ float red[256];
    red[threadIdx.x] = s;
    __syncthreads();
    if (threadIdx.x < 64) {
        float t = red[threadIdx.x] + red[64 + threadIdx.x] + red[128 + threadIdx.x] +
                  red[192 + threadIdx.x];
        atomicAdd(&gsum[lane], t * scale);
    }
}

__global__ void head(const float* __restrict__ g, const float* __restrict__ W1,
                     const float* __restrict__ b1, const float* __restrict__ W2,
                     const float* __restrict__ b2, const int* __restrict__ flag,
                     void* __restrict__ out) {
    const int c = threadIdx.x;
    float x = b1[c];
    for (int k = 0; k < HD; ++k) x = fmaf(g[k], W1[k * HD + c], x);
    x = fmaxf(x, 0.f);
    float t = x * W2[c];
    for (int off = 32; off; off >>= 1) t += __shfl_down(t, off);
    if (c == 0) {
        float z = t + b2[0];
        float s = 1.f / (1.f + expf(-z));
        if (flag[0]) *(__hip_bfloat16*)out = __float2bfloat16(s);
        else *(float*)out = s;
    }
}

extern "C" void kernel_launch(void* const* d_in, const int* in_sizes, int n_in,
                              void* d_out, int out_size, void* d_ws, size_t ws_size,
                              hipStream_t stream) {
    const void* x_user = d_in[0];
    const void* x_txn  = d_in[1];
    const int* ei_u2u = (const int*)d_in[2];
    const int* ei_t2t = (const int*)d_in[3];
    const int* ei_u2t = (const int*)d_in[4];
    const int* ei_t2u = (const int*)d_in[5];

    // ---- workspace layout ----
    // message tables ordered so each gather side's {A,B} pair is contiguous:
    //   U side: m_uu (NU) | m_tu (NT);  T side: m_tt (NT) | m_ut (NU)
    float* ws = (float*)d_ws;
    float* hu = ws;                                   // NU*64 f32
    float* ht = hu + (size_t)NU_ * HD;                // NT*64 f32
    float* dinv = ht + (size_t)NT_ * HD;              // HTOT
    float* wts = dinv + HTOT;                         // 60432 (padded)
    float* gsum = wts + 60432;                        // 64
    unsigned char* m_uu = (unsigned char*)(gsum + 64);  // NU rows fp8
    unsigned char* m_tu = m_uu + (size_t)NU_ * HD;      // NT rows
    unsigned char* m_tt = m_tu + (size_t)NT_ * HD;      // NT rows
    unsigned char* m_ut = m_tt + (size_t)NT_ * HD;      // NU rows
    int* hist = (int*)(m_ut + (size_t)NU_ * HD);      // HTOT
    int* aux  = hist + HTOT;                          // RPT2 region: gcnt/gbase/bofs
    int* rp   = aux + RPT2;                           // RPT2
    int* bsums = rp + RPT2;                           // 2048
    int* colU = bsums + 2048;                         // 2M
    int* colT = colU + 2 * NE_;                       // 2M
    int4* meta = (int4*)(colT + 2 * NE_);             // RPT2 (16B each)
    int* dflag = (int*)(meta + RPT2);                 // 1

    // partition bookkeeping in the old fill region (151,116 <= 300,000 ints)
    int* gcnt  = aux;               // NBKT
    int* gbase = gcnt + NBKT;       // NBKT
    int* bofs  = gbase + NBKT;      // PB1*NBKT = 150,528

    // partition payload aliases (consumed before layer-0 gemm/place writes)
    uint2* part_csr = (uint2*)m_uu;
    unsigned int* part_src = (unsigned int*)colU;

    // fp32 weight sub-pointers
    float* Wembu = wts;              // 2048
    float* bembu = Wembu + 2048;     // 64
    float* Wembt = bembu + 64;       // 4096
    float* bembt = Wembt + 4096;     // 64
    float* convWf = bembt + 64;      // 49152
    float* convbf = convWf + 49152;  // 768
    float* W1f = convbf + 768;       // 4096
    float* b1f = W1f + 4096;         // 64
    float* W2f = b1f + 64;           // 64
    float* b2f = W2f + 64;           // 1

    hipMemsetAsync(gcnt, 0, (size_t)NBKT * sizeof(int), stream);

    detect_dtype<<<1, 256, 0, stream>>>((const unsigned short*)x_user, dflag, 2048);
    {
        Ptr10 p;
        for (int k = 0; k < 10; ++k) p.p[k] = d_in[6 + k];
        cvt_weights<<<(60417 + 255) / 256, 256, 0, stream>>>(p, wts, gsum, dflag);
    }

    // ---- fused: partition pass 1 (LDS counts) + MFMA embedding GEMMs ----
    fused_p1_embed<<<PB1 + EMU + EMT, 256, 0, stream>>>(
        ei_u2u, ei_t2t, ei_u2t, ei_t2u, gcnt, bofs,
        x_user, x_txn, Wembu, bembu, Wembt, bembt, hu, ht, dflag);

    scan_buckets<<<1, 512, 0, stream>>>(gcnt, gbase);
    p2_scatter<<<PB1, 256, 0, stream>>>(ei_u2u, ei_t2t, ei_u2t, ei_t2u,
                                        gbase, bofs, part_csr, part_src);
    bucket_count<<<NBKT, 1024, 0, stream>>>(part_csr, part_src, gcnt, gbase, hist);

    scan1m<<<NBTOT2, 256, 0, stream>>>(hist, rp, bsums, dinv);
    scan2m<<<2, 1024, 0, stream>>>(bsums);
    scan3m<<<(RPT2 + 255) / 256, 256, 0, stream>>>(rp, bsums, hist, dinv, meta);

    bucket_place<<<NBKC, 1024, 0, stream>>>(part_csr, gcnt, gbase, rp, colU, colT);

    for (int l = 0; l < NL; ++l) {
        const float* W0   = convWf + ((size_t)l * 4 + 0) * HD * HD;
        const float* Wt   = convWf + ((size_t)l * 4 + 1) * HD * HD;
        const float* Wu2t = convWf + ((size_t)l * 4 + 2) * HD * HD;
        const float* Wt2u = convWf + ((size_t)l * 4 + 3) * HD * HD;
        const float* B0   = convbf + ((size_t)l * 4 + 0) * HD;
        const float* Bt   = convbf + ((size_t)l * 4 + 1) * HD;
        const float* Bu2t = convbf + ((size_t)l * 4 + 2) * HD;
        const float* Bt2u = convbf + ((size_t)l * 4 + 3) * HD;

        gemm_dual_both<<<GMU + GMT, 256, 0, stream>>>(hu, ht, W0, Wu2t, Wt, Wt2u, dinv,
                                                      m_uu, m_ut, m_tt, m_tu);

        gather_both<<<GBU + GBT, 256, 0, stream>>>(m_uu, m_tt,
                                                   meta, colU, colT,
                                                   B0, Bt2u, Bt, Bu2t, hu, ht);
    }

    // ---- readout ----
    colmean_both<<<1024, 256, 0, stream>>>(hu, ht, gsum);
    head<<<1, 64, 0, stream>>>(gsum, W1f, b1f, W2f, b2f, dflag, d_out);
}

// Round 7
// 679.024 us; speedup vs baseline: 2.8190x; 1.2400x over previous
//
#include <hip/hip_runtime.h>
#include <hip/hip_bf16.h>
#include <hip/hip_fp8.h>

#define NU_ 100000
#define NT_ 200000
#define NE_ 1000000
#define HD  64
#define NL  3

// hist/dinv region offsets (node-keyed arrays)
#define OFF0 0                   // u2u dst (NU)  [selfloop]
#define OFF1 (NU_)               // t2t dst (NT)  [selfloop]
#define OFF2 (NU_ + NT_)         // u2t dst (NT)
#define OFF3 (NU_ + 2 * NT_)     // t2u dst (NU)
#define OFF4 (2 * NU_ + 2 * NT_) // u2t src (NU)
#define OFF5 (3 * NU_ + 2 * NT_) // t2u src (NT)
#define HTOT (3 * NU_ + 3 * NT_) // 900k
#define RPT2 (NU_ + NT_)         // merged rp size (300k)

// merged scan partition (256/block)
#define NBU 391
#define NBT 782
#define NBTOT2 (NBU + NBT)

// bucket partition (no-far-atomic CSR build)
#define PB1  512           // partition blocks (256 threads each); p1/p2 must match
#define BKP  2048          // node-keys per bucket (key >> 11)
#define NBKC 147           // CSR buckets  (300k / 2048)
#define NBKS 147           // src buckets  (300k / 2048)
#define NBKT (NBKC + NBKS) // 294

// fused grids
#define EMU 512            // mfma embed user blocks
#define EMT 1024           // mfma embed txn blocks
#define GMU 512            // mfma gemm user blocks
#define GMT 1024           // mfma gemm txn blocks
#define GBU 3125           // NU/32 gather blocks (32 dsts per block)
#define GBT 6250           // NT/32 gather blocks

typedef float floatx2 __attribute__((ext_vector_type(2)));
typedef _Float16 f16x8 __attribute__((ext_vector_type(8)));
typedef float f32x4 __attribute__((ext_vector_type(4)));
typedef unsigned short u16x8 __attribute__((ext_vector_type(8)));

// ---------------- fp8 helpers ----------------
__device__ __forceinline__ unsigned char enc_fp8(float v) {
    return (unsigned char)__hip_cvt_float_to_fp8(v, __HIP_SATFINITE, __HIP_E4M3);
}

__device__ __forceinline__ float dec1_fp8(unsigned int u) {
    int e = (u >> 3) & 15;
    int m = u & 7;
    int mant = m | (e ? 8 : 0);
    if (u & 0x80) mant = -mant;
    int ex = (e ? e : 1) - 10;
    return (float)mant * __uint_as_float((unsigned int)(ex + 127) << 23);
}

__device__ __forceinline__ void dec4_fp8(unsigned int u, float* f) {
#if __has_builtin(__builtin_amdgcn_cvt_pk_f32_fp8)
    floatx2 lo = __builtin_amdgcn_cvt_pk_f32_fp8((int)u, false);
    floatx2 hi = __builtin_amdgcn_cvt_pk_f32_fp8((int)u, true);
    f[0] = lo.x; f[1] = lo.y; f[2] = hi.x; f[3] = hi.y;
#else
    f[0] = dec1_fp8(u & 0xff);
    f[1] = dec1_fp8((u >> 8) & 0xff);
    f[2] = dec1_fp8((u >> 16) & 0xff);
    f[3] = dec1_fp8((u >> 24) & 0xff);
#endif
}

// ---------------- dtype detection ----------------
__global__ void detect_dtype(const unsigned short* __restrict__ x, int* __restrict__ flag, int n) {
    __shared__ int s_big;
    if (threadIdx.x == 0) s_big = 0;
    __syncthreads();
    int big = 0;
    for (int i = threadIdx.x; i < n; i += blockDim.x) {
        float v = __uint_as_float(((unsigned int)x[i]) << 16);
        if (!(fabsf(v) < 1.0e4f)) big = 1;
    }
    if (big) atomicAdd(&s_big, 1);
    __syncthreads();
    if (threadIdx.x == 0) flag[0] = (s_big > 0) ? 0 : 1;
}

// ---------------- fused weight conversion (+ gsum zero) ----------------
struct Ptr10 { const void* p[10]; };

__global__ void cvt_weights(Ptr10 src, float* __restrict__ dst, float* __restrict__ gsum,
                            const int* __restrict__ flag) {
    const int c[11] = {0, 2048, 2112, 6208, 6272, 55424, 56192, 60288, 60352, 60416, 60417};
    int i = blockIdx.x * blockDim.x + threadIdx.x;
    if (i < 64) gsum[i] = 0.f;
    if (i >= 60417) return;
    int r = 0;
#pragma unroll
    for (int k = 1; k < 10; ++k)
        if (i >= c[k]) r = k;
    int e = i - c[r];
    if (flag[0]) {
        unsigned short u = ((const unsigned short*)src.p[r])[e];
        dst[i] = __uint_as_float(((unsigned int)u) << 16);
    } else {
        dst[i] = ((const float*)src.p[r])[e];
    }
}

// ---------------- partition pass 1: per-block bucket counts (LDS) ----------------
__device__ __forceinline__ void p1_dev(int bid, const int* __restrict__ eu2u,
                                       const int* __restrict__ et2t,
                                       const int* __restrict__ eu2t,
                                       const int* __restrict__ et2u,
                                       int* __restrict__ gcnt, int* __restrict__ bofs) {
    __shared__ int cnt[NBKT];
    for (int j = threadIdx.x; j < NBKT; j += 256) cnt[j] = 0;
    __syncthreads();
    for (int i = bid * 256 + threadIdx.x; i < 6 * NE_; i += PB1 * 256) {
        int b;
        if (i < 4 * NE_) {
            int m;
            if (i < NE_)          m = eu2u[i + NE_];
            else if (i < 2 * NE_) m = NU_ + et2t[i];          // (i-NE_) + NE_
            else if (i < 3 * NE_) m = NU_ + eu2t[i - NE_];    // (i-2NE_) + NE_
            else                  m = et2u[i - 2 * NE_];      // (i-3NE_) + NE_
            b = m >> 11;
        } else {
            int m2 = (i < 5 * NE_) ? eu2t[i - 4 * NE_] : (NU_ + et2u[i - 5 * NE_]);
            b = NBKC + (m2 >> 11);
        }
        atomicAdd(&cnt[b], 1);
    }
    __syncthreads();
    for (int j = threadIdx.x; j < NBKT; j += 256) {
        bofs[bid * NBKT + j] = atomicAdd(&gcnt[j], cnt[j]);
    }
}

// ---------------- MFMA embed: out[16x64] = X[16xK] @ W[Kx64] + bias ----------------
template <int K>
__device__ __forceinline__ void embed_mfma_dev(int t0, int tstride, int ntiles,
                                               const void* __restrict__ x,
                                               const float* __restrict__ W,
                                               const float* __restrict__ bias,
                                               float* __restrict__ out,
                                               const int* __restrict__ flag) {
    constexpr int KS = K / 32;
    const int lane = threadIdx.x & 63;
    const int rq = lane & 15;
    const int oct = lane >> 4;

    f16x8 bf[4][KS];
#pragma unroll
    for (int ct = 0; ct < 4; ++ct)
#pragma unroll
        for (int s = 0; s < KS; ++s) {
            const float* wp = W + (size_t)(32 * s + 8 * oct) * HD + 16 * ct + rq;
            f16x8 v;
#pragma unroll
            for (int j = 0; j < 8; ++j) v[j] = (_Float16)wp[(size_t)j * HD];
            bf[ct][s] = v;
        }
    float bv[4];
#pragma unroll
    for (int ct = 0; ct < 4; ++ct) bv[ct] = bias[16 * ct + rq];

    const bool isb = flag[0] != 0;

    for (int t = t0; t < ntiles; t += tstride) {
        const int r0 = t << 4;
        f16x8 a[KS];
        if (isb) {
            const unsigned short* xr = (const unsigned short*)x + (size_t)(r0 + rq) * K + 8 * oct;
#pragma unroll
            for (int s = 0; s < KS; ++s) {
                u16x8 uv = *(const u16x8*)(xr + 32 * s);
                f16x8 v;
#pragma unroll
                for (int j = 0; j < 8; ++j)
                    v[j] = (_Float16)__uint_as_float(((unsigned int)uv[j]) << 16);
                a[s] = v;
            }
        } else {
            const float* xr = (const float*)x + (size_t)(r0 + rq) * K + 8 * oct;
#pragma unroll
            for (int s = 0; s < KS; ++s) {
                float4 x0 = *(const float4*)(xr + 32 * s);
                float4 x1 = *(const float4*)(xr + 32 * s + 4);
                f16x8 v;
                v[0] = (_Float16)x0.x; v[1] = (_Float16)x0.y;
                v[2] = (_Float16)x0.z; v[3] = (_Float16)x0.w;
                v[4] = (_Float16)x1.x; v[5] = (_Float16)x1.y;
                v[6] = (_Float16)x1.z; v[7] = (_Float16)x1.w;
                a[s] = v;
            }
        }

        f32x4 acc[4];
#pragma unroll
        for (int ct = 0; ct < 4; ++ct) acc[ct] = (f32x4){0.f, 0.f, 0.f, 0.f};
#pragma unroll
        for (int ct = 0; ct < 4; ++ct)
#pragma unroll
            for (int s = 0; s < KS; ++s)
                acc[ct] = __builtin_amdgcn_mfma_f32_16x16x32_f16(a[s], bf[ct][s], acc[ct], 0, 0, 0);

        const int rb = r0 + (oct << 2);
#pragma unroll
        for (int ct = 0; ct < 4; ++ct)
#pragma unroll
            for (int g = 0; g < 4; ++g)
                out[(size_t)(rb + g) * HD + 16 * ct + rq] = acc[ct][g] + bv[ct];
    }
}

__global__ __launch_bounds__(256) void fused_p1_embed(
    const int* __restrict__ eu2u, const int* __restrict__ et2t,
    const int* __restrict__ eu2t, const int* __restrict__ et2u,
    int* __restrict__ gcnt, int* __restrict__ bofs,
    const void* __restrict__ x_user, const void* __restrict__ x_txn,
    const float* __restrict__ Wembu, const float* __restrict__ bembu,
    const float* __restrict__ Wembt, const float* __restrict__ bembt,
    float* __restrict__ hu, float* __restrict__ ht, const int* __restrict__ flag) {
    int b = blockIdx.x;
    int wid = threadIdx.x >> 6;
    if (b < PB1) {
        p1_dev(b, eu2u, et2t, eu2t, et2u, gcnt, bofs);
    } else if (b < PB1 + EMU) {
        embed_mfma_dev<32>((b - PB1) * 4 + wid, EMU * 4, NU_ / 16, x_user, Wembu, bembu,
                           hu, flag);
    } else {
        embed_mfma_dev<64>((b - PB1 - EMU) * 4 + wid, EMT * 4, NT_ / 16, x_txn, Wembt, bembt,
                           ht, flag);
    }
}

// ---------------- bucket base scan (two independent segments) ----------------
__global__ void scan_buckets(const int* __restrict__ gcnt, int* __restrict__ gbase) {
    __shared__ int sc[NBKT];
    int t = threadIdx.x;
    if (t < NBKT) sc[t] = gcnt[t];
    __syncthreads();
    if (t == 0) {
        int s = 0;
        for (int j = 0; j < NBKC; ++j) { int c = sc[j]; sc[j] = s; s += c; }
        s = 0;
        for (int j = NBKC; j < NBKT; ++j) { int c = sc[j]; sc[j] = s; s += c; }
    }
    __syncthreads();
    if (t < NBKT) gbase[t] = sc[t];
}

// ---------------- partition pass 2: scatter (must mirror p1's item mapping) ----------------
// CSR payload pre-encoded as BYTE offset: (src<<6) | tag(bit31)
__global__ __launch_bounds__(256) void p2_scatter(
    const int* __restrict__ eu2u, const int* __restrict__ et2t,
    const int* __restrict__ eu2t, const int* __restrict__ et2u,
    const int* __restrict__ gbase, const int* __restrict__ bofs,
    uint2* __restrict__ part_csr, unsigned int* __restrict__ part_src) {
    __shared__ int lofs[NBKT];
    for (int j = threadIdx.x; j < NBKT; j += 256) lofs[j] = 0;
    __syncthreads();
    const int bid = blockIdx.x;
    for (int i = bid * 256 + threadIdx.x; i < 6 * NE_; i += PB1 * 256) {
        if (i < 4 * NE_) {
            int m; unsigned int p;
            if (i < NE_)          { m = eu2u[i + NE_];           p = ((unsigned int)eu2u[i]) << 6; }
            else if (i < 2 * NE_) { m = NU_ + et2t[i];           p = ((unsigned int)et2t[i - NE_]) << 6; }
            else if (i < 3 * NE_) { m = NU_ + eu2t[i - NE_];     p = (((unsigned int)eu2t[i - 2 * NE_]) << 6) | 0x80000000u; }
            else                  { m = et2u[i - 2 * NE_];       p = (((unsigned int)et2u[i - 3 * NE_]) << 6) | 0x80000000u; }
            int b = m >> 11;
            int l = atomicAdd(&lofs[b], 1);
            int pos = gbase[b] + bofs[bid * NBKT + b] + l;
            part_csr[pos] = make_uint2((unsigned int)m, p);
        } else {
            int m2 = (i < 5 * NE_) ? eu2t[i - 4 * NE_] : (NU_ + et2u[i - 5 * NE_]);
            int b = NBKC + (m2 >> 11);
            int l = atomicAdd(&lofs[b], 1);
            int pos = gbase[b] + bofs[bid * NBKT + b] + l;
            part_src[pos] = (unsigned int)m2;
        }
    }
}

// ---------------- per-bucket exact counting (LDS atomics only) ----------------
__global__ __launch_bounds__(1024) void bucket_count(const uint2* __restrict__ part_csr,
                                                     const unsigned int* __restrict__ part_src,
                                                     const int* __restrict__ gcnt,
                                                     const int* __restrict__ gbase,
                                                     int* __restrict__ hist) {
    __shared__ int cA[BKP];
    __shared__ int cB[BKP];
    const int b = blockIdx.x;
    const int n = gcnt[b];
    const int base = gbase[b];
    const int t = threadIdx.x;
    for (int j = t; j < BKP; j += 1024) { cA[j] = 0; cB[j] = 0; }
    __syncthreads();
    if (b < NBKC) {
        for (int i = t; i < n; i += 1024) {
            uint2 it = part_csr[base + i];
            int l = (int)(it.x & (BKP - 1));
            if (it.y >> 31) atomicAdd(&cB[l], 1);
            else            atomicAdd(&cA[l], 1);
        }
        __syncthreads();
        const int m0 = b << 11;
        for (int j = t; j < BKP; j += 1024) {
            int m = m0 + j;
            if (m < NU_ + NT_) {
                int oA = (m < NU_) ? (OFF0 + m) : (OFF1 + (m - NU_));
                int oB = (m < NU_) ? (OFF3 + m) : (OFF2 + (m - NU_));
                hist[oA] = cA[j];
                hist[oB] = cB[j];
            }
        }
    } else {
        for (int i = t; i < n; i += 1024) {
            unsigned int m2 = part_src[base + i];
            atomicAdd(&cA[(int)(m2 & (BKP - 1))], 1);
        }
        __syncthreads();
        const int m0 = (b - NBKC) << 11;
        for (int j = t; j < BKP; j += 1024) {
            int m2 = m0 + j;
            if (m2 < NU_ + NT_) {
                int o = (m2 < NU_) ? (OFF4 + m2) : (OFF5 + (m2 - NU_));
                hist[o] = cA[j];
            }
        }
    }
}

// ---------------- per-bucket CSR placement (LDS bump allocators) ----------------
__global__ __launch_bounds__(1024) void bucket_place(const uint2* __restrict__ part_csr,
                                                     const int* __restrict__ gcnt,
                                                     const int* __restrict__ gbase,
                                                     const int* __restrict__ rp,
                                                     int* __restrict__ colU,
                                                     int* __restrict__ colT) {
    __shared__ int fl[BKP];
    const int b = blockIdx.x;
    const int n = gcnt[b];
    const int base = gbase[b];
    const int t = threadIdx.x;
    for (int j = t; j < BKP; j += 1024) fl[j] = 0;
    __syncthreads();
    for (int i = t; i < n; i += 1024) {
        uint2 it = part_csr[base + i];
        int m = (int)it.x;
        int ofs = atomicAdd(&fl[m & (BKP - 1)], 1);
        if (m < NU_) colU[rp[m] + ofs] = (int)it.y;
        else         colT[rp[m] + ofs] = (int)it.y;
    }
}

// ---------------- MFMA dual GEMM ----------------
__device__ __forceinline__ void gemm_mfma_dev(int t0, int tstride, int ntiles,
                                              const float* __restrict__ h,
                                              const float* __restrict__ WA,
                                              const float* __restrict__ WB,
                                              const float* __restrict__ scA,
                                              const float* __restrict__ scB,
                                              unsigned char* __restrict__ mA,
                                              unsigned char* __restrict__ mB) {
    const int lane = threadIdx.x & 63;
    const int rq = lane & 15;
    const int oct = lane >> 4;

    f16x8 bf[2][4][2];
#pragma unroll
    for (int m = 0; m < 2; ++m) {
        const float* W = m ? WB : WA;
#pragma unroll
        for (int ct = 0; ct < 4; ++ct)
#pragma unroll
            for (int s = 0; s < 2; ++s) {
                const float* wp = W + (size_t)(32 * s + 8 * oct) * HD + 16 * ct + rq;
                f16x8 v;
#pragma unroll
                for (int j = 0; j < 8; ++j) v[j] = (_Float16)wp[(size_t)j * HD];
                bf[m][ct][s] = v;
            }
    }

    for (int t = t0; t < ntiles; t += tstride) {
        const int r0 = t << 4;
        const float* hr = h + (size_t)(r0 + rq) * HD + 8 * oct;
        float4 x0 = *(const float4*)(hr);
        float4 x1 = *(const float4*)(hr + 4);
        float4 y0 = *(const float4*)(hr + 32);
        float4 y1 = *(const float4*)(hr + 36);
        f16x8 a0, a1;
        a0[0] = (_Float16)x0.x; a0[1] = (_Float16)x0.y;
        a0[2] = (_Float16)x0.z; a0[3] = (_Float16)x0.w;
        a0[4] = (_Float16)x1.x; a0[5] = (_Float16)x1.y;
        a0[6] = (_Float16)x1.z; a0[7] = (_Float16)x1.w;
        a1[0] = (_Float16)y0.x; a1[1] = (_Float16)y0.y;
        a1[2] = (_Float16)y0.z; a1[3] = (_Float16)y0.w;
        a1[4] = (_Float16)y1.x; a1[5] = (_Float16)y1.y;
        a1[6] = (_Float16)y1.z; a1[7] = (_Float16)y1.w;

        f32x4 acc[2][4];
#pragma unroll
        for (int m = 0; m < 2; ++m)
#pragma unroll
            for (int ct = 0; ct < 4; ++ct) acc[m][ct] = (f32x4){0.f, 0.f, 0.f, 0.f};

#pragma unroll
        for (int m = 0; m < 2; ++m)
#pragma unroll
            for (int ct = 0; ct < 4; ++ct) {
                acc[m][ct] = __builtin_amdgcn_mfma_f32_16x16x32_f16(a0, bf[m][ct][0],
                                                                   acc[m][ct], 0, 0, 0);
                acc[m][ct] = __builtin_amdgcn_mfma_f32_16x16x32_f16(a1, bf[m][ct][1],
                                                                   acc[m][ct], 0, 0, 0);
            }

        const int rb = r0 + (oct << 2);
        float sa[4], sb[4];
#pragma unroll
        for (int g = 0; g < 4; ++g) { sa[g] = scA[rb + g]; sb[g] = scB[rb + g]; }
#pragma unroll
        for (int ct = 0; ct < 4; ++ct)
#pragma unroll
            for (int g = 0; g < 4; ++g) {
                mA[(size_t)(rb + g) * HD + 16 * ct + rq] = enc_fp8(acc[0][ct][g] * sa[g]);
                mB[(size_t)(rb + g) * HD + 16 * ct + rq] = enc_fp8(acc[1][ct][g] * sb[g]);
            }
    }
}

__global__ __launch_bounds__(256) void gemm_dual_both(
    const float* __restrict__ hu, const float* __restrict__ ht,
    const float* __restrict__ W0, const float* __restrict__ Wu2t,
    const float* __restrict__ Wt, const float* __restrict__ Wt2u,
    const float* __restrict__ dinv,
    unsigned char* __restrict__ m_uu, unsigned char* __restrict__ m_ut,
    unsigned char* __restrict__ m_tt, unsigned char* __restrict__ m_tu) {
    int b = blockIdx.x;
    int wid = threadIdx.x >> 6;
    if (b < GMU) {
        gemm_mfma_dev(b * 4 + wid, GMU * 4, NU_ / 16, hu, W0, Wu2t,
                      dinv + OFF0, dinv + OFF4, m_uu, m_ut);
    } else {
        gemm_mfma_dev((b - GMU) * 4 + wid, GMT * 4, NT_ / 16, ht, Wt, Wt2u,
                      dinv + OFF1, dinv + OFF5, m_tt, m_tu);
    }
}

// ---------------- gather: one dst per 8-lane group (no cross-group reduction) ----------------
// col entries pre-encoded as (src<<6)|tag(bit31); msg = side base (B table at +offB).
// meta dA/dB carry the HeteroConv 0.5 factor. Lane sub owns feature bytes [sub*8, sub*8+8).
__device__ __forceinline__ void gather_dev(int blk, const unsigned char* __restrict__ msg,
                                           unsigned int offB,
                                           const int4* __restrict__ meta,
                                           const int* __restrict__ col,
                                           const float* __restrict__ ba,
                                           const float* __restrict__ bb,
                                           float* __restrict__ out, int N) {
    const int lane = threadIdx.x & 63;
    const int grp = lane >> 3;
    const int sub = lane & 7;
    const int d = (blk << 5) + ((threadIdx.x >> 6) << 3) + grp;
    const bool valid = d < N;

    int4 mt = make_int4(0, 0, 0, 0);
    if (valid) mt = meta[d];
    const int st = mt.x;
    const int cnt = mt.y;
    const float dA = __int_as_float(mt.z);   // 0.5 * dinv folded in
    const float dB = __int_as_float(mt.w);
    const unsigned char* msgL = msg + (sub << 3);

    floatx2 acc[4];
#pragma unroll
    for (int q = 0; q < 4; ++q) acc[q] = (floatx2){0.f, 0.f};

    auto consume = [&](uint2 u, float s) {
        floatx2 s2; s2.x = s; s2.y = s;
#if __has_builtin(__builtin_amdgcn_cvt_pk_f32_fp8)
        acc[0] += __builtin_amdgcn_cvt_pk_f32_fp8((int)u.x, false) * s2;
        acc[1] += __builtin_amdgcn_cvt_pk_f32_fp8((int)u.x, true) * s2;
        acc[2] += __builtin_amdgcn_cvt_pk_f32_fp8((int)u.y, false) * s2;
        acc[3] += __builtin_amdgcn_cvt_pk_f32_fp8((int)u.y, true) * s2;
#else
        float f[8];
        dec4_fp8(u.x, f);
        dec4_fp8(u.y, f + 4);
        acc[0].x += f[0] * s; acc[0].y += f[1] * s;
        acc[1].x += f[2] * s; acc[1].y += f[3] * s;
        acc[2].x += f[4] * s; acc[2].y += f[5] * s;
        acc[3].x += f[6] * s; acc[3].y += f[7] * s;
#endif
    };

    // self row (each group adds its own dst's A-message)
    if (valid) {
        uint2 uself = *(const uint2*)(msgL + ((unsigned int)d << 6));
        consume(uself, dA);
    }

    // edge loop: 8 edges per chunk per group, 4-deep issue/consume ladder
    int done = 0;
    while (done < cnt) {
        int rem = cnt - done;
        if (rem > 8) rem = 8;
        // cooperative col prefetch: lane sub holds col[st+done+sub] for its group
        int cw = (sub < rem) ? col[st + done + sub] : 0;

        uint2 ub0, ub1, ub2, ub3;
        float sc0, sc1, sc2, sc3;

        auto issue = [&](int p, uint2& ub, float& sc) {
            int c = __shfl(cw, (grp << 3) + p);
            unsigned int off = ((unsigned int)c & 0x7fffffffu) + ((c < 0) ? offB : 0u);
            float sv = (c < 0) ? dB : dA;
            sc = (p < rem) ? sv : 0.f;
            ub = *(const uint2*)(msgL + off);
        };

        issue(0, ub0, sc0);
        issue(1, ub1, sc1);
        issue(2, ub2, sc2);
        issue(3, ub3, sc3);

        consume(ub0, sc0);
        issue(4, ub0, sc0);
        consume(ub1, sc1);
        issue(5, ub1, sc1);
        consume(ub2, sc2);
        issue(6, ub2, sc2);
        consume(ub3, sc3);
        issue(7, ub3, sc3);
        consume(ub0, sc0);
        consume(ub1, sc1);
        consume(ub2, sc2);
        consume(ub3, sc3);

        done += 8;
    }

    if (valid) {
        const int col0 = sub << 3;
        float4 a0 = *(const float4*)(ba + col0);
        float4 a1 = *(const float4*)(ba + col0 + 4);
        float4 c0 = *(const float4*)(bb + col0);
        float4 c1 = *(const float4*)(bb + col0 + 4);
        float af[8] = {acc[0].x, acc[0].y, acc[1].x, acc[1].y,
                       acc[2].x, acc[2].y, acc[3].x, acc[3].y};
        float bf[8] = {a0.x + c0.x, a0.y + c0.y, a0.z + c0.z, a0.w + c0.w,
                       a1.x + c1.x, a1.y + c1.y, a1.z + c1.z, a1.w + c1.w};
        float o[8];
#pragma unroll
        for (int k = 0; k < 8; ++k)
            o[k] = fmaxf(af[k] + 0.5f * bf[k], 0.f);
        float4 v0 = {o[0], o[1], o[2], o[3]};
        float4 v1 = {o[4], o[5], o[6], o[7]};
        *(float4*)(out + ((size_t)d << 6) + col0) = v0;
        *(float4*)(out + ((size_t)d << 6) + col0 + 4) = v1;
    }
}

__global__ __launch_bounds__(256) void gather_both(
    const unsigned char* __restrict__ msgU, const unsigned char* __restrict__ msgT,
    const int4* __restrict__ meta,
    const int* __restrict__ colU, const int* __restrict__ colT,
    const float* __restrict__ bU0, const float* __restrict__ bU1,
    const float* __restrict__ bT0, const float* __restrict__ bT1,
    float* __restrict__ hu, float* __restrict__ ht) {
    int b = blockIdx.x;
    if (b < GBU) {
        gather_dev(b, msgU, (unsigned int)NU_ * HD, meta, colU, bU0, bU1, hu, NU_);
    } else {
        gather_dev(b - GBU, msgT, (unsigned int)NT_ * HD, meta + NU_, colT, bT0, bT1, ht, NT_);
    }
}

// ---------------- CSR scan kernels (dinv folded in) ----------------
__global__ __launch_bounds__(256) void scan1m(const int* __restrict__ hist, int* __restrict__ rp,
                                              int* __restrict__ bsums, float* __restrict__ dinv) {
    int b = blockIdx.x, t = threadIdx.x;
    int r, lb, n, rpbase, oA, oB;
    if (b < NBU) { r = 0; lb = b;       n = NU_; rpbase = 0;   oA = OFF0; oB = OFF3; }
    else         { r = 1; lb = b - NBU; n = NT_; rpbase = NU_; oA = OFF1; oB = OFF2; }
    int i = lb * 256 + t;
    int hA = (i < n) ? hist[oA + i] : 0;
    int hB = (i < n) ? hist[oB + i] : 0;
    if (i < n) {
        dinv[oA + i] = rsqrtf((float)hA + 1.0f);                       // self-loop type
        dinv[oB + i] = (hB > 0) ? rsqrtf((float)hB) : 0.f;             // bipartite dst
    }
    int v = hA + hB;
    __shared__ int s[256];
    s[t] = v;
    __syncthreads();
    for (int off = 1; off < 256; off <<= 1) {
        int x = (t >= off) ? s[t - off] : 0;
        __syncthreads();
        s[t] += x;
        __syncthreads();
    }
    if (i < n) rp[rpbase + i] = s[t] - v;
    if (t == 255) bsums[r * 1024 + lb] = s[255];
}

__global__ __launch_bounds__(1024) void scan2m(int* __restrict__ bsums) {
    int r = blockIdx.x, t = threadIdx.x;
    const int nb = r ? NBT : NBU;
    int v = (t < nb) ? bsums[r * 1024 + t] : 0;
    __shared__ int s[1024];
    s[t] = v;
    __syncthreads();
    for (int off = 1; off < 1024; off <<= 1) {
        int x = (t >= off) ? s[t - off] : 0;
        __syncthreads();
        s[t] += x;
        __syncthreads();
    }
    if (t < nb) bsums[r * 1024 + t] = s[t] - v;
}

// scan3m: finalize rp, src dinv, and pack gather metadata {rp, cnt, 0.5dA, 0.5dB}
__global__ void scan3m(int* __restrict__ rp, const int* __restrict__ bsums,
                       const int* __restrict__ hist, float* __restrict__ dinv,
                       int4* __restrict__ meta) {
    int gid = blockIdx.x * blockDim.x + threadIdx.x;
    if (gid >= RPT2) return;
    int r = (gid < NU_) ? 0 : 1;
    int base = r ? NU_ : 0;
    int lb = (gid - base) >> 8;
    int rpf = rp[gid] + bsums[r * 1024 + lb];
    rp[gid] = rpf;
    // src dinv (for GEMM scaling)
    int si = r ? (OFF5 + gid - NU_) : (OFF4 + gid);
    int h = hist[si];
    dinv[si] = (h > 0) ? rsqrtf((float)h) : 0.f;
    // packed gather meta (0.5 HeteroConv-mean factor folded in)
    int oA = r ? (OFF1 + gid - NU_) : (OFF0 + gid);
    int oB = r ? (OFF2 + gid - NU_) : (OFF3 + gid);
    int hA = hist[oA];
    int hB = hist[oB];
    float dA = 0.5f * rsqrtf((float)hA + 1.0f);
    float dB = (hB > 0) ? 0.5f * rsqrtf((float)hB) : 0.f;
    int4 mt;
    mt.x = rpf;
    mt.y = hA + hB;
    mt.z = __float_as_int(dA);
    mt.w = __float_as_int(dB);
    meta[gid] = mt;
}

// ---------------- readout ----------------
__global__ __launch_bounds__(256) void colmean_both(const float* __restrict__ hu,
                                                    const float* __restrict__ ht,
                                                    float* __restrict__ gsum) {
    const bool isU = blockIdx.x < 512;
    const float* h = isU ? hu : ht;
    const int n = isU ? NU_ : NT_;
    const float scale = isU ? 0.5f / NU_ : 0.5f / NT_;
    const int blk = isU ? blockIdx.x : blockIdx.x - 512;
    const int lane = threadIdx.x & 63;
    const int w = threadIdx.x >> 6;
    float s = 0.f;
    for (int r = blk * 4 + w; r < n; r += 512 * 4)
        s += h[(size_t)r * HD + lane];
    __shared__ float red[256];
    red[threadIdx.x] = s;
    __syncthreads();
    if (threadIdx.x < 64) {
        float t = red[threadIdx.x] + red[64 + threadIdx.x] + red[128 + threadIdx.x] +
                  red[192 + threadIdx.x];
        atomicAdd(&gsum[lane], t * scale);
    }
}

__global__ void head(const float* __restrict__ g, const float* __restrict__ W1,
                     const float* __restrict__ b1, const float* __restrict__ W2,
                     const float* __restrict__ b2, const int* __restrict__ flag,
                     void* __restrict__ out) {
    const int c = threadIdx.x;
    float x = b1[c];
    for (int k = 0; k < HD; ++k) x = fmaf(g[k], W1[k * HD + c], x);
    x = fmaxf(x, 0.f);
    float t = x * W2[c];
    for (int off = 32; off; off >>= 1) t += __shfl_down(t, off);
    if (c == 0) {
        float z = t + b2[0];
        float s = 1.f / (1.f + expf(-z));
        if (flag[0]) *(__hip_bfloat16*)out = __float2bfloat16(s);
        else *(float*)out = s;
    }
}

extern "C" void kernel_launch(void* const* d_in, const int* in_sizes, int n_in,
                              void* d_out, int out_size, void* d_ws, size_t ws_size,
                              hipStream_t stream) {
    const void* x_user = d_in[0];
    const void* x_txn  = d_in[1];
    const int* ei_u2u = (const int*)d_in[2];
    const int* ei_t2t = (const int*)d_in[3];
    const int* ei_u2t = (const int*)d_in[4];
    const int* ei_t2u = (const int*)d_in[5];

    // ---- workspace layout ----
    // message tables ordered so each gather side's {A,B} pair is contiguous:
    //   U side: m_uu (NU) | m_tu (NT);  T side: m_tt (NT) | m_ut (NU)
    float* ws = (float*)d_ws;
    float* hu = ws;                                   // NU*64 f32
    float* ht = hu + (size_t)NU_ * HD;                // NT*64 f32
    float* dinv = ht + (size_t)NT_ * HD;              // HTOT
    float* wts = dinv + HTOT;                         // 60432 (padded)
    float* gsum = wts + 60432;                        // 64
    unsigned char* m_uu = (unsigned char*)(gsum + 64);  // NU rows fp8
    unsigned char* m_tu = m_uu + (size_t)NU_ * HD;      // NT rows
    unsigned char* m_tt = m_tu + (size_t)NT_ * HD;      // NT rows
    unsigned char* m_ut = m_tt + (size_t)NT_ * HD;      // NU rows
    int* hist = (int*)(m_ut + (size_t)NU_ * HD);      // HTOT
    int* aux  = hist + HTOT;                          // RPT2 region: gcnt/gbase/bofs
    int* rp   = aux + RPT2;                           // RPT2
    int* bsums = rp + RPT2;                           // 2048
    int* colU = bsums + 2048;                         // 2M
    int* colT = colU + 2 * NE_;                       // 2M
    int4* meta = (int4*)(colT + 2 * NE_);             // RPT2 (16B each)
    int* dflag = (int*)(meta + RPT2);                 // 1

    // partition bookkeeping in the old fill region (151,116 <= 300,000 ints)
    int* gcnt  = aux;               // NBKT
    int* gbase = gcnt + NBKT;       // NBKT
    int* bofs  = gbase + NBKT;      // PB1*NBKT = 150,528

    // partition payload aliases (consumed before layer-0 gemm/place writes)
    uint2* part_csr = (uint2*)m_uu;
    unsigned int* part_src = (unsigned int*)colU;

    // fp32 weight sub-pointers
    float* Wembu = wts;              // 2048
    float* bembu = Wembu + 2048;     // 64
    float* Wembt = bembu + 64;       // 4096
    float* bembt = Wembt + 4096;     // 64
    float* convWf = bembt + 64;      // 49152
    float* convbf = convWf + 49152;  // 768
    float* W1f = convbf + 768;       // 4096
    float* b1f = W1f + 4096;         // 64
    float* W2f = b1f + 64;           // 64
    float* b2f = W2f + 64;           // 1

    hipMemsetAsync(gcnt, 0, (size_t)NBKT * sizeof(int), stream);

    detect_dtype<<<1, 256, 0, stream>>>((const unsigned short*)x_user, dflag, 2048);
    {
        Ptr10 p;
        for (int k = 0; k < 10; ++k) p.p[k] = d_in[6 + k];
        cvt_weights<<<(60417 + 255) / 256, 256, 0, stream>>>(p, wts, gsum, dflag);
    }

    // ---- fused: partition pass 1 (LDS counts) + MFMA embedding GEMMs ----
    fused_p1_embed<<<PB1 + EMU + EMT, 256, 0, stream>>>(
        ei_u2u, ei_t2t, ei_u2t, ei_t2u, gcnt, bofs,
        x_user, x_txn, Wembu, bembu, Wembt, bembt, hu, ht, dflag);

    scan_buckets<<<1, 512, 0, stream>>>(gcnt, gbase);
    p2_scatter<<<PB1, 256, 0, stream>>>(ei_u2u, ei_t2t, ei_u2t, ei_t2u,
                                        gbase, bofs, part_csr, part_src);
    bucket_count<<<NBKT, 1024, 0, stream>>>(part_csr, part_src, gcnt, gbase, hist);

    scan1m<<<NBTOT2, 256, 0, stream>>>(hist, rp, bsums, dinv);
    scan2m<<<2, 1024, 0, stream>>>(bsums);
    scan3m<<<(RPT2 + 255) / 256, 256, 0, stream>>>(rp, bsums, hist, dinv, meta);

    bucket_place<<<NBKC, 1024, 0, stream>>>(part_csr, gcnt, gbase, rp, colU, colT);

    for (int l = 0; l < NL; ++l) {
        const float* W0   = convWf + ((size_t)l * 4 + 0) * HD * HD;
        const float* Wt   = convWf + ((size_t)l * 4 + 1) * HD * HD;
        const float* Wu2t = convWf + ((size_t)l * 4 + 2) * HD * HD;
        const float* Wt2u = convWf + ((size_t)l * 4 + 3) * HD * HD;
        const float* B0   = convbf + ((size_t)l * 4 + 0) * HD;
        const float* Bt   = convbf + ((size_t)l * 4 + 1) * HD;
        const float* Bu2t = convbf + ((size_t)l * 4 + 2) * HD;
        const float* Bt2u = convbf + ((size_t)l * 4 + 3) * HD;

        gemm_dual_both<<<GMU + GMT, 256, 0, stream>>>(hu, ht, W0, Wu2t, Wt, Wt2u, dinv,
                                                      m_uu, m_ut, m_tt, m_tu);

        gather_both<<<GBU + GBT, 256, 0, stream>>>(m_uu, m_tt,
                                                   meta, colU, colT,
                                                   B0, Bt2u, Bt, Bu2t, hu, ht);
    }

    // ---- readout ----
    colmean_both<<<1024, 256, 0, stream>>>(hu, ht, gsum);
    head<<<1, 64, 0, stream>>>(gsum, W1f, b1f, W2f, b2f, dflag, d_out);
}

// Round 8
// 641.615 us; speedup vs baseline: 2.9833x; 1.0583x over previous
//
#include <hip/hip_runtime.h>
#include <hip/hip_bf16.h>
#include <hip/hip_fp8.h>

#define NU_ 100000
#define NT_ 200000
#define NE_ 1000000
#define HD  64
#define NL  3

// hist/dinv region offsets (node-keyed arrays)
#define OFF0 0                   // u2u dst (NU)  [selfloop]
#define OFF1 (NU_)               // t2t dst (NT)  [selfloop]
#define OFF2 (NU_ + NT_)         // u2t dst (NT)
#define OFF3 (NU_ + 2 * NT_)     // t2u dst (NU)
#define OFF4 (2 * NU_ + 2 * NT_) // u2t src (NU)
#define OFF5 (3 * NU_ + 2 * NT_) // t2u src (NT)
#define HTOT (3 * NU_ + 3 * NT_) // 900k
#define RPT2 (NU_ + NT_)         // merged rp size (300k)

// merged scan partition (256/block)
#define NBU 391
#define NBT 782
#define NBTOT2 (NBU + NBT)

// bucket partition (no-far-atomic CSR build)
#define PB1  512           // partition blocks (256 threads each); p1/p2 must match
#define BKP  2048          // node-keys per bucket (key >> 11)
#define NBKC 147           // CSR buckets  (300k / 2048)
#define NBKS 147           // src buckets  (300k / 2048)
#define NBKT (NBKC + NBKS) // 294

// fused grids
#define EMU 512            // mfma embed user blocks
#define EMT 1024           // mfma embed txn blocks
#define GMU 512            // mfma gemm user blocks
#define GMT 1024           // mfma gemm txn blocks
#define GBU 3125           // NU/32 gather blocks (32 dsts per block)
#define GBT 6250           // NT/32 gather blocks

typedef float floatx2 __attribute__((ext_vector_type(2)));
typedef _Float16 f16x8 __attribute__((ext_vector_type(8)));
typedef float f32x4 __attribute__((ext_vector_type(4)));
typedef unsigned short u16x8 __attribute__((ext_vector_type(8)));

// ---------------- fp8 helpers ----------------
__device__ __forceinline__ unsigned char enc_fp8(float v) {
    return (unsigned char)__hip_cvt_float_to_fp8(v, __HIP_SATFINITE, __HIP_E4M3);
}

__device__ __forceinline__ float dec1_fp8(unsigned int u) {
    int e = (u >> 3) & 15;
    int m = u & 7;
    int mant = m | (e ? 8 : 0);
    if (u & 0x80) mant = -mant;
    int ex = (e ? e : 1) - 10;
    return (float)mant * __uint_as_float((unsigned int)(ex + 127) << 23);
}

__device__ __forceinline__ void dec4_fp8(unsigned int u, float* f) {
#if __has_builtin(__builtin_amdgcn_cvt_pk_f32_fp8)
    floatx2 lo = __builtin_amdgcn_cvt_pk_f32_fp8((int)u, false);
    floatx2 hi = __builtin_amdgcn_cvt_pk_f32_fp8((int)u, true);
    f[0] = lo.x; f[1] = lo.y; f[2] = hi.x; f[3] = hi.y;
#else
    f[0] = dec1_fp8(u & 0xff);
    f[1] = dec1_fp8((u >> 8) & 0xff);
    f[2] = dec1_fp8((u >> 16) & 0xff);
    f[3] = dec1_fp8((u >> 24) & 0xff);
#endif
}

// ---------------- dtype detection ----------------
__global__ void detect_dtype(const unsigned short* __restrict__ x, int* __restrict__ flag, int n) {
    __shared__ int s_big;
    if (threadIdx.x == 0) s_big = 0;
    __syncthreads();
    int big = 0;
    for (int i = threadIdx.x; i < n; i += blockDim.x) {
        float v = __uint_as_float(((unsigned int)x[i]) << 16);
        if (!(fabsf(v) < 1.0e4f)) big = 1;
    }
    if (big) atomicAdd(&s_big, 1);
    __syncthreads();
    if (threadIdx.x == 0) flag[0] = (s_big > 0) ? 0 : 1;
}

// ---------------- fused weight conversion (+ gsum zero) ----------------
struct Ptr10 { const void* p[10]; };

__global__ void cvt_weights(Ptr10 src, float* __restrict__ dst, float* __restrict__ gsum,
                            const int* __restrict__ flag) {
    const int c[11] = {0, 2048, 2112, 6208, 6272, 55424, 56192, 60288, 60352, 60416, 60417};
    int i = blockIdx.x * blockDim.x + threadIdx.x;
    if (i < 64) gsum[i] = 0.f;
    if (i >= 60417) return;
    int r = 0;
#pragma unroll
    for (int k = 1; k < 10; ++k)
        if (i >= c[k]) r = k;
    int e = i - c[r];
    if (flag[0]) {
        unsigned short u = ((const unsigned short*)src.p[r])[e];
        dst[i] = __uint_as_float(((unsigned int)u) << 16);
    } else {
        dst[i] = ((const float*)src.p[r])[e];
    }
}

// ---------------- partition pass 1: per-block bucket counts (LDS) ----------------
__device__ __forceinline__ void p1_dev(int bid, const int* __restrict__ eu2u,
                                       const int* __restrict__ et2t,
                                       const int* __restrict__ eu2t,
                                       const int* __restrict__ et2u,
                                       int* __restrict__ gcnt, int* __restrict__ bofs) {
    __shared__ int cnt[NBKT];
    for (int j = threadIdx.x; j < NBKT; j += 256) cnt[j] = 0;
    __syncthreads();
    for (int i = bid * 256 + threadIdx.x; i < 6 * NE_; i += PB1 * 256) {
        int b;
        if (i < 4 * NE_) {
            int m;
            if (i < NE_)          m = eu2u[i + NE_];
            else if (i < 2 * NE_) m = NU_ + et2t[i];          // (i-NE_) + NE_
            else if (i < 3 * NE_) m = NU_ + eu2t[i - NE_];    // (i-2NE_) + NE_
            else                  m = et2u[i - 2 * NE_];      // (i-3NE_) + NE_
            b = m >> 11;
        } else {
            int m2 = (i < 5 * NE_) ? eu2t[i - 4 * NE_] : (NU_ + et2u[i - 5 * NE_]);
            b = NBKC + (m2 >> 11);
        }
        atomicAdd(&cnt[b], 1);
    }
    __syncthreads();
    for (int j = threadIdx.x; j < NBKT; j += 256) {
        bofs[bid * NBKT + j] = atomicAdd(&gcnt[j], cnt[j]);
    }
}

// ---------------- MFMA embed: out[16x64] = X[16xK] @ W[Kx64] + bias (h stored f16) ----------------
template <int K>
__device__ __forceinline__ void embed_mfma_dev(int t0, int tstride, int ntiles,
                                               const void* __restrict__ x,
                                               const float* __restrict__ W,
                                               const float* __restrict__ bias,
                                               _Float16* __restrict__ out,
                                               const int* __restrict__ flag) {
    constexpr int KS = K / 32;
    const int lane = threadIdx.x & 63;
    const int rq = lane & 15;
    const int oct = lane >> 4;

    f16x8 bf[4][KS];
#pragma unroll
    for (int ct = 0; ct < 4; ++ct)
#pragma unroll
        for (int s = 0; s < KS; ++s) {
            const float* wp = W + (size_t)(32 * s + 8 * oct) * HD + 16 * ct + rq;
            f16x8 v;
#pragma unroll
            for (int j = 0; j < 8; ++j) v[j] = (_Float16)wp[(size_t)j * HD];
            bf[ct][s] = v;
        }
    float bv[4];
#pragma unroll
    for (int ct = 0; ct < 4; ++ct) bv[ct] = bias[16 * ct + rq];

    const bool isb = flag[0] != 0;

    for (int t = t0; t < ntiles; t += tstride) {
        const int r0 = t << 4;
        f16x8 a[KS];
        if (isb) {
            const unsigned short* xr = (const unsigned short*)x + (size_t)(r0 + rq) * K + 8 * oct;
#pragma unroll
            for (int s = 0; s < KS; ++s) {
                u16x8 uv = *(const u16x8*)(xr + 32 * s);
                f16x8 v;
#pragma unroll
                for (int j = 0; j < 8; ++j)
                    v[j] = (_Float16)__uint_as_float(((unsigned int)uv[j]) << 16);
                a[s] = v;
            }
        } else {
            const float* xr = (const float*)x + (size_t)(r0 + rq) * K + 8 * oct;
#pragma unroll
            for (int s = 0; s < KS; ++s) {
                float4 x0 = *(const float4*)(xr + 32 * s);
                float4 x1 = *(const float4*)(xr + 32 * s + 4);
                f16x8 v;
                v[0] = (_Float16)x0.x; v[1] = (_Float16)x0.y;
                v[2] = (_Float16)x0.z; v[3] = (_Float16)x0.w;
                v[4] = (_Float16)x1.x; v[5] = (_Float16)x1.y;
                v[6] = (_Float16)x1.z; v[7] = (_Float16)x1.w;
                a[s] = v;
            }
        }

        f32x4 acc[4];
#pragma unroll
        for (int ct = 0; ct < 4; ++ct) acc[ct] = (f32x4){0.f, 0.f, 0.f, 0.f};
#pragma unroll
        for (int ct = 0; ct < 4; ++ct)
#pragma unroll
            for (int s = 0; s < KS; ++s)
                acc[ct] = __builtin_amdgcn_mfma_f32_16x16x32_f16(a[s], bf[ct][s], acc[ct], 0, 0, 0);

        const int rb = r0 + (oct << 2);
#pragma unroll
        for (int ct = 0; ct < 4; ++ct)
#pragma unroll
            for (int g = 0; g < 4; ++g)
                out[(size_t)(rb + g) * HD + 16 * ct + rq] = (_Float16)(acc[ct][g] + bv[ct]);
    }
}

__global__ __launch_bounds__(256) void fused_p1_embed(
    const int* __restrict__ eu2u, const int* __restrict__ et2t,
    const int* __restrict__ eu2t, const int* __restrict__ et2u,
    int* __restrict__ gcnt, int* __restrict__ bofs,
    const void* __restrict__ x_user, const void* __restrict__ x_txn,
    const float* __restrict__ Wembu, const float* __restrict__ bembu,
    const float* __restrict__ Wembt, const float* __restrict__ bembt,
    _Float16* __restrict__ hu, _Float16* __restrict__ ht, const int* __restrict__ flag) {
    int b = blockIdx.x;
    int wid = threadIdx.x >> 6;
    if (b < PB1) {
        p1_dev(b, eu2u, et2t, eu2t, et2u, gcnt, bofs);
    } else if (b < PB1 + EMU) {
        embed_mfma_dev<32>((b - PB1) * 4 + wid, EMU * 4, NU_ / 16, x_user, Wembu, bembu,
                           hu, flag);
    } else {
        embed_mfma_dev<64>((b - PB1 - EMU) * 4 + wid, EMT * 4, NT_ / 16, x_txn, Wembt, bembt,
                           ht, flag);
    }
}

// ---------------- bucket base scan (two independent segments) ----------------
__global__ void scan_buckets(const int* __restrict__ gcnt, int* __restrict__ gbase) {
    __shared__ int sc[NBKT];
    int t = threadIdx.x;
    if (t < NBKT) sc[t] = gcnt[t];
    __syncthreads();
    if (t == 0) {
        int s = 0;
        for (int j = 0; j < NBKC; ++j) { int c = sc[j]; sc[j] = s; s += c; }
        s = 0;
        for (int j = NBKC; j < NBKT; ++j) { int c = sc[j]; sc[j] = s; s += c; }
    }
    __syncthreads();
    if (t < NBKT) gbase[t] = sc[t];
}

// ---------------- partition pass 2: scatter (must mirror p1's item mapping) ----------------
// CSR payload pre-encoded as BYTE offset: (src<<6) | tag(bit31)
__global__ __launch_bounds__(256) void p2_scatter(
    const int* __restrict__ eu2u, const int* __restrict__ et2t,
    const int* __restrict__ eu2t, const int* __restrict__ et2u,
    const int* __restrict__ gbase, const int* __restrict__ bofs,
    uint2* __restrict__ part_csr, unsigned int* __restrict__ part_src) {
    __shared__ int lofs[NBKT];
    for (int j = threadIdx.x; j < NBKT; j += 256) lofs[j] = 0;
    __syncthreads();
    const int bid = blockIdx.x;
    for (int i = bid * 256 + threadIdx.x; i < 6 * NE_; i += PB1 * 256) {
        if (i < 4 * NE_) {
            int m; unsigned int p;
            if (i < NE_)          { m = eu2u[i + NE_];           p = ((unsigned int)eu2u[i]) << 6; }
            else if (i < 2 * NE_) { m = NU_ + et2t[i];           p = ((unsigned int)et2t[i - NE_]) << 6; }
            else if (i < 3 * NE_) { m = NU_ + eu2t[i - NE_];     p = (((unsigned int)eu2t[i - 2 * NE_]) << 6) | 0x80000000u; }
            else                  { m = et2u[i - 2 * NE_];       p = (((unsigned int)et2u[i - 3 * NE_]) << 6) | 0x80000000u; }
            int b = m >> 11;
            int l = atomicAdd(&lofs[b], 1);
            int pos = gbase[b] + bofs[bid * NBKT + b] + l;
            part_csr[pos] = make_uint2((unsigned int)m, p);
        } else {
            int m2 = (i < 5 * NE_) ? eu2t[i - 4 * NE_] : (NU_ + et2u[i - 5 * NE_]);
            int b = NBKC + (m2 >> 11);
            int l = atomicAdd(&lofs[b], 1);
            int pos = gbase[b] + bofs[bid * NBKT + b] + l;
            part_src[pos] = (unsigned int)m2;
        }
    }
}

// ---------------- per-bucket exact counting (LDS atomics only) ----------------
__global__ __launch_bounds__(1024) void bucket_count(const uint2* __restrict__ part_csr,
                                                     const unsigned int* __restrict__ part_src,
                                                     const int* __restrict__ gcnt,
                                                     const int* __restrict__ gbase,
                                                     int* __restrict__ hist) {
    __shared__ int cA[BKP];
    __shared__ int cB[BKP];
    const int b = blockIdx.x;
    const int n = gcnt[b];
    const int base = gbase[b];
    const int t = threadIdx.x;
    for (int j = t; j < BKP; j += 1024) { cA[j] = 0; cB[j] = 0; }
    __syncthreads();
    if (b < NBKC) {
        for (int i = t; i < n; i += 1024) {
            uint2 it = part_csr[base + i];
            int l = (int)(it.x & (BKP - 1));
            if (it.y >> 31) atomicAdd(&cB[l], 1);
            else            atomicAdd(&cA[l], 1);
        }
        __syncthreads();
        const int m0 = b << 11;
        for (int j = t; j < BKP; j += 1024) {
            int m = m0 + j;
            if (m < NU_ + NT_) {
                int oA = (m < NU_) ? (OFF0 + m) : (OFF1 + (m - NU_));
                int oB = (m < NU_) ? (OFF3 + m) : (OFF2 + (m - NU_));
                hist[oA] = cA[j];
                hist[oB] = cB[j];
            }
        }
    } else {
        for (int i = t; i < n; i += 1024) {
            unsigned int m2 = part_src[base + i];
            atomicAdd(&cA[(int)(m2 & (BKP - 1))], 1);
        }
        __syncthreads();
        const int m0 = (b - NBKC) << 11;
        for (int j = t; j < BKP; j += 1024) {
            int m2 = m0 + j;
            if (m2 < NU_ + NT_) {
                int o = (m2 < NU_) ? (OFF4 + m2) : (OFF5 + (m2 - NU_));
                hist[o] = cA[j];
            }
        }
    }
}

// ---------------- per-bucket CSR placement (LDS bump allocators) ----------------
__global__ __launch_bounds__(1024) void bucket_place(const uint2* __restrict__ part_csr,
                                                     const int* __restrict__ gcnt,
                                                     const int* __restrict__ gbase,
                                                     const int* __restrict__ rp,
                                                     int* __restrict__ colU,
                                                     int* __restrict__ colT) {
    __shared__ int fl[BKP];
    const int b = blockIdx.x;
    const int n = gcnt[b];
    const int base = gbase[b];
    const int t = threadIdx.x;
    for (int j = t; j < BKP; j += 1024) fl[j] = 0;
    __syncthreads();
    for (int i = t; i < n; i += 1024) {
        uint2 it = part_csr[base + i];
        int m = (int)it.x;
        int ofs = atomicAdd(&fl[m & (BKP - 1)], 1);
        if (m < NU_) colU[rp[m] + ofs] = (int)it.y;
        else         colT[rp[m] + ofs] = (int)it.y;
    }
}

// ---------------- MFMA dual GEMM (h read as f16) ----------------
__device__ __forceinline__ void gemm_mfma_dev(int t0, int tstride, int ntiles,
                                              const _Float16* __restrict__ h,
                                              const float* __restrict__ WA,
                                              const float* __restrict__ WB,
                                              const float* __restrict__ scA,
                                              const float* __restrict__ scB,
                                              unsigned char* __restrict__ mA,
                                              unsigned char* __restrict__ mB) {
    const int lane = threadIdx.x & 63;
    const int rq = lane & 15;
    const int oct = lane >> 4;

    f16x8 bf[2][4][2];
#pragma unroll
    for (int m = 0; m < 2; ++m) {
        const float* W = m ? WB : WA;
#pragma unroll
        for (int ct = 0; ct < 4; ++ct)
#pragma unroll
            for (int s = 0; s < 2; ++s) {
                const float* wp = W + (size_t)(32 * s + 8 * oct) * HD + 16 * ct + rq;
                f16x8 v;
#pragma unroll
                for (int j = 0; j < 8; ++j) v[j] = (_Float16)wp[(size_t)j * HD];
                bf[m][ct][s] = v;
            }
    }

    for (int t = t0; t < ntiles; t += tstride) {
        const int r0 = t << 4;
        const _Float16* hr = h + (size_t)(r0 + rq) * HD + 8 * oct;
        f16x8 a0 = *(const f16x8*)(hr);
        f16x8 a1 = *(const f16x8*)(hr + 32);

        f32x4 acc[2][4];
#pragma unroll
        for (int m = 0; m < 2; ++m)
#pragma unroll
            for (int ct = 0; ct < 4; ++ct) acc[m][ct] = (f32x4){0.f, 0.f, 0.f, 0.f};

#pragma unroll
        for (int m = 0; m < 2; ++m)
#pragma unroll
            for (int ct = 0; ct < 4; ++ct) {
                acc[m][ct] = __builtin_amdgcn_mfma_f32_16x16x32_f16(a0, bf[m][ct][0],
                                                                   acc[m][ct], 0, 0, 0);
                acc[m][ct] = __builtin_amdgcn_mfma_f32_16x16x32_f16(a1, bf[m][ct][1],
                                                                   acc[m][ct], 0, 0, 0);
            }

        const int rb = r0 + (oct << 2);
        float sa[4], sb[4];
#pragma unroll
        for (int g = 0; g < 4; ++g) { sa[g] = scA[rb + g]; sb[g] = scB[rb + g]; }
#pragma unroll
        for (int ct = 0; ct < 4; ++ct)
#pragma unroll
            for (int g = 0; g < 4; ++g) {
                mA[(size_t)(rb + g) * HD + 16 * ct + rq] = enc_fp8(acc[0][ct][g] * sa[g]);
                mB[(size_t)(rb + g) * HD + 16 * ct + rq] = enc_fp8(acc[1][ct][g] * sb[g]);
            }
    }
}

__global__ __launch_bounds__(256) void gemm_dual_both(
    const _Float16* __restrict__ hu, const _Float16* __restrict__ ht,
    const float* __restrict__ W0, const float* __restrict__ Wu2t,
    const float* __restrict__ Wt, const float* __restrict__ Wt2u,
    const float* __restrict__ dinv,
    unsigned char* __restrict__ m_uu, unsigned char* __restrict__ m_ut,
    unsigned char* __restrict__ m_tt, unsigned char* __restrict__ m_tu) {
    int b = blockIdx.x;
    int wid = threadIdx.x >> 6;
    if (b < GMU) {
        gemm_mfma_dev(b * 4 + wid, GMU * 4, NU_ / 16, hu, W0, Wu2t,
                      dinv + OFF0, dinv + OFF4, m_uu, m_ut);
    } else {
        gemm_mfma_dev((b - GMU) * 4 + wid, GMT * 4, NT_ / 16, ht, Wt, Wt2u,
                      dinv + OFF1, dinv + OFF5, m_tt, m_tu);
    }
}

// ---------------- gather: one dst per 8-lane group, h written f16 ----------------
// col entries pre-encoded as (src<<6)|tag(bit31); msg = side base (B table at +offB).
// meta dA/dB carry the HeteroConv 0.5 factor. Lane sub owns feature cols [sub*8, sub*8+8).
__device__ __forceinline__ void gather_dev(int blk, const unsigned char* __restrict__ msg,
                                           unsigned int offB,
                                           const int4* __restrict__ meta,
                                           const int* __restrict__ col,
                                           const float* __restrict__ ba,
                                           const float* __restrict__ bb,
                                           _Float16* __restrict__ out, int N) {
    const int lane = threadIdx.x & 63;
    const int grp = lane >> 3;
    const int sub = lane & 7;
    const int d = (blk << 5) + ((threadIdx.x >> 6) << 3) + grp;
    const bool valid = d < N;

    int4 mt = make_int4(0, 0, 0, 0);
    if (valid) mt = meta[d];
    const int st = mt.x;
    const int cnt = mt.y;
    const float dA = __int_as_float(mt.z);   // 0.5 * dinv folded in
    const float dB = __int_as_float(mt.w);
    const unsigned char* msgL = msg + (sub << 3);

    floatx2 acc[4];
#pragma unroll
    for (int q = 0; q < 4; ++q) acc[q] = (floatx2){0.f, 0.f};

    auto consume = [&](uint2 u, float s) {
        floatx2 s2; s2.x = s; s2.y = s;
#if __has_builtin(__builtin_amdgcn_cvt_pk_f32_fp8)
        acc[0] += __builtin_amdgcn_cvt_pk_f32_fp8((int)u.x, false) * s2;
        acc[1] += __builtin_amdgcn_cvt_pk_f32_fp8((int)u.x, true) * s2;
        acc[2] += __builtin_amdgcn_cvt_pk_f32_fp8((int)u.y, false) * s2;
        acc[3] += __builtin_amdgcn_cvt_pk_f32_fp8((int)u.y, true) * s2;
#else
        float f[8];
        dec4_fp8(u.x, f);
        dec4_fp8(u.y, f + 4);
        acc[0].x += f[0] * s; acc[0].y += f[1] * s;
        acc[1].x += f[2] * s; acc[1].y += f[3] * s;
        acc[2].x += f[4] * s; acc[2].y += f[5] * s;
        acc[3].x += f[6] * s; acc[3].y += f[7] * s;
#endif
    };

    // self row (each group adds its own dst's A-message)
    if (valid) {
        uint2 uself = *(const uint2*)(msgL + ((unsigned int)d << 6));
        consume(uself, dA);
    }

    // edge loop: 8 edges per chunk per group, 4-deep issue/consume ladder
    int done = 0;
    while (done < cnt) {
        int rem = cnt - done;
        if (rem > 8) rem = 8;
        // cooperative col prefetch: lane sub holds col[st+done+sub] for its group
        int cw = (sub < rem) ? col[st + done + sub] : 0;

        uint2 ub0, ub1, ub2, ub3;
        float sc0, sc1, sc2, sc3;

        auto issue = [&](int p, uint2& ub, float& sc) {
            int c = __shfl(cw, (grp << 3) + p);
            unsigned int off = ((unsigned int)c & 0x7fffffffu) + ((c < 0) ? offB : 0u);
            float sv = (c < 0) ? dB : dA;
            sc = (p < rem) ? sv : 0.f;
            ub = *(const uint2*)(msgL + off);
        };

        issue(0, ub0, sc0);
        issue(1, ub1, sc1);
        issue(2, ub2, sc2);
        issue(3, ub3, sc3);

        consume(ub0, sc0);
        issue(4, ub0, sc0);
        consume(ub1, sc1);
        issue(5, ub1, sc1);
        consume(ub2, sc2);
        issue(6, ub2, sc2);
        consume(ub3, sc3);
        issue(7, ub3, sc3);
        consume(ub0, sc0);
        consume(ub1, sc1);
        consume(ub2, sc2);
        consume(ub3, sc3);

        done += 8;
    }

    if (valid) {
        const int col0 = sub << 3;
        float4 a0 = *(const float4*)(ba + col0);
        float4 a1 = *(const float4*)(ba + col0 + 4);
        float4 c0 = *(const float4*)(bb + col0);
        float4 c1 = *(const float4*)(bb + col0 + 4);
        float af[8] = {acc[0].x, acc[0].y, acc[1].x, acc[1].y,
                       acc[2].x, acc[2].y, acc[3].x, acc[3].y};
        float bf[8] = {a0.x + c0.x, a0.y + c0.y, a0.z + c0.z, a0.w + c0.w,
                       a1.x + c1.x, a1.y + c1.y, a1.z + c1.z, a1.w + c1.w};
        f16x8 o;
#pragma unroll
        for (int k = 0; k < 8; ++k)
            o[k] = (_Float16)fmaxf(af[k] + 0.5f * bf[k], 0.f);
        *(f16x8*)(out + ((size_t)d << 6) + col0) = o;
    }
}

__global__ __launch_bounds__(256) void gather_both(
    const unsigned char* __restrict__ msgU, const unsigned char* __restrict__ msgT,
    const int4* __restrict__ meta,
    const int* __restrict__ colU, const int* __restrict__ colT,
    const float* __restrict__ bU0, const float* __restrict__ bU1,
    const float* __restrict__ bT0, const float* __restrict__ bT1,
    _Float16* __restrict__ hu, _Float16* __restrict__ ht) {
    int b = blockIdx.x;
    if (b < GBU) {
        gather_dev(b, msgU, (unsigned int)NU_ * HD, meta, colU, bU0, bU1, hu, NU_);
    } else {
        gather_dev(b - GBU, msgT, (unsigned int)NT_ * HD, meta + NU_, colT, bT0, bT1, ht, NT_);
    }
}

// ---------------- CSR scan kernels (dinv folded in) ----------------
__global__ __launch_bounds__(256) void scan1m(const int* __restrict__ hist, int* __restrict__ rp,
                                              int* __restrict__ bsums, float* __restrict__ dinv) {
    int b = blockIdx.x, t = threadIdx.x;
    int r, lb, n, rpbase, oA, oB;
    if (b < NBU) { r = 0; lb = b;       n = NU_; rpbase = 0;   oA = OFF0; oB = OFF3; }
    else         { r = 1; lb = b - NBU; n = NT_; rpbase = NU_; oA = OFF1; oB = OFF2; }
    int i = lb * 256 + t;
    int hA = (i < n) ? hist[oA + i] : 0;
    int hB = (i < n) ? hist[oB + i] : 0;
    if (i < n) {
        dinv[oA + i] = rsqrtf((float)hA + 1.0f);                       // self-loop type
        dinv[oB + i] = (hB > 0) ? rsqrtf((float)hB) : 0.f;             // bipartite dst
    }
    int v = hA + hB;
    __shared__ int s[256];
    s[t] = v;
    __syncthreads();
    for (int off = 1; off < 256; off <<= 1) {
        int x = (t >= off) ? s[t - off] : 0;
        __syncthreads();
        s[t] += x;
        __syncthreads();
    }
    if (i < n) rp[rpbase + i] = s[t] - v;
    if (t == 255) bsums[r * 1024 + lb] = s[255];
}

__global__ __launch_bounds__(1024) void scan2m(int* __restrict__ bsums) {
    int r = blockIdx.x, t = threadIdx.x;
    const int nb = r ? NBT : NBU;
    int v = (t < nb) ? bsums[r * 1024 + t] : 0;
    __shared__ int s[1024];
    s[t] = v;
    __syncthreads();
    for (int off = 1; off < 1024; off <<= 1) {
        int x = (t >= off) ? s[t - off] : 0;
        __syncthreads();
        s[t] += x;
        __syncthreads();
    }
    if (t < nb) bsums[r * 1024 + t] = s[t] - v;
}

// scan3m: finalize rp, src dinv, and pack gather metadata {rp, cnt, 0.5dA, 0.5dB}
__global__ void scan3m(int* __restrict__ rp, const int* __restrict__ bsums,
                       const int* __restrict__ hist, float* __restrict__ dinv,
                       int4* __restrict__ meta) {
    int gid = blockIdx.x * blockDim.x + threadIdx.x;
    if (gid >= RPT2) return;
    int r = (gid < NU_) ? 0 : 1;
    int base = r ? NU_ : 0;
    int lb = (gid - base) >> 8;
    int rpf = rp[gid] + bsums[r * 1024 + lb];
    rp[gid] = rpf;
    // src dinv (for GEMM scaling)
    int si = r ? (OFF5 + gid - NU_) : (OFF4 + gid);
    int h = hist[si];
    dinv[si] = (h > 0) ? rsqrtf((float)h) : 0.f;
    // packed gather meta (0.5 HeteroConv-mean factor folded in)
    int oA = r ? (OFF1 + gid - NU_) : (OFF0 + gid);
    int oB = r ? (OFF2 + gid - NU_) : (OFF3 + gid);
    int hA = hist[oA];
    int hB = hist[oB];
    float dA = 0.5f * rsqrtf((float)hA + 1.0f);
    float dB = (hB > 0) ? 0.5f * rsqrtf((float)hB) : 0.f;
    int4 mt;
    mt.x = rpf;
    mt.y = hA + hB;
    mt.z = __float_as_int(dA);
    mt.w = __float_as_int(dB);
    meta[gid] = mt;
}

// ---------------- readout ----------------
__global__ __launch_bounds__(256) void colmean_both(const _Float16* __restrict__ hu,
                                                    const _Float16* __restrict__ ht,
                                                    float* __restrict__ gsum) {
    const bool isU = blockIdx.x < 512;
    const _Float16* h = isU ? hu : ht;
    const int n = isU ? NU_ : NT_;
    const float scale = isU ? 0.5f / NU_ : 0.5f / NT_;
    const int blk = isU ? blockIdx.x : blockIdx.x - 512;
    const int lane = threadIdx.x & 63;
    const int w = threadIdx.x >> 6;
    float s = 0.f;
    for (int r = blk * 4 + w; r < n; r += 512 * 4)
        s += (float)h[(size_t)r * HD + lane];
    __shared__ float red[256];
    red[threadIdx.x] = s;
    __syncthreads();
    if (threadIdx.x < 64) {
        float t = red[threadIdx.x] + red[64 + threadIdx.x] + red[128 + threadIdx.x] +
                  red[192 + threadIdx.x];
        atomicAdd(&gsum[lane], t * scale);
    }
}

__global__ void head(const float* __restrict__ g, const float* __restrict__ W1,
                     const float* __restrict__ b1, const float* __restrict__ W2,
                     const float* __restrict__ b2, const int* __restrict__ flag,
                     void* __restrict__ out) {
    const int c = threadIdx.x;
    float x = b1[c];
    for (int k = 0; k < HD; ++k) x = fmaf(g[k], W1[k * HD + c], x);
    x = fmaxf(x, 0.f);
    float t = x * W2[c];
    for (int off = 32; off; off >>= 1) t += __shfl_down(t, off);
    if (c == 0) {
        float z = t + b2[0];
        float s = 1.f / (1.f + expf(-z));
        if (flag[0]) *(__hip_bfloat16*)out = __float2bfloat16(s);
        else *(float*)out = s;
    }
}

extern "C" void kernel_launch(void* const* d_in, const int* in_sizes, int n_in,
                              void* d_out, int out_size, void* d_ws, size_t ws_size,
                              hipStream_t stream) {
    const void* x_user = d_in[0];
    const void* x_txn  = d_in[1];
    const int* ei_u2u = (const int*)d_in[2];
    const int* ei_t2t = (const int*)d_in[3];
    const int* ei_u2t = (const int*)d_in[4];
    const int* ei_t2u = (const int*)d_in[5];

    // ---- workspace layout ----
    // h stored f16 (halved intermediate traffic). Message tables ordered so each
    // gather side's {A,B} pair is contiguous: U: m_uu|m_tu ; T: m_tt|m_ut
    float* ws = (float*)d_ws;
    _Float16* hu = (_Float16*)ws;                     // NU*64 f16
    _Float16* ht = hu + (size_t)NU_ * HD;             // NT*64 f16
    float* dinv = (float*)(ht + (size_t)NT_ * HD);    // HTOT f32
    float* wts = dinv + HTOT;                         // 60432 (padded)
    float* gsum = wts + 60432;                        // 64
    unsigned char* m_uu = (unsigned char*)(gsum + 64);  // NU rows fp8
    unsigned char* m_tu = m_uu + (size_t)NU_ * HD;      // NT rows
    unsigned char* m_tt = m_tu + (size_t)NT_ * HD;      // NT rows
    unsigned char* m_ut = m_tt + (size_t)NT_ * HD;      // NU rows
    int* hist = (int*)(m_ut + (size_t)NU_ * HD);      // HTOT
    int* aux  = hist + HTOT;                          // RPT2 region: gcnt/gbase/bofs
    int* rp   = aux + RPT2;                           // RPT2
    int* bsums = rp + RPT2;                           // 2048
    int* colU = bsums + 2048;                         // 2M
    int* colT = colU + 2 * NE_;                       // 2M
    int4* meta = (int4*)(colT + 2 * NE_);             // RPT2 (16B each)
    int* dflag = (int*)(meta + RPT2);                 // 1

    // partition bookkeeping in the old fill region (151,116 <= 300,000 ints)
    int* gcnt  = aux;               // NBKT
    int* gbase = gcnt + NBKT;       // NBKT
    int* bofs  = gbase + NBKT;      // PB1*NBKT = 150,528

    // partition payload aliases (consumed before layer-0 gemm/place writes)
    uint2* part_csr = (uint2*)m_uu;
    unsigned int* part_src = (unsigned int*)colU;

    // fp32 weight sub-pointers
    float* Wembu = wts;              // 2048
    float* bembu = Wembu + 2048;     // 64
    float* Wembt = bembu + 64;       // 4096
    float* bembt = Wembt + 4096;     // 64
    float* convWf = bembt + 64;      // 49152
    float* convbf = convWf + 49152;  // 768
    float* W1f = convbf + 768;       // 4096
    float* b1f = W1f + 4096;         // 64
    float* W2f = b1f + 64;           // 64
    float* b2f = W2f + 64;           // 1

    hipMemsetAsync(gcnt, 0, (size_t)NBKT * sizeof(int), stream);

    detect_dtype<<<1, 256, 0, stream>>>((const unsigned short*)x_user, dflag, 2048);
    {
        Ptr10 p;
        for (int k = 0; k < 10; ++k) p.p[k] = d_in[6 + k];
        cvt_weights<<<(60417 + 255) / 256, 256, 0, stream>>>(p, wts, gsum, dflag);
    }

    // ---- fused: partition pass 1 (LDS counts) + MFMA embedding GEMMs ----
    fused_p1_embed<<<PB1 + EMU + EMT, 256, 0, stream>>>(
        ei_u2u, ei_t2t, ei_u2t, ei_t2u, gcnt, bofs,
        x_user, x_txn, Wembu, bembu, Wembt, bembt, hu, ht, dflag);

    scan_buckets<<<1, 512, 0, stream>>>(gcnt, gbase);
    p2_scatter<<<PB1, 256, 0, stream>>>(ei_u2u, ei_t2t, ei_u2t, ei_t2u,
                                        gbase, bofs, part_csr, part_src);
    bucket_count<<<NBKT, 1024, 0, stream>>>(part_csr, part_src, gcnt, gbase, hist);

    scan1m<<<NBTOT2, 256, 0, stream>>>(hist, rp, bsums, dinv);
    scan2m<<<2, 1024, 0, stream>>>(bsums);
    scan3m<<<(RPT2 + 255) / 256, 256, 0, stream>>>(rp, bsums, hist, dinv, meta);

    bucket_place<<<NBKC, 1024, 0, stream>>>(part_csr, gcnt, gbase, rp, colU, colT);

    for (int l = 0; l < NL; ++l) {
        const float* W0   = convWf + ((size_t)l * 4 + 0) * HD * HD;
        const float* Wt   = convWf + ((size_t)l * 4 + 1) * HD * HD;
        const float* Wu2t = convWf + ((size_t)l * 4 + 2) * HD * HD;
        const float* Wt2u = convWf + ((size_t)l * 4 + 3) * HD * HD;
        const float* B0   = convbf + ((size_t)l * 4 + 0) * HD;
        const float* Bt   = convbf + ((size_t)l * 4 + 1) * HD;
        const float* Bu2t = convbf + ((size_t)l * 4 + 2) * HD;
        const float* Bt2u = convbf + ((size_t)l * 4 + 3) * HD;

        gemm_dual_both<<<GMU + GMT, 256, 0, stream>>>(hu, ht, W0, Wu2t, Wt, Wt2u, dinv,
                                                      m_uu, m_ut, m_tt, m_tu);

        gather_both<<<GBU + GBT, 256, 0, stream>>>(m_uu, m_tt,
                                                   meta, colU, colT,
                                                   B0, Bt2u, Bt, Bu2t, hu, ht);
    }

    // ---- readout ----
    colmean_both<<<1024, 256, 0, stream>>>(hu, ht, gsum);
    head<<<1, 64, 0, stream>>>(gsum, W1f, b1f, W2f, b2f, dflag, d_out);
}

// Round 9
// 610.390 us; speedup vs baseline: 3.1359x; 1.0512x over previous
//
#include <hip/hip_runtime.h>
#include <hip/hip_bf16.h>
#include <hip/hip_fp8.h>

#define NU_ 100000
#define NT_ 200000
#define NE_ 1000000
#define HD  64
#define NL  3

// hist/dinv region offsets (node-keyed arrays)
#define OFF0 0                   // u2u dst (NU)  [selfloop]
#define OFF1 (NU_)               // t2t dst (NT)  [selfloop]
#define OFF2 (NU_ + NT_)         // u2t dst (NT)
#define OFF3 (NU_ + 2 * NT_)     // t2u dst (NU)
#define OFF4 (2 * NU_ + 2 * NT_) // u2t src (NU)
#define OFF5 (3 * NU_ + 2 * NT_) // t2u src (NT)
#define HTOT (3 * NU_ + 3 * NT_) // 900k
#define RPT2 (NU_ + NT_)         // merged rp size (300k)

// merged scan partition (256/block)
#define NBU 391
#define NBT 782
#define NBTOT2 (NBU + NBT)

// bucket partition (no-far-atomic CSR build)
#define PB1  512           // partition blocks (256 threads each); p1/p2 must match
#define BKP  2048          // node-keys per bucket (key >> 11)
#define NBKC 147           // CSR buckets  (300k / 2048)
#define NBKS 147           // src buckets  (300k / 2048)
#define NBKT (NBKC + NBKS) // 294

// packed-weight layout (f16 fragments, 512 f16 per fragment = 64 lanes x 8)
#define WPK_EMBU 0         // 4 frags (K=32)
#define WPK_EMBT 2048      // 8 frags (K=64)
#define WPK_CONV 6144      // 12 mats x 8 frags
#define WPK_TOT  55296

// fused grids
#define EMU 512            // mfma embed user blocks
#define EMT 1024           // mfma embed txn blocks
#define GMU 512            // mfma gemm user blocks
#define GMT 1024           // mfma gemm txn blocks
#define GBU 3125           // NU/32 gather blocks (32 dsts per block)
#define GBT 6250           // NT/32 gather blocks

typedef float floatx2 __attribute__((ext_vector_type(2)));
typedef _Float16 f16x8 __attribute__((ext_vector_type(8)));
typedef float f32x4 __attribute__((ext_vector_type(4)));
typedef unsigned short u16x8 __attribute__((ext_vector_type(8)));

// ---------------- fp8 helpers ----------------
__device__ __forceinline__ unsigned char enc_fp8(float v) {
    return (unsigned char)__hip_cvt_float_to_fp8(v, __HIP_SATFINITE, __HIP_E4M3);
}

__device__ __forceinline__ float dec1_fp8(unsigned int u) {
    int e = (u >> 3) & 15;
    int m = u & 7;
    int mant = m | (e ? 8 : 0);
    if (u & 0x80) mant = -mant;
    int ex = (e ? e : 1) - 10;
    return (float)mant * __uint_as_float((unsigned int)(ex + 127) << 23);
}

__device__ __forceinline__ void dec4_fp8(unsigned int u, float* f) {
#if __has_builtin(__builtin_amdgcn_cvt_pk_f32_fp8)
    floatx2 lo = __builtin_amdgcn_cvt_pk_f32_fp8((int)u, false);
    floatx2 hi = __builtin_amdgcn_cvt_pk_f32_fp8((int)u, true);
    f[0] = lo.x; f[1] = lo.y; f[2] = hi.x; f[3] = hi.y;
#else
    f[0] = dec1_fp8(u & 0xff);
    f[1] = dec1_fp8((u >> 8) & 0xff);
    f[2] = dec1_fp8((u >> 16) & 0xff);
    f[3] = dec1_fp8((u >> 24) & 0xff);
#endif
}

// ---------------- dtype detection ----------------
__global__ void detect_dtype(const unsigned short* __restrict__ x, int* __restrict__ flag, int n) {
    __shared__ int s_big;
    if (threadIdx.x == 0) s_big = 0;
    __syncthreads();
    int big = 0;
    for (int i = threadIdx.x; i < n; i += blockDim.x) {
        float v = __uint_as_float(((unsigned int)x[i]) << 16);
        if (!(fabsf(v) < 1.0e4f)) big = 1;
    }
    if (big) atomicAdd(&s_big, 1);
    __syncthreads();
    if (threadIdx.x == 0) flag[0] = (s_big > 0) ? 0 : 1;
}

// ---------------- fused weight conversion (+ gsum zero) ----------------
struct Ptr10 { const void* p[10]; };

__global__ void cvt_weights(Ptr10 src, float* __restrict__ dst, float* __restrict__ gsum,
                            const int* __restrict__ flag) {
    const int c[11] = {0, 2048, 2112, 6208, 6272, 55424, 56192, 60288, 60352, 60416, 60417};
    int i = blockIdx.x * blockDim.x + threadIdx.x;
    if (i < 64) gsum[i] = 0.f;
    if (i >= 60417) return;
    int r = 0;
#pragma unroll
    for (int k = 1; k < 10; ++k)
        if (i >= c[k]) r = k;
    int e = i - c[r];
    if (flag[0]) {
        unsigned short u = ((const unsigned short*)src.p[r])[e];
        dst[i] = __uint_as_float(((unsigned int)u) << 16);
    } else {
        dst[i] = ((const float*)src.p[r])[e];
    }
}

// ---------------- pack MFMA weight fragments (f32 wts -> f16 per-lane order) ----------------
// Fragment f = ct*KS + s; within fragment, lane holds 8 f16 at [k=32s+8*(lane>>4)+j][n=16ct+(lane&15)].
__global__ void pack_weights(const float* __restrict__ wts, _Float16* __restrict__ wpk) {
    int gid = blockIdx.x * 256 + threadIdx.x;
    if (gid >= WPK_TOT) return;
    const float* W;
    int r, KS;
    if (gid < WPK_EMBT) { W = wts; r = gid; KS = 1; }                       // embed user 32x64
    else if (gid < WPK_CONV) { W = wts + 2112; r = gid - WPK_EMBT; KS = 2; } // embed txn 64x64
    else {
        int mat = (gid - WPK_CONV) >> 12;
        W = wts + 6272 + mat * 4096;
        r = (gid - WPK_CONV) & 4095;
        KS = 2;
    }
    int j = r & 7;
    int lane = (r >> 3) & 63;
    int f = r >> 9;
    int ct = f / KS;
    int s = f - ct * KS;
    int k = 32 * s + 8 * (lane >> 4) + j;
    int n = 16 * ct + (lane & 15);
    wpk[gid] = (_Float16)W[k * 64 + n];
}

// ---------------- partition pass 1: per-block bucket counts (LDS) ----------------
__device__ __forceinline__ void p1_dev(int bid, const int* __restrict__ eu2u,
                                       const int* __restrict__ et2t,
                                       const int* __restrict__ eu2t,
                                       const int* __restrict__ et2u,
                                       int* __restrict__ gcnt, int* __restrict__ bofs) {
    __shared__ int cnt[NBKT];
    for (int j = threadIdx.x; j < NBKT; j += 256) cnt[j] = 0;
    __syncthreads();
    for (int i = bid * 256 + threadIdx.x; i < 6 * NE_; i += PB1 * 256) {
        int b;
        if (i < 4 * NE_) {
            int m;
            if (i < NE_)          m = eu2u[i + NE_];
            else if (i < 2 * NE_) m = NU_ + et2t[i];          // (i-NE_) + NE_
            else if (i < 3 * NE_) m = NU_ + eu2t[i - NE_];    // (i-2NE_) + NE_
            else                  m = et2u[i - 2 * NE_];      // (i-3NE_) + NE_
            b = m >> 11;
        } else {
            int m2 = (i < 5 * NE_) ? eu2t[i - 4 * NE_] : (NU_ + et2u[i - 5 * NE_]);
            b = NBKC + (m2 >> 11);
        }
        atomicAdd(&cnt[b], 1);
    }
    __syncthreads();
    for (int j = threadIdx.x; j < NBKT; j += 256) {
        bofs[bid * NBKT + j] = atomicAdd(&gcnt[j], cnt[j]);
    }
}

// ---------------- MFMA embed: out[16x64] = X[16xK] @ W[Kx64] + bias (h stored f16) ----------------
template <int K>
__device__ __forceinline__ void embed_mfma_dev(int t0, int tstride, int ntiles,
                                               const void* __restrict__ x,
                                               const _Float16* __restrict__ Wpk,
                                               const float* __restrict__ bias,
                                               _Float16* __restrict__ out,
                                               const int* __restrict__ flag) {
    constexpr int KS = K / 32;
    const int lane = threadIdx.x & 63;
    const int rq = lane & 15;
    const int oct = lane >> 4;

    f16x8 bf[4][KS];
#pragma unroll
    for (int ct = 0; ct < 4; ++ct)
#pragma unroll
        for (int s = 0; s < KS; ++s)
            bf[ct][s] = *(const f16x8*)(Wpk + (((ct * KS + s) << 9) + (lane << 3)));
    float bv[4];
#pragma unroll
    for (int ct = 0; ct < 4; ++ct) bv[ct] = bias[16 * ct + rq];

    const bool isb = flag[0] != 0;

    for (int t = t0; t < ntiles; t += tstride) {
        const int r0 = t << 4;
        f16x8 a[KS];
        if (isb) {
            const unsigned short* xr = (const unsigned short*)x + (size_t)(r0 + rq) * K + 8 * oct;
#pragma unroll
            for (int s = 0; s < KS; ++s) {
                u16x8 uv = *(const u16x8*)(xr + 32 * s);
                f16x8 v;
#pragma unroll
                for (int j = 0; j < 8; ++j)
                    v[j] = (_Float16)__uint_as_float(((unsigned int)uv[j]) << 16);
                a[s] = v;
            }
        } else {
            const float* xr = (const float*)x + (size_t)(r0 + rq) * K + 8 * oct;
#pragma unroll
            for (int s = 0; s < KS; ++s) {
                float4 x0 = *(const float4*)(xr + 32 * s);
                float4 x1 = *(const float4*)(xr + 32 * s + 4);
                f16x8 v;
                v[0] = (_Float16)x0.x; v[1] = (_Float16)x0.y;
                v[2] = (_Float16)x0.z; v[3] = (_Float16)x0.w;
                v[4] = (_Float16)x1.x; v[5] = (_Float16)x1.y;
                v[6] = (_Float16)x1.z; v[7] = (_Float16)x1.w;
                a[s] = v;
            }
        }

        f32x4 acc[4];
#pragma unroll
        for (int ct = 0; ct < 4; ++ct) acc[ct] = (f32x4){0.f, 0.f, 0.f, 0.f};
#pragma unroll
        for (int ct = 0; ct < 4; ++ct)
#pragma unroll
            for (int s = 0; s < KS; ++s)
                acc[ct] = __builtin_amdgcn_mfma_f32_16x16x32_f16(a[s], bf[ct][s], acc[ct], 0, 0, 0);

        const int rb = r0 + (oct << 2);
#pragma unroll
        for (int ct = 0; ct < 4; ++ct)
#pragma unroll
            for (int g = 0; g < 4; ++g)
                out[(size_t)(rb + g) * HD + 16 * ct + rq] = (_Float16)(acc[ct][g] + bv[ct]);
    }
}

__global__ __launch_bounds__(256) void fused_p1_embed(
    const int* __restrict__ eu2u, const int* __restrict__ et2t,
    const int* __restrict__ eu2t, const int* __restrict__ et2u,
    int* __restrict__ gcnt, int* __restrict__ bofs,
    const void* __restrict__ x_user, const void* __restrict__ x_txn,
    const _Float16* __restrict__ wpk,
    const float* __restrict__ bembu, const float* __restrict__ bembt,
    _Float16* __restrict__ hu, _Float16* __restrict__ ht, const int* __restrict__ flag) {
    int b = blockIdx.x;
    int wid = threadIdx.x >> 6;
    if (b < PB1) {
        p1_dev(b, eu2u, et2t, eu2t, et2u, gcnt, bofs);
    } else if (b < PB1 + EMU) {
        embed_mfma_dev<32>((b - PB1) * 4 + wid, EMU * 4, NU_ / 16, x_user,
                           wpk + WPK_EMBU, bembu, hu, flag);
    } else {
        embed_mfma_dev<64>((b - PB1 - EMU) * 4 + wid, EMT * 4, NT_ / 16, x_txn,
                           wpk + WPK_EMBT, bembt, ht, flag);
    }
}

// ---------------- partition pass 2: scatter (mirrors p1's item mapping) ----------------
// CSR item packed u32: [src:18|tag:1|mlow:11]. Prefix over gcnt computed per-block in LDS
// (block 0 publishes gbase for bucket_count/place).
__global__ __launch_bounds__(256) void p2_scatter(
    const int* __restrict__ eu2u, const int* __restrict__ et2t,
    const int* __restrict__ eu2t, const int* __restrict__ et2u,
    const int* __restrict__ gcnt, int* __restrict__ gbase, const int* __restrict__ bofs,
    unsigned int* __restrict__ part_csr, unsigned int* __restrict__ part_src) {
    __shared__ int gb[NBKT];
    __shared__ int lofs[NBKT];
    const int t = threadIdx.x;
    for (int j = t; j < NBKT; j += 256) { lofs[j] = 0; gb[j] = gcnt[j]; }
    __syncthreads();
    if (t == 0) {
        int s = 0;
        for (int j = 0; j < NBKC; ++j) { int c = gb[j]; gb[j] = s; s += c; }
        s = 0;
        for (int j = NBKC; j < NBKT; ++j) { int c = gb[j]; gb[j] = s; s += c; }
    }
    __syncthreads();
    const int bid = blockIdx.x;
    if (bid == 0)
        for (int j = t; j < NBKT; j += 256) gbase[j] = gb[j];
    for (int i = bid * 256 + t; i < 6 * NE_; i += PB1 * 256) {
        if (i < 4 * NE_) {
            int m; unsigned int src, tag;
            if (i < NE_)          { m = eu2u[i + NE_];        src = (unsigned int)eu2u[i];           tag = 0u; }
            else if (i < 2 * NE_) { m = NU_ + et2t[i];        src = (unsigned int)et2t[i - NE_];     tag = 1u; tag = 0u; }
            else if (i < 3 * NE_) { m = NU_ + eu2t[i - NE_];  src = (unsigned int)eu2t[i - 2 * NE_]; tag = 1u; }
            else                  { m = et2u[i - 2 * NE_];    src = (unsigned int)et2u[i - 3 * NE_]; tag = 1u; }
            int b = m >> 11;
            int l = atomicAdd(&lofs[b], 1);
            int pos = gb[b] + bofs[bid * NBKT + b] + l;
            part_csr[pos] = (src << 12) | (tag << 11) | (unsigned int)(m & (BKP - 1));
        } else {
            int m2 = (i < 5 * NE_) ? eu2t[i - 4 * NE_] : (NU_ + et2u[i - 5 * NE_]);
            int b = NBKC + (m2 >> 11);
            int l = atomicAdd(&lofs[b], 1);
            int pos = gb[b] + bofs[bid * NBKT + b] + l;
            part_src[pos] = (unsigned int)m2;
        }
    }
}

// ---------------- per-bucket exact counting (LDS atomics only) ----------------
__global__ __launch_bounds__(1024) void bucket_count(const unsigned int* __restrict__ part_csr,
                                                     const unsigned int* __restrict__ part_src,
                                                     const int* __restrict__ gcnt,
                                                     const int* __restrict__ gbase,
                                                     int* __restrict__ hist) {
    __shared__ int cA[BKP];
    __shared__ int cB[BKP];
    const int b = blockIdx.x;
    const int n = gcnt[b];
    const int base = gbase[b];
    const int t = threadIdx.x;
    for (int j = t; j < BKP; j += 1024) { cA[j] = 0; cB[j] = 0; }
    __syncthreads();
    if (b < NBKC) {
        for (int i = t; i < n; i += 1024) {
            unsigned int it = part_csr[base + i];
            int l = (int)(it & (BKP - 1));
            if (it & 0x800u) atomicAdd(&cB[l], 1);
            else             atomicAdd(&cA[l], 1);
        }
        __syncthreads();
        const int m0 = b << 11;
        for (int j = t; j < BKP; j += 1024) {
            int m = m0 + j;
            if (m < NU_ + NT_) {
                int oA = (m < NU_) ? (OFF0 + m) : (OFF1 + (m - NU_));
                int oB = (m < NU_) ? (OFF3 + m) : (OFF2 + (m - NU_));
                hist[oA] = cA[j];
                hist[oB] = cB[j];
            }
        }
    } else {
        for (int i = t; i < n; i += 1024) {
            unsigned int m2 = part_src[base + i];
            atomicAdd(&cA[(int)(m2 & (BKP - 1))], 1);
        }
        __syncthreads();
        const int m0 = (b - NBKC) << 11;
        for (int j = t; j < BKP; j += 1024) {
            int m2 = m0 + j;
            if (m2 < NU_ + NT_) {
                int o = (m2 < NU_) ? (OFF4 + m2) : (OFF5 + (m2 - NU_));
                hist[o] = cA[j];
            }
        }
    }
}

// ---------------- per-bucket CSR placement (LDS bump allocators) ----------------
__global__ __launch_bounds__(1024) void bucket_place(const unsigned int* __restrict__ part_csr,
                                                     const int* __restrict__ gcnt,
                                                     const int* __restrict__ gbase,
                                                     const int* __restrict__ rp,
                                                     int* __restrict__ colU,
                                                     int* __restrict__ colT) {
    __shared__ int fl[BKP];
    const int b = blockIdx.x;
    const int n = gcnt[b];
    const int base = gbase[b];
    const int t = threadIdx.x;
    for (int j = t; j < BKP; j += 1024) fl[j] = 0;
    __syncthreads();
    const int m0 = b << 11;
    for (int i = t; i < n; i += 1024) {
        unsigned int it = part_csr[base + i];
        int mlow = (int)(it & (BKP - 1));
        int m = m0 + mlow;
        int ofs = atomicAdd(&fl[mlow], 1);
        // col value: byte offset (src<<6) with tag in bit 31
        int colv = (int)(((it >> 12) << 6) | ((it & 0x800u) << 20));
        if (m < NU_) colU[rp[m] + ofs] = colv;
        else         colT[rp[m] + ofs] = colv;
    }
}

// ---------------- MFMA dual GEMM (h f16, packed weights) ----------------
__device__ __forceinline__ void gemm_mfma_dev(int t0, int tstride, int ntiles,
                                              const _Float16* __restrict__ h,
                                              const _Float16* __restrict__ WApk,
                                              const _Float16* __restrict__ WBpk,
                                              const float* __restrict__ scA,
                                              const float* __restrict__ scB,
                                              unsigned char* __restrict__ mA,
                                              unsigned char* __restrict__ mB) {
    const int lane = threadIdx.x & 63;
    const int rq = lane & 15;
    const int oct = lane >> 4;

    f16x8 bf[2][4][2];
#pragma unroll
    for (int m = 0; m < 2; ++m) {
        const _Float16* P = m ? WBpk : WApk;
#pragma unroll
        for (int ct = 0; ct < 4; ++ct)
#pragma unroll
            for (int s = 0; s < 2; ++s)
                bf[m][ct][s] = *(const f16x8*)(P + ((((ct << 1) + s) << 9) + (lane << 3)));
    }

    for (int t = t0; t < ntiles; t += tstride) {
        const int r0 = t << 4;
        const _Float16* hr = h + (size_t)(r0 + rq) * HD + 8 * oct;
        f16x8 a0 = *(const f16x8*)(hr);
        f16x8 a1 = *(const f16x8*)(hr + 32);

        f32x4 acc[2][4];
#pragma unroll
        for (int m = 0; m < 2; ++m)
#pragma unroll
            for (int ct = 0; ct < 4; ++ct) acc[m][ct] = (f32x4){0.f, 0.f, 0.f, 0.f};

#pragma unroll
        for (int m = 0; m < 2; ++m)
#pragma unroll
            for (int ct = 0; ct < 4; ++ct) {
                acc[m][ct] = __builtin_amdgcn_mfma_f32_16x16x32_f16(a0, bf[m][ct][0],
                                                                   acc[m][ct], 0, 0, 0);
                acc[m][ct] = __builtin_amdgcn_mfma_f32_16x16x32_f16(a1, bf[m][ct][1],
                                                                   acc[m][ct], 0, 0, 0);
            }

        const int rb = r0 + (oct << 2);
        float sa[4], sb[4];
#pragma unroll
        for (int g = 0; g < 4; ++g) { sa[g] = scA[rb + g]; sb[g] = scB[rb + g]; }
#pragma unroll
        for (int ct = 0; ct < 4; ++ct)
#pragma unroll
            for (int g = 0; g < 4; ++g) {
                mA[(size_t)(rb + g) * HD + 16 * ct + rq] = enc_fp8(acc[0][ct][g] * sa[g]);
                mB[(size_t)(rb + g) * HD + 16 * ct + rq] = enc_fp8(acc[1][ct][g] * sb[g]);
            }
    }
}

__global__ __launch_bounds__(256) void gemm_dual_both(
    const _Float16* __restrict__ hu, const _Float16* __restrict__ ht,
    const _Float16* __restrict__ W0, const _Float16* __restrict__ Wu2t,
    const _Float16* __restrict__ Wt, const _Float16* __restrict__ Wt2u,
    const float* __restrict__ dinv,
    unsigned char* __restrict__ m_uu, unsigned char* __restrict__ m_ut,
    unsigned char* __restrict__ m_tt, unsigned char* __restrict__ m_tu) {
    int b = blockIdx.x;
    int wid = threadIdx.x >> 6;
    if (b < GMU) {
        gemm_mfma_dev(b * 4 + wid, GMU * 4, NU_ / 16, hu, W0, Wu2t,
                      dinv + OFF0, dinv + OFF4, m_uu, m_ut);
    } else {
        gemm_mfma_dev((b - GMU) * 4 + wid, GMT * 4, NT_ / 16, ht, Wt, Wt2u,
                      dinv + OFF1, dinv + OFF5, m_tt, m_tu);
    }
}

// ---------------- gather: one dst per 8-lane group, 8-deep MLP, col prefetch ----------------
__device__ __forceinline__ void gather_dev(int blk, const unsigned char* __restrict__ msg,
                                           unsigned int offB,
                                           const int4* __restrict__ meta,
                                           const int* __restrict__ col,
                                           const float* __restrict__ ba,
                                           const float* __restrict__ bb,
                                           _Float16* __restrict__ out, int N) {
    const int lane = threadIdx.x & 63;
    const int grp = lane >> 3;
    const int sub = lane & 7;
    const int d = (blk << 5) + ((threadIdx.x >> 6) << 3) + grp;
    const bool valid = d < N;

    int4 mt = make_int4(0, 0, 0, 0);
    if (valid) mt = meta[d];
    const int st = mt.x;
    const int cnt = mt.y;
    const float dA = __int_as_float(mt.z);   // 0.5 * dinv folded in
    const float dB = __int_as_float(mt.w);
    const unsigned char* msgL = msg + (sub << 3);

    floatx2 acc[4];
#pragma unroll
    for (int q = 0; q < 4; ++q) acc[q] = (floatx2){0.f, 0.f};

    auto consume = [&](uint2 u, float s) {
        floatx2 s2; s2.x = s; s2.y = s;
#if __has_builtin(__builtin_amdgcn_cvt_pk_f32_fp8)
        acc[0] += __builtin_amdgcn_cvt_pk_f32_fp8((int)u.x, false) * s2;
        acc[1] += __builtin_amdgcn_cvt_pk_f32_fp8((int)u.x, true) * s2;
        acc[2] += __builtin_amdgcn_cvt_pk_f32_fp8((int)u.y, false) * s2;
        acc[3] += __builtin_amdgcn_cvt_pk_f32_fp8((int)u.y, true) * s2;
#else
        float f[8];
        dec4_fp8(u.x, f);
        dec4_fp8(u.y, f + 4);
        acc[0].x += f[0] * s; acc[0].y += f[1] * s;
        acc[1].x += f[2] * s; acc[1].y += f[3] * s;
        acc[2].x += f[4] * s; acc[2].y += f[5] * s;
        acc[3].x += f[6] * s; acc[3].y += f[7] * s;
#endif
    };

    // self row (each group adds its own dst's A-message)
    if (valid) {
        uint2 uself = *(const uint2*)(msgL + ((unsigned int)d << 6));
        consume(uself, dA);
    }

    // edge loop: 8 edges per chunk per group, 8-deep issue then consume, col prefetched
    int cw = (sub < cnt) ? col[st + sub] : 0;
    int done = 0;
    while (done < cnt) {
        int rem = cnt - done;
        if (rem > 8) rem = 8;

        uint2 ub0, ub1, ub2, ub3, ub4, ub5, ub6, ub7;
        float sc0, sc1, sc2, sc3, sc4, sc5, sc6, sc7;

        auto issue = [&](int p, uint2& ub, float& sc) {
            int c = __shfl(cw, (grp << 3) + p);
            unsigned int off = ((unsigned int)c & 0x7fffffffu) + ((c < 0) ? offB : 0u);
            sc = (p < rem) ? ((c < 0) ? dB : dA) : 0.f;
            ub = *(const uint2*)(msgL + off);
        };

        issue(0, ub0, sc0);
        issue(1, ub1, sc1);
        issue(2, ub2, sc2);
        issue(3, ub3, sc3);
        issue(4, ub4, sc4);
        issue(5, ub5, sc5);
        issue(6, ub6, sc6);
        issue(7, ub7, sc7);

        int nd = done + 8;
        int cw2 = (nd + sub < cnt) ? col[st + nd + sub] : 0;

        consume(ub0, sc0);
        consume(ub1, sc1);
        consume(ub2, sc2);
        consume(ub3, sc3);
        consume(ub4, sc4);
        consume(ub5, sc5);
        consume(ub6, sc6);
        consume(ub7, sc7);

        cw = cw2;
        done = nd;
    }

    if (valid) {
        const int col0 = sub << 3;
        float4 a0 = *(const float4*)(ba + col0);
        float4 a1 = *(const float4*)(ba + col0 + 4);
        float4 c0 = *(const float4*)(bb + col0);
        float4 c1 = *(const float4*)(bb + col0 + 4);
        float af[8] = {acc[0].x, acc[0].y, acc[1].x, acc[1].y,
                       acc[2].x, acc[2].y, acc[3].x, acc[3].y};
        float bf[8] = {a0.x + c0.x, a0.y + c0.y, a0.z + c0.z, a0.w + c0.w,
                       a1.x + c1.x, a1.y + c1.y, a1.z + c1.z, a1.w + c1.w};
        f16x8 o;
#pragma unroll
        for (int k = 0; k < 8; ++k)
            o[k] = (_Float16)fmaxf(af[k] + 0.5f * bf[k], 0.f);
        *(f16x8*)(out + ((size_t)d << 6) + col0) = o;
    }
}

__global__ __launch_bounds__(256) void gather_both(
    const unsigned char* __restrict__ msgU, const unsigned char* __restrict__ msgT,
    const int4* __restrict__ meta,
    const int* __restrict__ colU, const int* __restrict__ colT,
    const float* __restrict__ bU0, const float* __restrict__ bU1,
    const float* __restrict__ bT0, const float* __restrict__ bT1,
    _Float16* __restrict__ hu, _Float16* __restrict__ ht) {
    int b = blockIdx.x;
    if (b < GBU) {
        gather_dev(b, msgU, (unsigned int)NU_ * HD, meta, colU, bU0, bU1, hu, NU_);
    } else {
        gather_dev(b - GBU, msgT, (unsigned int)NT_ * HD, meta + NU_, colT, bT0, bT1, ht, NT_);
    }
}

// ---------------- CSR scan kernels (dinv folded in) ----------------
__global__ __launch_bounds__(256) void scan1m(const int* __restrict__ hist, int* __restrict__ rp,
                                              int* __restrict__ bsums, float* __restrict__ dinv) {
    int b = blockIdx.x, t = threadIdx.x;
    int r, lb, n, rpbase, oA, oB;
    if (b < NBU) { r = 0; lb = b;       n = NU_; rpbase = 0;   oA = OFF0; oB = OFF3; }
    else         { r = 1; lb = b - NBU; n = NT_; rpbase = NU_; oA = OFF1; oB = OFF2; }
    int i = lb * 256 + t;
    int hA = (i < n) ? hist[oA + i] : 0;
    int hB = (i < n) ? hist[oB + i] : 0;
    if (i < n) {
        dinv[oA + i] = rsqrtf((float)hA + 1.0f);                       // self-loop type
        dinv[oB + i] = (hB > 0) ? rsqrtf((float)hB) : 0.f;             // bipartite dst
    }
    int v = hA + hB;
    __shared__ int s[256];
    s[t] = v;
    __syncthreads();
    for (int off = 1; off < 256; off <<= 1) {
        int x = (t >= off) ? s[t - off] : 0;
        __syncthreads();
        s[t] += x;
        __syncthreads();
    }
    if (i < n) rp[rpbase + i] = s[t] - v;
    if (t == 255) bsums[r * 1024 + lb] = s[255];
}

__global__ __launch_bounds__(1024) void scan2m(int* __restrict__ bsums) {
    int r = blockIdx.x, t = threadIdx.x;
    const int nb = r ? NBT : NBU;
    int v = (t < nb) ? bsums[r * 1024 + t] : 0;
    __shared__ int s[1024];
    s[t] = v;
    __syncthreads();
    for (int off = 1; off < 1024; off <<= 1) {
        int x = (t >= off) ? s[t - off] : 0;
        __syncthreads();
        s[t] += x;
        __syncthreads();
    }
    if (t < nb) bsums[r * 1024 + t] = s[t] - v;
}

// scan3m: finalize rp, src dinv, and pack gather metadata {rp, cnt, 0.5dA, 0.5dB}
__global__ void scan3m(int* __restrict__ rp, const int* __restrict__ bsums,
                       const int* __restrict__ hist, float* __restrict__ dinv,
                       int4* __restrict__ meta) {
    int gid = blockIdx.x * blockDim.x + threadIdx.x;
    if (gid >= RPT2) return;
    int r = (gid < NU_) ? 0 : 1;
    int base = r ? NU_ : 0;
    int lb = (gid - base) >> 8;
    int rpf = rp[gid] + bsums[r * 1024 + lb];
    rp[gid] = rpf;
    // src dinv (for GEMM scaling)
    int si = r ? (OFF5 + gid - NU_) : (OFF4 + gid);
    int h = hist[si];
    dinv[si] = (h > 0) ? rsqrtf((float)h) : 0.f;
    // packed gather meta (0.5 HeteroConv-mean factor folded in)
    int oA = r ? (OFF1 + gid - NU_) : (OFF0 + gid);
    int oB = r ? (OFF2 + gid - NU_) : (OFF3 + gid);
    int hA = hist[oA];
    int hB = hist[oB];
    float dA = 0.5f * rsqrtf((float)hA + 1.0f);
    float dB = (hB > 0) ? 0.5f * rsqrtf((float)hB) : 0.f;
    int4 mt;
    mt.x = rpf;
    mt.y = hA + hB;
    mt.z = __float_as_int(dA);
    mt.w = __float_as_int(dB);
    meta[gid] = mt;
}

// ---------------- readout ----------------
__global__ __launch_bounds__(256) void colmean_both(const _Float16* __restrict__ hu,
                                                    const _Float16* __restrict__ ht,
                                                    float* __restrict__ gsum) {
    const bool isU = blockIdx.x < 512;
    const _Float16* h = isU ? hu : ht;
    const int n = isU ? NU_ : NT_;
    const float scale = isU ? 0.5f / NU_ : 0.5f / NT_;
    const int blk = isU ? blockIdx.x : blockIdx.x - 512;
    const int lane = threadIdx.x & 63;
    const int w = threadIdx.x >> 6;
    float s = 0.f;
    for (int r = blk * 4 + w; r < n; r += 512 * 4)
        s += (float)h[(size_t)r * HD + lane];
    __shared__ float red[256];
    red[threadIdx.x] = s;
    __syncthreads();
    if (threadIdx.x < 64) {
        float t = red[threadIdx.x] + red[64 + threadIdx.x] + red[128 + threadIdx.x] +
                  red[192 + threadIdx.x];
        atomicAdd(&gsum[lane], t * scale);
    }
}

__global__ void head(const float* __restrict__ g, const float* __restrict__ W1,
                     const float* __restrict__ b1, const float* __restrict__ W2,
                     const float* __restrict__ b2, const int* __restrict__ flag,
                     void* __restrict__ out) {
    const int c = threadIdx.x;
    float x = b1[c];
    for (int k = 0; k < HD; ++k) x = fmaf(g[k], W1[k * HD + c], x);
    x = fmaxf(x, 0.f);
    float t = x * W2[c];
    for (int off = 32; off; off >>= 1) t += __shfl_down(t, off);
    if (c == 0) {
        float z = t + b2[0];
        float s = 1.f / (1.f + expf(-z));
        if (flag[0]) *(__hip_bfloat16*)out = __float2bfloat16(s);
        else *(float*)out = s;
    }
}

extern "C" void kernel_launch(void* const* d_in, const int* in_sizes, int n_in,
                              void* d_out, int out_size, void* d_ws, size_t ws_size,
                              hipStream_t stream) {
    const void* x_user = d_in[0];
    const void* x_txn  = d_in[1];
    const int* ei_u2u = (const int*)d_in[2];
    const int* ei_t2t = (const int*)d_in[3];
    const int* ei_u2t = (const int*)d_in[4];
    const int* ei_t2u = (const int*)d_in[5];

    // ---- workspace layout ----
    // h stored f16. Message tables ordered so each gather side's {A,B} pair is
    // contiguous: U: m_uu|m_tu ; T: m_tt|m_ut. wpk = packed f16 weight fragments.
    float* ws = (float*)d_ws;
    _Float16* hu = (_Float16*)ws;                     // NU*64 f16
    _Float16* ht = hu + (size_t)NU_ * HD;             // NT*64 f16
    float* dinv = (float*)(ht + (size_t)NT_ * HD);    // HTOT f32
    float* wts = dinv + HTOT;                         // 60432 (padded)
    float* gsum = wts + 60432;                        // 64
    _Float16* wpk = (_Float16*)(gsum + 64);           // WPK_TOT f16 = 27648 f32-slots
    unsigned char* m_uu = (unsigned char*)(wpk + WPK_TOT);  // NU rows fp8
    unsigned char* m_tu = m_uu + (size_t)NU_ * HD;      // NT rows
    unsigned char* m_tt = m_tu + (size_t)NT_ * HD;      // NT rows
    unsigned char* m_ut = m_tt + (size_t)NT_ * HD;      // NU rows
    int* hist = (int*)(m_ut + (size_t)NU_ * HD);      // HTOT
    int* aux  = hist + HTOT;                          // RPT2 region: gcnt/gbase/bofs
    int* rp   = aux + RPT2;                           // RPT2
    int* bsums = rp + RPT2;                           // 2048
    int* colU = bsums + 2048;                         // 2M
    int* colT = colU + 2 * NE_;                       // 2M
    int4* meta = (int4*)(colT + 2 * NE_);             // RPT2 (16B each)
    int* dflag = (int*)(meta + RPT2);                 // 1

    // partition bookkeeping in the old fill region (151,116 <= 300,000 ints)
    int* gcnt  = aux;               // NBKT
    int* gbase = gcnt + NBKT;       // NBKT
    int* bofs  = gbase + NBKT;      // PB1*NBKT = 150,528

    // partition payload aliases (consumed before layer-0 gemm/place writes)
    unsigned int* part_csr = (unsigned int*)m_uu;     // 4M u32 = 16 MB
    unsigned int* part_src = (unsigned int*)colU;     // 2M u32 = 8 MB

    // fp32 weight sub-pointers
    float* bembu = wts + 2048;       // 64
    float* bembt = wts + 6208;       // 64
    float* convbf = wts + 55424;     // 768
    float* W1f = wts + 56192;        // 4096
    float* b1f = W1f + 4096;         // 64
    float* W2f = b1f + 64;           // 64
    float* b2f = W2f + 64;           // 1

    hipMemsetAsync(gcnt, 0, (size_t)NBKT * sizeof(int), stream);

    detect_dtype<<<1, 256, 0, stream>>>((const unsigned short*)x_user, dflag, 2048);
    {
        Ptr10 p;
        for (int k = 0; k < 10; ++k) p.p[k] = d_in[6 + k];
        cvt_weights<<<(60417 + 255) / 256, 256, 0, stream>>>(p, wts, gsum, dflag);
    }
    pack_weights<<<(WPK_TOT + 255) / 256, 256, 0, stream>>>(wts, wpk);

    // ---- fused: partition pass 1 (LDS counts) + MFMA embedding GEMMs ----
    fused_p1_embed<<<PB1 + EMU + EMT, 256, 0, stream>>>(
        ei_u2u, ei_t2t, ei_u2t, ei_t2u, gcnt, bofs,
        x_user, x_txn, wpk, bembu, bembt, hu, ht, dflag);

    p2_scatter<<<PB1, 256, 0, stream>>>(ei_u2u, ei_t2t, ei_u2t, ei_t2u,
                                        gcnt, gbase, bofs, part_csr, part_src);
    bucket_count<<<NBKT, 1024, 0, stream>>>(part_csr, part_src, gcnt, gbase, hist);

    scan1m<<<NBTOT2, 256, 0, stream>>>(hist, rp, bsums, dinv);
    scan2m<<<2, 1024, 0, stream>>>(bsums);
    scan3m<<<(RPT2 + 255) / 256, 256, 0, stream>>>(rp, bsums, hist, dinv, meta);

    bucket_place<<<NBKC, 1024, 0, stream>>>(part_csr, gcnt, gbase, rp, colU, colT);

    for (int l = 0; l < NL; ++l) {
        const _Float16* W0   = wpk + WPK_CONV + ((size_t)l * 4 + 0) * 4096;
        const _Float16* Wt   = wpk + WPK_CONV + ((size_t)l * 4 + 1) * 4096;
        const _Float16* Wu2t = wpk + WPK_CONV + ((size_t)l * 4 + 2) * 4096;
        const _Float16* Wt2u = wpk + WPK_CONV + ((size_t)l * 4 + 3) * 4096;
        const float* B0   = convbf + ((size_t)l * 4 + 0) * HD;
        const float* Bt   = convbf + ((size_t)l * 4 + 1) * HD;
        const float* Bu2t = convbf + ((size_t)l * 4 + 2) * HD;
        const float* Bt2u = convbf + ((size_t)l * 4 + 3) * HD;

        gemm_dual_both<<<GMU + GMT, 256, 0, stream>>>(hu, ht, W0, Wu2t, Wt, Wt2u, dinv,
                                                      m_uu, m_ut, m_tt, m_tu);

        gather_both<<<GBU + GBT, 256, 0, stream>>>(m_uu, m_tt,
                                                   meta, colU, colT,
                                                   B0, Bt2u, Bt, Bu2t, hu, ht);
    }

    // ---- readout ----
    colmean_both<<<1024, 256, 0, stream>>>(hu, ht, gsum);
    head<<<1, 64, 0, stream>>>(gsum, W1f, b1f, W2f, b2f, dflag, d_out);
}

// Round 10
// 582.462 us; speedup vs baseline: 3.2863x; 1.0479x over previous
//
#include <hip/hip_runtime.h>
#include <hip/hip_bf16.h>
#include <hip/hip_fp8.h>

#define NU_ 100000
#define NT_ 200000
#define NE_ 1000000
#define HD  64
#define NL  3

// dinv region offsets (node-keyed; OFF2/OFF3 unused now)
#define OFF0 0                   // u2u dst (NU)  [selfloop]
#define OFF1 (NU_)               // t2t dst (NT)  [selfloop]
#define OFF4 (2 * NU_ + 2 * NT_) // u2t src (NU)
#define OFF5 (3 * NU_ + 2 * NT_) // t2u src (NT)
#define HTOT (3 * NU_ + 3 * NT_) // 900k
#define RPT2 (NU_ + NT_)         // merged node count (300k)

// bucket partition (no-far-atomic CSR build)
#define PB1  512           // partition blocks (256 threads each); p1/p2 must match
#define BKP  2048          // node-keys per bucket (key >> 11)
#define NBKC 147           // CSR buckets  (300k / 2048)
#define NBKS 147           // src buckets
#define NBKT (NBKC + NBKS) // 294

// packed-weight layout (f16 fragments, 512 f16 per fragment)
#define WPK_EMBU 0         // legacy (unused frags, kept for index simplicity)
#define WPK_EMBT 2048
#define WPK_CONV 6144      // 12 mats x 8 frags x 512
#define WPK_G0U  55296     // composed layer-0 user: 2 mats x 4 frags x 512
#define WPK_G0T  59392     // composed layer-0 txn: 2 mats x 8 frags x 512
#define WPK_TOT  67584
#define PK_ELEMS (WPK_TOT + 256)   // + composed biases (f32, separate array)
#define PKB      ((PK_ELEMS + 255) / 256)

// grids
#define GMU 512            // mfma gemm user blocks
#define GMT 1024           // mfma gemm txn blocks
#define GBU 3125           // NU/32 gather blocks (32 dsts per block)
#define GBT 6250           // NT/32 gather blocks

typedef float floatx2 __attribute__((ext_vector_type(2)));
typedef _Float16 f16x8 __attribute__((ext_vector_type(8)));
typedef float f32x4 __attribute__((ext_vector_type(4)));
typedef unsigned short u16x8 __attribute__((ext_vector_type(8)));

// ---------------- fp8 helpers ----------------
__device__ __forceinline__ unsigned char enc_fp8(float v) {
    return (unsigned char)__hip_cvt_float_to_fp8(v, __HIP_SATFINITE, __HIP_E4M3);
}

__device__ __forceinline__ float dec1_fp8(unsigned int u) {
    int e = (u >> 3) & 15;
    int m = u & 7;
    int mant = m | (e ? 8 : 0);
    if (u & 0x80) mant = -mant;
    int ex = (e ? e : 1) - 10;
    return (float)mant * __uint_as_float((unsigned int)(ex + 127) << 23);
}

__device__ __forceinline__ void dec4_fp8(unsigned int u, float* f) {
#if __has_builtin(__builtin_amdgcn_cvt_pk_f32_fp8)
    floatx2 lo = __builtin_amdgcn_cvt_pk_f32_fp8((int)u, false);
    floatx2 hi = __builtin_amdgcn_cvt_pk_f32_fp8((int)u, true);
    f[0] = lo.x; f[1] = lo.y; f[2] = hi.x; f[3] = hi.y;
#else
    f[0] = dec1_fp8(u & 0xff);
    f[1] = dec1_fp8((u >> 8) & 0xff);
    f[2] = dec1_fp8((u >> 16) & 0xff);
    f[3] = dec1_fp8((u >> 24) & 0xff);
#endif
}

// ---------------- dtype detection ----------------
__global__ void detect_dtype(const unsigned short* __restrict__ x, int* __restrict__ flag, int n) {
    __shared__ int s_big;
    if (threadIdx.x == 0) s_big = 0;
    __syncthreads();
    int big = 0;
    for (int i = threadIdx.x; i < n; i += blockDim.x) {
        float v = __uint_as_float(((unsigned int)x[i]) << 16);
        if (!(fabsf(v) < 1.0e4f)) big = 1;
    }
    if (big) atomicAdd(&s_big, 1);
    __syncthreads();
    if (threadIdx.x == 0) flag[0] = (s_big > 0) ? 0 : 1;
}

// ---------------- fused weight conversion (+ gsum zero) ----------------
struct Ptr10 { const void* p[10]; };

__global__ void cvt_weights(Ptr10 src, float* __restrict__ dst, float* __restrict__ gsum,
                            const int* __restrict__ flag) {
    const int c[11] = {0, 2048, 2112, 6208, 6272, 55424, 56192, 60288, 60352, 60416, 60417};
    int i = blockIdx.x * blockDim.x + threadIdx.x;
    if (i < 64) gsum[i] = 0.f;
    if (i >= 60417) return;
    int r = 0;
#pragma unroll
    for (int k = 1; k < 10; ++k)
        if (i >= c[k]) r = k;
    int e = i - c[r];
    if (flag[0]) {
        unsigned short u = ((const unsigned short*)src.p[r])[e];
        dst[i] = __uint_as_float(((unsigned int)u) << 16);
    } else {
        dst[i] = ((const float*)src.p[r])[e];
    }
}

// ---------------- pack weights (frag layout) + compose layer-0 (We@Wc, be@Wc) ----------------
__device__ __forceinline__ void pack_dev(int gid, const float* __restrict__ wts,
                                         _Float16* __restrict__ wpk,
                                         float* __restrict__ bcomp) {
    if (gid >= PK_ELEMS) return;
    if (gid < WPK_G0U) {
        const float* W;
        int r, KS;
        if (gid < WPK_EMBT) { W = wts; r = gid; KS = 1; }
        else if (gid < WPK_CONV) { W = wts + 2112; r = gid - WPK_EMBT; KS = 2; }
        else {
            int mat = (gid - WPK_CONV) >> 12;
            W = wts + 6272 + mat * 4096;
            r = (gid - WPK_CONV) & 4095;
            KS = 2;
        }
        int j = r & 7;
        int lane = (r >> 3) & 63;
        int f = r >> 9;
        int ct = f / KS;
        int s = f - ct * KS;
        int k = 32 * s + 8 * (lane >> 4) + j;
        int n = 16 * ct + (lane & 15);
        wpk[gid] = (_Float16)W[k * 64 + n];
    } else if (gid < WPK_TOT) {
        // composed layer-0 fragments: W' = We @ Wc
        const float* We;
        int matc, rr, KS;
        if (gid < WPK_G0T) {
            int r = gid - WPK_G0U;
            matc = (r >> 11) ? 2 : 0;            // W0 (u2u), Wu2t
            rr = r & 2047;
            We = wts;                            // [32][64]
            KS = 1;
        } else {
            int r = gid - WPK_G0T;
            matc = (r >> 12) ? 3 : 1;            // Wt (t2t), Wt2u
            rr = r & 4095;
            We = wts + 2112;                     // [64][64]
            KS = 2;
        }
        const float* Wc = wts + 6272 + matc * 4096;
        int j = rr & 7;
        int lane = (rr >> 3) & 63;
        int f = rr >> 9;
        int ct = f / KS;
        int s = f - ct * KS;
        int k = 32 * s + 8 * (lane >> 4) + j;
        int n = 16 * ct + (lane & 15);
        float acc = 0.f;
#pragma unroll
        for (int q = 0; q < 64; ++q)
            acc = fmaf(We[k * 64 + q], Wc[q * 64 + n], acc);
        wpk[gid] = (_Float16)acc;
    } else {
        // composed biases b' = be @ Wc  (mat-major: 4 x 64 f32)
        int q = gid - WPK_TOT;
        int mat = q >> 6;
        int n = q & 63;
        const float* be = (mat == 0 || mat == 2) ? (wts + 2048) : (wts + 6208);
        const float* Wc = wts + 6272 + mat * 4096;
        float acc = 0.f;
#pragma unroll
        for (int k = 0; k < 64; ++k)
            acc = fmaf(be[k], Wc[k * 64 + n], acc);
        bcomp[q] = acc;
    }
}

// ---------------- partition pass 1: per-block bucket counts (LDS) ----------------
__device__ __forceinline__ void p1_dev(int bid, const int* __restrict__ eu2u,
                                       const int* __restrict__ et2t,
                                       const int* __restrict__ eu2t,
                                       const int* __restrict__ et2u,
                                       int* __restrict__ gcnt, int* __restrict__ bofs) {
    __shared__ int cnt[NBKT];
    for (int j = threadIdx.x; j < NBKT; j += 256) cnt[j] = 0;
    __syncthreads();
    for (int i = bid * 256 + threadIdx.x; i < 6 * NE_; i += PB1 * 256) {
        int b;
        if (i < 4 * NE_) {
            int m;
            if (i < NE_)          m = eu2u[i + NE_];
            else if (i < 2 * NE_) m = NU_ + et2t[i];
            else if (i < 3 * NE_) m = NU_ + eu2t[i - NE_];
            else                  m = et2u[i - 2 * NE_];
            b = m >> 11;
        } else {
            int m2 = (i < 5 * NE_) ? eu2t[i - 4 * NE_] : (NU_ + et2u[i - 5 * NE_]);
            b = NBKC + (m2 >> 11);
        }
        atomicAdd(&cnt[b], 1);
    }
    __syncthreads();
    for (int j = threadIdx.x; j < NBKT; j += 256) {
        bofs[bid * NBKT + j] = atomicAdd(&gcnt[j], cnt[j]);
    }
}

// fused: p1 (edge bucket counts) + weight packing/composition (independent work)
__global__ __launch_bounds__(256) void fused_p1_pack(
    const int* __restrict__ eu2u, const int* __restrict__ et2t,
    const int* __restrict__ eu2t, const int* __restrict__ et2u,
    int* __restrict__ gcnt, int* __restrict__ bofs,
    const float* __restrict__ wts, _Float16* __restrict__ wpk, float* __restrict__ bcomp) {
    int b = blockIdx.x;
    if (b < PB1) {
        p1_dev(b, eu2u, et2t, eu2t, et2u, gcnt, bofs);
    } else {
        pack_dev((b - PB1) * 256 + threadIdx.x, wts, wpk, bcomp);
    }
}

// ---------------- partition pass 2: scatter (mirrors p1's item mapping) ----------------
// CSR item packed u32: [src:20|tag:1|mlow:11]; src<2^18 so fits.
__global__ __launch_bounds__(256) void p2_scatter(
    const int* __restrict__ eu2u, const int* __restrict__ et2t,
    const int* __restrict__ eu2t, const int* __restrict__ et2u,
    const int* __restrict__ gcnt, int* __restrict__ gbase, const int* __restrict__ bofs,
    unsigned int* __restrict__ part_csr, unsigned int* __restrict__ part_src) {
    __shared__ int gb[NBKT];
    __shared__ int lofs[NBKT];
    const int t = threadIdx.x;
    for (int j = t; j < NBKT; j += 256) { lofs[j] = 0; gb[j] = gcnt[j]; }
    __syncthreads();
    if (t == 0) {
        int s = 0;
        for (int j = 0; j < NBKC; ++j) { int c = gb[j]; gb[j] = s; s += c; }
        s = 0;
        for (int j = NBKC; j < NBKT; ++j) { int c = gb[j]; gb[j] = s; s += c; }
    }
    __syncthreads();
    const int bid = blockIdx.x;
    if (bid == 0)
        for (int j = t; j < NBKT; j += 256) gbase[j] = gb[j];
    for (int i = bid * 256 + t; i < 6 * NE_; i += PB1 * 256) {
        if (i < 4 * NE_) {
            int m; unsigned int src, tag;
            if (i < NE_)          { m = eu2u[i + NE_];        src = (unsigned int)eu2u[i];           tag = 0u; }
            else if (i < 2 * NE_) { m = NU_ + et2t[i];        src = (unsigned int)et2t[i - NE_];     tag = 0u; }
            else if (i < 3 * NE_) { m = NU_ + eu2t[i - NE_];  src = (unsigned int)eu2t[i - 2 * NE_]; tag = 1u; }
            else                  { m = et2u[i - 2 * NE_];    src = (unsigned int)et2u[i - 3 * NE_]; tag = 1u; }
            int b = m >> 11;
            int l = atomicAdd(&lofs[b], 1);
            int pos = gb[b] + bofs[bid * NBKT + b] + l;
            part_csr[pos] = (src << 12) | (tag << 11) | (unsigned int)(m & (BKP - 1));
        } else {
            int m2 = (i < 5 * NE_) ? eu2t[i - 4 * NE_] : (NU_ + et2u[i - 5 * NE_]);
            int b = NBKC + (m2 >> 11);
            int l = atomicAdd(&lofs[b], 1);
            int pos = gb[b] + bofs[bid * NBKT + b] + l;
            part_src[pos] = (unsigned int)m2;
        }
    }
}

// ---------------- bucket_build: count + LDS prefix scan + meta/dinv + CSR place ----------------
// CSR-bucket rp derivation: buckets are contiguous node ranges, so global CSR order =
// bucket-major node-major; rp[m] = gbase[b] + localPrefix(m) - (m>=NU ? 2M : 0)
// (total U-dst CSR items == 2*NE_ exactly: one per u2u + t2u edge).
__global__ __launch_bounds__(1024) void bucket_build(
    const unsigned int* __restrict__ part_csr, const unsigned int* __restrict__ part_src,
    const int* __restrict__ gcnt, const int* __restrict__ gbase,
    float* __restrict__ dinv, int4* __restrict__ meta,
    int* __restrict__ colU, int* __restrict__ colT) {
    const int b = blockIdx.x;
    const int t = threadIdx.x;
    if (b >= NBKC) {
        // src-degree bucket: count + dinv only
        __shared__ int cS[BKP];
        const int n = gcnt[b];
        const int base = gbase[b];
        for (int j = t; j < BKP; j += 1024) cS[j] = 0;
        __syncthreads();
        for (int i = t; i < n; i += 1024)
            atomicAdd(&cS[(int)(part_src[base + i] & (BKP - 1))], 1);
        __syncthreads();
        const int m0 = (b - NBKC) << 11;
        for (int j = t; j < BKP; j += 1024) {
            int m2 = m0 + j;
            if (m2 < NU_ + NT_) {
                int o = (m2 < NU_) ? (OFF4 + m2) : (OFF5 + (m2 - NU_));
                int h = cS[j];
                dinv[o] = (h > 0) ? rsqrtf((float)h) : 0.f;
            }
        }
        return;
    }
    __shared__ int cA[BKP];
    __shared__ int cB[BKP];
    __shared__ int lp[BKP];
    __shared__ int s1[1024];
    const int n = gcnt[b];
    const int base = gbase[b];
    for (int j = t; j < BKP; j += 1024) { cA[j] = 0; cB[j] = 0; }
    __syncthreads();
    for (int i = t; i < n; i += 1024) {
        unsigned int it = part_csr[base + i];
        int l = (int)(it & (BKP - 1));
        if (it & 0x800u) atomicAdd(&cB[l], 1);
        else             atomicAdd(&cA[l], 1);
    }
    __syncthreads();
    // exclusive prefix of (cA+cB) over 2048 nodes (thread owns 2)
    const int j0 = t << 1, j1 = j0 + 1;
    const int a0 = cA[j0] + cB[j0];
    const int a1 = cA[j1] + cB[j1];
    const int ps = a0 + a1;
    s1[t] = ps;
    __syncthreads();
    for (int off = 1; off < 1024; off <<= 1) {
        int x = (t >= off) ? s1[t - off] : 0;
        __syncthreads();
        s1[t] += x;
        __syncthreads();
    }
    const int excl = s1[t] - ps;
    lp[j0] = excl;
    lp[j1] = excl + a0;
    __syncthreads();
    // per-node meta + selfloop dinv
    const int m0 = b << 11;
    const int gb0 = gbase[b];
    for (int j = t; j < BKP; j += 1024) {
        int m = m0 + j;
        if (m < NU_ + NT_) {
            int hA = cA[j], hB = cB[j];
            float dslf = rsqrtf((float)hA + 1.0f);
            int oA = (m < NU_) ? (OFF0 + m) : (OFF1 + (m - NU_));
            dinv[oA] = dslf;
            int4 mt;
            mt.x = gb0 + lp[j] - ((m >= NU_) ? 2 * NE_ : 0);
            mt.y = hA + hB;
            mt.z = __float_as_int(0.5f * dslf);
            mt.w = __float_as_int((hB > 0) ? 0.5f * rsqrtf((float)hB) : 0.f);
            meta[m] = mt;
        }
    }
    __syncthreads();
    for (int j = t; j < BKP; j += 1024) cA[j] = 0;   // reuse as bump counters
    __syncthreads();
    for (int i = t; i < n; i += 1024) {
        unsigned int it = part_csr[base + i];
        int mlow = (int)(it & (BKP - 1));
        int ofs = atomicAdd(&cA[mlow], 1);
        int g = gb0 + lp[mlow] + ofs;
        int colv = (int)(((it >> 12) << 6) | ((it & 0x800u) << 20));
        int m = m0 + mlow;
        if (m < NU_) colU[g] = colv;
        else         colT[g - 2 * NE_] = colv;
    }
}

// ---------------- layer-0 GEMM: msg = (X @ W' + b') * sc  (embed folded in) ----------------
template <int K>
__device__ __forceinline__ void gemm0_dev(int t0, int tstride, int ntiles,
                                          const void* __restrict__ x,
                                          const _Float16* __restrict__ WApk,
                                          const _Float16* __restrict__ WBpk,
                                          const float* __restrict__ bA,
                                          const float* __restrict__ bB,
                                          const float* __restrict__ scA,
                                          const float* __restrict__ scB,
                                          unsigned char* __restrict__ mA,
                                          unsigned char* __restrict__ mB,
                                          const int* __restrict__ flag) {
    constexpr int KS = K / 32;
    const int lane = threadIdx.x & 63;
    const int rq = lane & 15;
    const int oct = lane >> 4;

    f16x8 bf[2][4][KS];
#pragma unroll
    for (int m = 0; m < 2; ++m) {
        const _Float16* P = m ? WBpk : WApk;
#pragma unroll
        for (int ct = 0; ct < 4; ++ct)
#pragma unroll
            for (int s = 0; s < KS; ++s)
                bf[m][ct][s] = *(const f16x8*)(P + (((ct * KS + s) << 9) + (lane << 3)));
    }
    float bvA[4], bvB[4];
#pragma unroll
    for (int ct = 0; ct < 4; ++ct) { bvA[ct] = bA[16 * ct + rq]; bvB[ct] = bB[16 * ct + rq]; }

    const bool isb = flag[0] != 0;

    for (int t = t0; t < ntiles; t += tstride) {
        const int r0 = t << 4;
        f16x8 a[KS];
        if (isb) {
            const unsigned short* xr = (const unsigned short*)x + (size_t)(r0 + rq) * K + 8 * oct;
#pragma unroll
            for (int s = 0; s < KS; ++s) {
                u16x8 uv = *(const u16x8*)(xr + 32 * s);
                f16x8 v;
#pragma unroll
                for (int j = 0; j < 8; ++j)
                    v[j] = (_Float16)__uint_as_float(((unsigned int)uv[j]) << 16);
                a[s] = v;
            }
        } else {
            const float* xr = (const float*)x + (size_t)(r0 + rq) * K + 8 * oct;
#pragma unroll
            for (int s = 0; s < KS; ++s) {
                float4 x0 = *(const float4*)(xr + 32 * s);
                float4 x1 = *(const float4*)(xr + 32 * s + 4);
                f16x8 v;
                v[0] = (_Float16)x0.x; v[1] = (_Float16)x0.y;
                v[2] = (_Float16)x0.z; v[3] = (_Float16)x0.w;
                v[4] = (_Float16)x1.x; v[5] = (_Float16)x1.y;
                v[6] = (_Float16)x1.z; v[7] = (_Float16)x1.w;
                a[s] = v;
            }
        }

        f32x4 acc[2][4];
#pragma unroll
        for (int m = 0; m < 2; ++m)
#pragma unroll
            for (int ct = 0; ct < 4; ++ct) acc[m][ct] = (f32x4){0.f, 0.f, 0.f, 0.f};
#pragma unroll
        for (int m = 0; m < 2; ++m)
#pragma unroll
            for (int ct = 0; ct < 4; ++ct)
#pragma unroll
                for (int s = 0; s < KS; ++s)
                    acc[m][ct] = __builtin_amdgcn_mfma_f32_16x16x32_f16(a[s], bf[m][ct][s],
                                                                       acc[m][ct], 0, 0, 0);

        const int rb = r0 + (oct << 2);
        float sa[4], sb[4];
#pragma unroll
        for (int g = 0; g < 4; ++g) { sa[g] = scA[rb + g]; sb[g] = scB[rb + g]; }
#pragma unroll
        for (int ct = 0; ct < 4; ++ct)
#pragma unroll
            for (int g = 0; g < 4; ++g) {
                mA[(size_t)(rb + g) * HD + 16 * ct + rq] =
                    enc_fp8((acc[0][ct][g] + bvA[ct]) * sa[g]);
                mB[(size_t)(rb + g) * HD + 16 * ct + rq] =
                    enc_fp8((acc[1][ct][g] + bvB[ct]) * sb[g]);
            }
    }
}

__global__ __launch_bounds__(256) void gemm0_both(
    const void* __restrict__ x_user, const void* __restrict__ x_txn,
    const _Float16* __restrict__ wpk, const float* __restrict__ bcomp,
    const float* __restrict__ dinv,
    unsigned char* __restrict__ m_uu, unsigned char* __restrict__ m_ut,
    unsigned char* __restrict__ m_tt, unsigned char* __restrict__ m_tu,
    const int* __restrict__ flag) {
    int b = blockIdx.x;
    int wid = threadIdx.x >> 6;
    if (b < GMU) {
        gemm0_dev<32>(b * 4 + wid, GMU * 4, NU_ / 16, x_user,
                      wpk + WPK_G0U, wpk + WPK_G0U + 2048,
                      bcomp + 0, bcomp + 128,
                      dinv + OFF0, dinv + OFF4, m_uu, m_ut, flag);
    } else {
        gemm0_dev<64>((b - GMU) * 4 + wid, GMT * 4, NT_ / 16, x_txn,
                      wpk + WPK_G0T, wpk + WPK_G0T + 4096,
                      bcomp + 64, bcomp + 192,
                      dinv + OFF1, dinv + OFF5, m_tt, m_tu, flag);
    }
}

// ---------------- layers 1-2 dual GEMM (h f16, packed weights) ----------------
__device__ __forceinline__ void gemm_mfma_dev(int t0, int tstride, int ntiles,
                                              const _Float16* __restrict__ h,
                                              const _Float16* __restrict__ WApk,
                                              const _Float16* __restrict__ WBpk,
                                              const float* __restrict__ scA,
                                              const float* __restrict__ scB,
                                              unsigned char* __restrict__ mA,
                                              unsigned char* __restrict__ mB) {
    const int lane = threadIdx.x & 63;
    const int rq = lane & 15;
    const int oct = lane >> 4;

    f16x8 bf[2][4][2];
#pragma unroll
    for (int m = 0; m < 2; ++m) {
        const _Float16* P = m ? WBpk : WApk;
#pragma unroll
        for (int ct = 0; ct < 4; ++ct)
#pragma unroll
            for (int s = 0; s < 2; ++s)
                bf[m][ct][s] = *(const f16x8*)(P + ((((ct << 1) + s) << 9) + (lane << 3)));
    }

    for (int t = t0; t < ntiles; t += tstride) {
        const int r0 = t << 4;
        const _Float16* hr = h + (size_t)(r0 + rq) * HD + 8 * oct;
        f16x8 a0 = *(const f16x8*)(hr);
        f16x8 a1 = *(const f16x8*)(hr + 32);

        f32x4 acc[2][4];
#pragma unroll
        for (int m = 0; m < 2; ++m)
#pragma unroll
            for (int ct = 0; ct < 4; ++ct) acc[m][ct] = (f32x4){0.f, 0.f, 0.f, 0.f};

#pragma unroll
        for (int m = 0; m < 2; ++m)
#pragma unroll
            for (int ct = 0; ct < 4; ++ct) {
                acc[m][ct] = __builtin_amdgcn_mfma_f32_16x16x32_f16(a0, bf[m][ct][0],
                                                                   acc[m][ct], 0, 0, 0);
                acc[m][ct] = __builtin_amdgcn_mfma_f32_16x16x32_f16(a1, bf[m][ct][1],
                                                                   acc[m][ct], 0, 0, 0);
            }

        const int rb = r0 + (oct << 2);
        float sa[4], sb[4];
#pragma unroll
        for (int g = 0; g < 4; ++g) { sa[g] = scA[rb + g]; sb[g] = scB[rb + g]; }
#pragma unroll
        for (int ct = 0; ct < 4; ++ct)
#pragma unroll
            for (int g = 0; g < 4; ++g) {
                mA[(size_t)(rb + g) * HD + 16 * ct + rq] = enc_fp8(acc[0][ct][g] * sa[g]);
                mB[(size_t)(rb + g) * HD + 16 * ct + rq] = enc_fp8(acc[1][ct][g] * sb[g]);
            }
    }
}

__global__ __launch_bounds__(256) void gemm_dual_both(
    const _Float16* __restrict__ hu, const _Float16* __restrict__ ht,
    const _Float16* __restrict__ W0, const _Float16* __restrict__ Wu2t,
    const _Float16* __restrict__ Wt, const _Float16* __restrict__ Wt2u,
    const float* __restrict__ dinv,
    unsigned char* __restrict__ m_uu, unsigned char* __restrict__ m_ut,
    unsigned char* __restrict__ m_tt, unsigned char* __restrict__ m_tu) {
    int b = blockIdx.x;
    int wid = threadIdx.x >> 6;
    if (b < GMU) {
        gemm_mfma_dev(b * 4 + wid, GMU * 4, NU_ / 16, hu, W0, Wu2t,
                      dinv + OFF0, dinv + OFF4, m_uu, m_ut);
    } else {
        gemm_mfma_dev((b - GMU) * 4 + wid, GMT * 4, NT_ / 16, ht, Wt, Wt2u,
                      dinv + OFF1, dinv + OFF5, m_tt, m_tu);
    }
}

// ---------------- gather: one dst per 8-lane group, 8-deep MLP, col prefetch ----------------
__device__ __forceinline__ void gather_dev(int blk, const unsigned char* __restrict__ msg,
                                           unsigned int offB,
                                           const int4* __restrict__ meta,
                                           const int* __restrict__ col,
                                           const float* __restrict__ ba,
                                           const float* __restrict__ bb,
                                           _Float16* __restrict__ out, int N) {
    const int lane = threadIdx.x & 63;
    const int grp = lane >> 3;
    const int sub = lane & 7;
    const int d = (blk << 5) + ((threadIdx.x >> 6) << 3) + grp;
    const bool valid = d < N;

    int4 mt = make_int4(0, 0, 0, 0);
    if (valid) mt = meta[d];
    const int st = mt.x;
    const int cnt = mt.y;
    const float dA = __int_as_float(mt.z);   // 0.5 * dinv folded in
    const float dB = __int_as_float(mt.w);
    const unsigned char* msgL = msg + (sub << 3);

    floatx2 acc[4];
#pragma unroll
    for (int q = 0; q < 4; ++q) acc[q] = (floatx2){0.f, 0.f};

    auto consume = [&](uint2 u, float s) {
        floatx2 s2; s2.x = s; s2.y = s;
#if __has_builtin(__builtin_amdgcn_cvt_pk_f32_fp8)
        acc[0] += __builtin_amdgcn_cvt_pk_f32_fp8((int)u.x, false) * s2;
        acc[1] += __builtin_amdgcn_cvt_pk_f32_fp8((int)u.x, true) * s2;
        acc[2] += __builtin_amdgcn_cvt_pk_f32_fp8((int)u.y, false) * s2;
        acc[3] += __builtin_amdgcn_cvt_pk_f32_fp8((int)u.y, true) * s2;
#else
        float f[8];
        dec4_fp8(u.x, f);
        dec4_fp8(u.y, f + 4);
        acc[0].x += f[0] * s; acc[0].y += f[1] * s;
        acc[1].x += f[2] * s; acc[1].y += f[3] * s;
        acc[2].x += f[4] * s; acc[2].y += f[5] * s;
        acc[3].x += f[6] * s; acc[3].y += f[7] * s;
#endif
    };

    if (valid) {
        uint2 uself = *(const uint2*)(msgL + ((unsigned int)d << 6));
        consume(uself, dA);
    }

    int cw = (sub < cnt) ? col[st + sub] : 0;
    int done = 0;
    while (done < cnt) {
        int rem = cnt - done;
        if (rem > 8) rem = 8;

        uint2 ub0, ub1, ub2, ub3, ub4, ub5, ub6, ub7;
        float sc0, sc1, sc2, sc3, sc4, sc5, sc6, sc7;

        auto issue = [&](int p, uint2& ub, float& sc) {
            int c = __shfl(cw, (grp << 3) + p);
            unsigned int off = ((unsigned int)c & 0x7fffffffu) + ((c < 0) ? offB : 0u);
            sc = (p < rem) ? ((c < 0) ? dB : dA) : 0.f;
            ub = *(const uint2*)(msgL + off);
        };

        issue(0, ub0, sc0);
        issue(1, ub1, sc1);
        issue(2, ub2, sc2);
        issue(3, ub3, sc3);
        issue(4, ub4, sc4);
        issue(5, ub5, sc5);
        issue(6, ub6, sc6);
        issue(7, ub7, sc7);

        int nd = done + 8;
        int cw2 = (nd + sub < cnt) ? col[st + nd + sub] : 0;

        consume(ub0, sc0);
        consume(ub1, sc1);
        consume(ub2, sc2);
        consume(ub3, sc3);
        consume(ub4, sc4);
        consume(ub5, sc5);
        consume(ub6, sc6);
        consume(ub7, sc7);

        cw = cw2;
        done = nd;
    }

    if (valid) {
        const int col0 = sub << 3;
        float4 a0 = *(const float4*)(ba + col0);
        float4 a1 = *(const float4*)(ba + col0 + 4);
        float4 c0 = *(const float4*)(bb + col0);
        float4 c1 = *(const float4*)(bb + col0 + 4);
        float af[8] = {acc[0].x, acc[0].y, acc[1].x, acc[1].y,
                       acc[2].x, acc[2].y, acc[3].x, acc[3].y};
        float bf[8] = {a0.x + c0.x, a0.y + c0.y, a0.z + c0.z, a0.w + c0.w,
                       a1.x + c1.x, a1.y + c1.y, a1.z + c1.z, a1.w + c1.w};
        f16x8 o;
#pragma unroll
        for (int k = 0; k < 8; ++k)
            o[k] = (_Float16)fmaxf(af[k] + 0.5f * bf[k], 0.f);
        *(f16x8*)(out + ((size_t)d << 6) + col0) = o;
    }
}

__global__ __launch_bounds__(256) void gather_both(
    const unsigned char* __restrict__ msgU, const unsigned char* __restrict__ msgT,
    const int4* __restrict__ meta,
    const int* __restrict__ colU, const int* __restrict__ colT,
    const float* __restrict__ bU0, const float* __restrict__ bU1,
    const float* __restrict__ bT0, const float* __restrict__ bT1,
    _Float16* __restrict__ hu, _Float16* __restrict__ ht) {
    int b = blockIdx.x;
    if (b < GBU) {
        gather_dev(b, msgU, (unsigned int)NU_ * HD, meta, colU, bU0, bU1, hu, NU_);
    } else {
        gather_dev(b - GBU, msgT, (unsigned int)NT_ * HD, meta + NU_, colT, bT0, bT1, ht, NT_);
    }
}

// ---------------- readout ----------------
__global__ __launch_bounds__(256) void colmean_both(const _Float16* __restrict__ hu,
                                                    const _Float16* __restrict__ ht,
                                                    float* __restrict__ gsum) {
    const bool isU = blockIdx.x < 512;
    const _Float16* h = isU ? hu : ht;
    const int n = isU ? NU_ : NT_;
    const float scale = isU ? 0.5f / NU_ : 0.5f / NT_;
    const int blk = isU ? blockIdx.x : blockIdx.x - 512;
    const int lane = threadIdx.x & 63;
    const int w = threadIdx.x >> 6;
    float s = 0.f;
    for (int r = blk * 4 + w; r < n; r += 512 * 4)
        s += (float)h[(size_t)r * HD + lane];
    __shared__ float red[256];
    red[threadIdx.x] = s;
    __syncthreads();
    if (threadIdx.x < 64) {
        float t = red[threadIdx.x] + red[64 + threadIdx.x] + red[128 + threadIdx.x] +
                  red[192 + threadIdx.x];
        atomicAdd(&gsum[lane], t * scale);
    }
}

__global__ void head(const float* __restrict__ g, const float* __restrict__ W1,
                     const float* __restrict__ b1, const float* __restrict__ W2,
                     const float* __restrict__ b2, const int* __restrict__ flag,
                     void* __restrict__ out) {
    const int c = threadIdx.x;
    float x = b1[c];
    for (int k = 0; k < HD; ++k) x = fmaf(g[k], W1[k * HD + c], x);
    x = fmaxf(x, 0.f);
    float t = x * W2[c];
    for (int off = 32; off; off >>= 1) t += __shfl_down(t, off);
    if (c == 0) {
        float z = t + b2[0];
        float s = 1.f / (1.f + expf(-z));
        if (flag[0]) *(__hip_bfloat16*)out = __float2bfloat16(s);
        else *(float*)out = s;
    }
}

extern "C" void kernel_launch(void* const* d_in, const int* in_sizes, int n_in,
                              void* d_out, int out_size, void* d_ws, size_t ws_size,
                              hipStream_t stream) {
    const void* x_user = d_in[0];
    const void* x_txn  = d_in[1];
    const int* ei_u2u = (const int*)d_in[2];
    const int* ei_t2t = (const int*)d_in[3];
    const int* ei_u2t = (const int*)d_in[4];
    const int* ei_t2u = (const int*)d_in[5];

    // ---- workspace layout ----
    float* ws = (float*)d_ws;
    _Float16* hu = (_Float16*)ws;                     // NU*64 f16 (first written by gather0)
    _Float16* ht = hu + (size_t)NU_ * HD;             // NT*64 f16
    float* dinv = (float*)(ht + (size_t)NT_ * HD);    // HTOT f32
    float* wts = dinv + HTOT;                         // 60432
    float* gsum = wts + 60432;                        // 64
    float* bcomp = gsum + 64;                         // 256 (composed layer-0 biases)
    _Float16* wpk = (_Float16*)(bcomp + 256);         // WPK_TOT f16
    unsigned char* m_uu = (unsigned char*)(wpk + WPK_TOT);  // NU rows fp8
    unsigned char* m_tu = m_uu + (size_t)NU_ * HD;      // NT rows
    unsigned char* m_tt = m_tu + (size_t)NT_ * HD;      // NT rows
    unsigned char* m_ut = m_tt + (size_t)NT_ * HD;      // NU rows
    int* aux  = (int*)(m_ut + (size_t)NU_ * HD);      // gcnt/gbase/bofs
    int* colU = aux + 2 * NBKT + PB1 * NBKT;          // 2M
    int* colT = colU + 2 * NE_;                       // 2M
    int4* meta = (int4*)(colT + 2 * NE_);             // RPT2 (16B each)
    int* dflag = (int*)(meta + RPT2);                 // 1

    int* gcnt  = aux;               // NBKT
    int* gbase = gcnt + NBKT;       // NBKT
    int* bofs  = gbase + NBKT;      // PB1*NBKT

    // partition payload aliases (all consumed by bucket_build, which runs
    // before gemm0 writes m_* and before gather0 writes hu)
    unsigned int* part_csr = (unsigned int*)m_uu;     // 4M u32 = 16 MB
    unsigned int* part_src = (unsigned int*)hu;       // 2M u32 = 8 MB

    // fp32 weight sub-pointers
    float* W1f = wts + 56192;        // 4096
    float* b1f = W1f + 4096;         // 64
    float* W2f = b1f + 64;           // 64
    float* b2f = W2f + 64;           // 1

    hipMemsetAsync(gcnt, 0, (size_t)NBKT * sizeof(int), stream);

    detect_dtype<<<1, 256, 0, stream>>>((const unsigned short*)x_user, dflag, 2048);
    {
        Ptr10 p;
        for (int k = 0; k < 10; ++k) p.p[k] = d_in[6 + k];
        cvt_weights<<<(60417 + 255) / 256, 256, 0, stream>>>(p, wts, gsum, dflag);
    }

    // p1 (edge bucket counts) + weight packing/composition, one launch
    fused_p1_pack<<<PB1 + PKB, 256, 0, stream>>>(ei_u2u, ei_t2t, ei_u2t, ei_t2u,
                                                 gcnt, bofs, wts, wpk, bcomp);

    p2_scatter<<<PB1, 256, 0, stream>>>(ei_u2u, ei_t2t, ei_u2t, ei_t2u,
                                        gcnt, gbase, bofs, part_csr, part_src);

    bucket_build<<<NBKT, 1024, 0, stream>>>(part_csr, part_src, gcnt, gbase,
                                            dinv, meta, colU, colT);

    for (int l = 0; l < NL; ++l) {
        const float* convbf = wts + 55424;
        const float* B0   = convbf + ((size_t)l * 4 + 0) * HD;
        const float* Bt   = convbf + ((size_t)l * 4 + 1) * HD;
        const float* Bu2t = convbf + ((size_t)l * 4 + 2) * HD;
        const float* Bt2u = convbf + ((size_t)l * 4 + 3) * HD;

        if (l == 0) {
            gemm0_both<<<GMU + GMT, 256, 0, stream>>>(x_user, x_txn, wpk, bcomp, dinv,
                                                      m_uu, m_ut, m_tt, m_tu, dflag);
        } else {
            const _Float16* W0   = wpk + WPK_CONV + ((size_t)l * 4 + 0) * 4096;
            const _Float16* Wt   = wpk + WPK_CONV + ((size_t)l * 4 + 1) * 4096;
            const _Float16* Wu2t = wpk + WPK_CONV + ((size_t)l * 4 + 2) * 4096;
            const _Float16* Wt2u = wpk + WPK_CONV + ((size_t)l * 4 + 3) * 4096;
            gemm_dual_both<<<GMU + GMT, 256, 0, stream>>>(hu, ht, W0, Wu2t, Wt, Wt2u, dinv,
                                                          m_uu, m_ut, m_tt, m_tu);
        }

        gather_both<<<GBU + GBT, 256, 0, stream>>>(m_uu, m_tt,
                                                   meta, colU, colT,
                                                   B0, Bt2u, Bt, Bu2t, hu, ht);
    }

    // ---- readout ----
    colmean_both<<<1024, 256, 0, stream>>>(hu, ht, gsum);
    head<<<1, 64, 0, stream>>>(gsum, W1f, b1f, W2f, b2f, dflag, d_out);
}

// Round 11
// 552.840 us; speedup vs baseline: 3.4624x; 1.0536x over previous
//
#include <hip/hip_runtime.h>
#include <hip/hip_bf16.h>
#include <hip/hip_fp8.h>

#define NU_ 100000
#define NT_ 200000
#define NE_ 1000000
#define HD  64
#define NL  3

// dinv region offsets (node-keyed)
#define OFF0 0                   // u2u dst (NU)  [selfloop]
#define OFF1 (NU_)               // t2t dst (NT)  [selfloop]
#define OFF4 (2 * NU_ + 2 * NT_) // u2t src (NU)
#define OFF5 (3 * NU_ + 2 * NT_) // t2u src (NT)
#define HTOT (3 * NU_ + 3 * NT_) // 900k
#define RPT2 (NU_ + NT_)         // merged node count (300k)

// bucket partition (no-far-atomic CSR build)
#define PB1  512
#define BKP  2048
#define NBKC 147
#define NBKS 147
#define NBKT (NBKC + NBKS)

// packed-weight layout (f16 fragments, 512 f16 per fragment)
#define WPK_EMBU 0
#define WPK_EMBT 2048
#define WPK_CONV 6144      // 12 mats x 8 frags x 512
#define WPK_G0U  55296     // composed layer-0 user: 2 mats x 4 frags x 512
#define WPK_G0T  59392     // composed layer-0 txn: 2 mats x 8 frags x 512
#define WPK_TOT  67584
#define PK_ELEMS (WPK_TOT + 256)
#define PKB      ((PK_ELEMS + 255) / 256)

// grids
#define GMU 512
#define GMT 1024
#define GBU 3125           // NU/32 gather blocks (32 dsts per block)
#define GBT 6250           // NT/32

typedef float floatx2 __attribute__((ext_vector_type(2)));
typedef _Float16 f16x8 __attribute__((ext_vector_type(8)));
typedef float f32x4 __attribute__((ext_vector_type(4)));
typedef unsigned short u16x8 __attribute__((ext_vector_type(8)));

// ---------------- fp8 helpers ----------------
__device__ __forceinline__ unsigned char enc_fp8(float v) {
    return (unsigned char)__hip_cvt_float_to_fp8(v, __HIP_SATFINITE, __HIP_E4M3);
}

__device__ __forceinline__ float dec1_fp8(unsigned int u) {
    int e = (u >> 3) & 15;
    int m = u & 7;
    int mant = m | (e ? 8 : 0);
    if (u & 0x80) mant = -mant;
    int ex = (e ? e : 1) - 10;
    return (float)mant * __uint_as_float((unsigned int)(ex + 127) << 23);
}

__device__ __forceinline__ void dec4_fp8(unsigned int u, float* f) {
#if __has_builtin(__builtin_amdgcn_cvt_pk_f32_fp8)
    floatx2 lo = __builtin_amdgcn_cvt_pk_f32_fp8((int)u, false);
    floatx2 hi = __builtin_amdgcn_cvt_pk_f32_fp8((int)u, true);
    f[0] = lo.x; f[1] = lo.y; f[2] = hi.x; f[3] = hi.y;
#else
    f[0] = dec1_fp8(u & 0xff);
    f[1] = dec1_fp8((u >> 8) & 0xff);
    f[2] = dec1_fp8((u >> 16) & 0xff);
    f[3] = dec1_fp8((u >> 24) & 0xff);
#endif
}

// ---------------- dtype detection ----------------
__global__ void detect_dtype(const unsigned short* __restrict__ x, int* __restrict__ flag, int n) {
    __shared__ int s_big;
    if (threadIdx.x == 0) s_big = 0;
    __syncthreads();
    int big = 0;
    for (int i = threadIdx.x; i < n; i += blockDim.x) {
        float v = __uint_as_float(((unsigned int)x[i]) << 16);
        if (!(fabsf(v) < 1.0e4f)) big = 1;
    }
    if (big) atomicAdd(&s_big, 1);
    __syncthreads();
    if (threadIdx.x == 0) flag[0] = (s_big > 0) ? 0 : 1;
}

// ---------------- fused weight conversion (+ gsum/gcnt zero) ----------------
struct Ptr10 { const void* p[10]; };

__global__ void cvt_weights(Ptr10 src, float* __restrict__ dst, float* __restrict__ gsum,
                            int* __restrict__ gcnt, const int* __restrict__ flag) {
    const int c[11] = {0, 2048, 2112, 6208, 6272, 55424, 56192, 60288, 60352, 60416, 60417};
    int i = blockIdx.x * blockDim.x + threadIdx.x;
    if (i < 64) gsum[i] = 0.f;
    if (i < NBKT) gcnt[i] = 0;
    if (i >= 60417) return;
    int r = 0;
#pragma unroll
    for (int k = 1; k < 10; ++k)
        if (i >= c[k]) r = k;
    int e = i - c[r];
    if (flag[0]) {
        unsigned short u = ((const unsigned short*)src.p[r])[e];
        dst[i] = __uint_as_float(((unsigned int)u) << 16);
    } else {
        dst[i] = ((const float*)src.p[r])[e];
    }
}

// ---------------- pack weights (frag layout) + compose layer-0 (We@Wc, be@Wc) ----------------
__device__ __forceinline__ void pack_dev(int gid, const float* __restrict__ wts,
                                         _Float16* __restrict__ wpk,
                                         float* __restrict__ bcomp) {
    if (gid >= PK_ELEMS) return;
    if (gid < WPK_G0U) {
        const float* W;
        int r, KS;
        if (gid < WPK_EMBT) { W = wts; r = gid; KS = 1; }
        else if (gid < WPK_CONV) { W = wts + 2112; r = gid - WPK_EMBT; KS = 2; }
        else {
            int mat = (gid - WPK_CONV) >> 12;
            W = wts + 6272 + mat * 4096;
            r = (gid - WPK_CONV) & 4095;
            KS = 2;
        }
        int j = r & 7;
        int lane = (r >> 3) & 63;
        int f = r >> 9;
        int ct = f / KS;
        int s = f - ct * KS;
        int k = 32 * s + 8 * (lane >> 4) + j;
        int n = 16 * ct + (lane & 15);
        wpk[gid] = (_Float16)W[k * 64 + n];
    } else if (gid < WPK_TOT) {
        const float* We;
        int matc, rr, KS;
        if (gid < WPK_G0T) {
            int r = gid - WPK_G0U;
            matc = (r >> 11) ? 2 : 0;
            rr = r & 2047;
            We = wts;
            KS = 1;
        } else {
            int r = gid - WPK_G0T;
            matc = (r >> 12) ? 3 : 1;
            rr = r & 4095;
            We = wts + 2112;
            KS = 2;
        }
        const float* Wc = wts + 6272 + matc * 4096;
        int j = rr & 7;
        int lane = (rr >> 3) & 63;
        int f = rr >> 9;
        int ct = f / KS;
        int s = f - ct * KS;
        int k = 32 * s + 8 * (lane >> 4) + j;
        int n = 16 * ct + (lane & 15);
        float acc = 0.f;
#pragma unroll
        for (int q = 0; q < 64; ++q)
            acc = fmaf(We[k * 64 + q], Wc[q * 64 + n], acc);
        wpk[gid] = (_Float16)acc;
    } else {
        int q = gid - WPK_TOT;
        int mat = q >> 6;
        int n = q & 63;
        const float* be = (mat == 0 || mat == 2) ? (wts + 2048) : (wts + 6208);
        const float* Wc = wts + 6272 + mat * 4096;
        float acc = 0.f;
#pragma unroll
        for (int k = 0; k < 64; ++k)
            acc = fmaf(be[k], Wc[k * 64 + n], acc);
        bcomp[q] = acc;
    }
}

// ---------------- partition pass 1: per-block bucket counts (LDS) ----------------
__device__ __forceinline__ void p1_dev(int bid, const int* __restrict__ eu2u,
                                       const int* __restrict__ et2t,
                                       const int* __restrict__ eu2t,
                                       const int* __restrict__ et2u,
                                       int* __restrict__ gcnt, int* __restrict__ bofs) {
    __shared__ int cnt[NBKT];
    for (int j = threadIdx.x; j < NBKT; j += 256) cnt[j] = 0;
    __syncthreads();
    for (int i = bid * 256 + threadIdx.x; i < 6 * NE_; i += PB1 * 256) {
        int b;
        if (i < 4 * NE_) {
            int m;
            if (i < NE_)          m = eu2u[i + NE_];
            else if (i < 2 * NE_) m = NU_ + et2t[i];
            else if (i < 3 * NE_) m = NU_ + eu2t[i - NE_];
            else                  m = et2u[i - 2 * NE_];
            b = m >> 11;
        } else {
            int m2 = (i < 5 * NE_) ? eu2t[i - 4 * NE_] : (NU_ + et2u[i - 5 * NE_]);
            b = NBKC + (m2 >> 11);
        }
        atomicAdd(&cnt[b], 1);
    }
    __syncthreads();
    for (int j = threadIdx.x; j < NBKT; j += 256) {
        bofs[bid * NBKT + j] = atomicAdd(&gcnt[j], cnt[j]);
    }
}

// fused: p1 + weight packing/composition (independent work)
__global__ __launch_bounds__(256) void fused_p1_pack(
    const int* __restrict__ eu2u, const int* __restrict__ et2t,
    const int* __restrict__ eu2t, const int* __restrict__ et2u,
    int* __restrict__ gcnt, int* __restrict__ bofs,
    const float* __restrict__ wts, _Float16* __restrict__ wpk, float* __restrict__ bcomp) {
    int b = blockIdx.x;
    if (b < PB1) {
        p1_dev(b, eu2u, et2t, eu2t, et2u, gcnt, bofs);
    } else {
        pack_dev((b - PB1) * 256 + threadIdx.x, wts, wpk, bcomp);
    }
}

// ---------------- partition pass 2: scatter ----------------
__global__ __launch_bounds__(256) void p2_scatter(
    const int* __restrict__ eu2u, const int* __restrict__ et2t,
    const int* __restrict__ eu2t, const int* __restrict__ et2u,
    const int* __restrict__ gcnt, int* __restrict__ gbase, const int* __restrict__ bofs,
    unsigned int* __restrict__ part_csr, unsigned int* __restrict__ part_src) {
    __shared__ int gb[NBKT];
    __shared__ int lofs[NBKT];
    const int t = threadIdx.x;
    for (int j = t; j < NBKT; j += 256) { lofs[j] = 0; gb[j] = gcnt[j]; }
    __syncthreads();
    if (t == 0) {
        int s = 0;
        for (int j = 0; j < NBKC; ++j) { int c = gb[j]; gb[j] = s; s += c; }
        s = 0;
        for (int j = NBKC; j < NBKT; ++j) { int c = gb[j]; gb[j] = s; s += c; }
    }
    __syncthreads();
    const int bid = blockIdx.x;
    if (bid == 0)
        for (int j = t; j < NBKT; j += 256) gbase[j] = gb[j];
    for (int i = bid * 256 + t; i < 6 * NE_; i += PB1 * 256) {
        if (i < 4 * NE_) {
            int m; unsigned int src, tag;
            if (i < NE_)          { m = eu2u[i + NE_];        src = (unsigned int)eu2u[i];           tag = 0u; }
            else if (i < 2 * NE_) { m = NU_ + et2t[i];        src = (unsigned int)et2t[i - NE_];     tag = 0u; }
            else if (i < 3 * NE_) { m = NU_ + eu2t[i - NE_];  src = (unsigned int)eu2t[i - 2 * NE_]; tag = 1u; }
            else                  { m = et2u[i - 2 * NE_];    src = (unsigned int)et2u[i - 3 * NE_]; tag = 1u; }
            int b = m >> 11;
            int l = atomicAdd(&lofs[b], 1);
            int pos = gb[b] + bofs[bid * NBKT + b] + l;
            part_csr[pos] = (src << 12) | (tag << 11) | (unsigned int)(m & (BKP - 1));
        } else {
            int m2 = (i < 5 * NE_) ? eu2t[i - 4 * NE_] : (NU_ + et2u[i - 5 * NE_]);
            int b = NBKC + (m2 >> 11);
            int l = atomicAdd(&lofs[b], 1);
            int pos = gb[b] + bofs[bid * NBKT + b] + l;
            part_src[pos] = (unsigned int)m2;
        }
    }
}

// ---------------- bucket_build: count + scan + meta/dinv + place (single pass) ----------------
__global__ __launch_bounds__(1024) void bucket_build(
    const unsigned int* __restrict__ part_csr, const unsigned int* __restrict__ part_src,
    const int* __restrict__ gcnt, const int* __restrict__ gbase,
    float* __restrict__ dinv, int4* __restrict__ meta,
    int* __restrict__ colU, int* __restrict__ colT) {
    const int b = blockIdx.x;
    const int t = threadIdx.x;
    if (b >= NBKC) {
        __shared__ int cS[BKP];
        const int n = gcnt[b];
        const int base = gbase[b];
        for (int j = t; j < BKP; j += 1024) cS[j] = 0;
        __syncthreads();
        for (int i = t; i < n; i += 1024)
            atomicAdd(&cS[(int)(part_src[base + i] & (BKP - 1))], 1);
        __syncthreads();
        const int m0 = (b - NBKC) << 11;
        for (int j = t; j < BKP; j += 1024) {
            int m2 = m0 + j;
            if (m2 < NU_ + NT_) {
                int o = (m2 < NU_) ? (OFF4 + m2) : (OFF5 + (m2 - NU_));
                int h = cS[j];
                dinv[o] = (h > 0) ? rsqrtf((float)h) : 0.f;
            }
        }
        return;
    }
    __shared__ int cA[BKP];
    __shared__ int cB[BKP];
    __shared__ int lp[BKP];
    __shared__ int s1[1024];
    const int n = gcnt[b];
    const int base = gbase[b];
    for (int j = t; j < BKP; j += 1024) { cA[j] = 0; cB[j] = 0; }
    __syncthreads();
    for (int i = t; i < n; i += 1024) {
        unsigned int it = part_csr[base + i];
        int l = (int)(it & (BKP - 1));
        if (it & 0x800u) atomicAdd(&cB[l], 1);
        else             atomicAdd(&cA[l], 1);
    }
    __syncthreads();
    const int j0 = t << 1, j1 = j0 + 1;
    const int a0 = cA[j0] + cB[j0];
    const int a1 = cA[j1] + cB[j1];
    const int ps = a0 + a1;
    s1[t] = ps;
    __syncthreads();
    for (int off = 1; off < 1024; off <<= 1) {
        int x = (t >= off) ? s1[t - off] : 0;
        __syncthreads();
        s1[t] += x;
        __syncthreads();
    }
    const int excl = s1[t] - ps;
    lp[j0] = excl;
    lp[j1] = excl + a0;
    __syncthreads();
    const int m0 = b << 11;
    const int gb0 = gbase[b];
    for (int j = t; j < BKP; j += 1024) {
        int m = m0 + j;
        if (m < NU_ + NT_) {
            int hA = cA[j], hB = cB[j];
            float dslf = rsqrtf((float)hA + 1.0f);
            int oA = (m < NU_) ? (OFF0 + m) : (OFF1 + (m - NU_));
            dinv[oA] = dslf;
            int4 mt;
            mt.x = gb0 + lp[j] - ((m >= NU_) ? 2 * NE_ : 0);
            mt.y = hA + hB;
            mt.z = __float_as_int(0.5f * dslf);
            mt.w = __float_as_int((hB > 0) ? 0.5f * rsqrtf((float)hB) : 0.f);
            meta[m] = mt;
        }
    }
    __syncthreads();
    for (int j = t; j < BKP; j += 1024) cA[j] = 0;
    __syncthreads();
    for (int i = t; i < n; i += 1024) {
        unsigned int it = part_csr[base + i];
        int mlow = (int)(it & (BKP - 1));
        int ofs = atomicAdd(&cA[mlow], 1);
        int g = gb0 + lp[mlow] + ofs;
        int colv = (int)(((it >> 12) << 6) | ((it & 0x800u) << 20));
        int m = m0 + mlow;
        if (m < NU_) colU[g] = colv;
        else         colT[g - 2 * NE_] = colv;
    }
}

// ---------------- layer-0 GEMM: msg = (X @ W' + b') * sc  (embed folded in) ----------------
template <int K>
__device__ __forceinline__ void gemm0_dev(int t0, int tstride, int ntiles,
                                          const void* __restrict__ x,
                                          const _Float16* __restrict__ WApk,
                                          const _Float16* __restrict__ WBpk,
                                          const float* __restrict__ bA,
                                          const float* __restrict__ bB,
                                          const float* __restrict__ scA,
                                          const float* __restrict__ scB,
                                          unsigned char* __restrict__ mA,
                                          unsigned char* __restrict__ mB,
                                          const int* __restrict__ flag) {
    constexpr int KS = K / 32;
    const int lane = threadIdx.x & 63;
    const int rq = lane & 15;
    const int oct = lane >> 4;

    f16x8 bf[2][4][KS];
#pragma unroll
    for (int m = 0; m < 2; ++m) {
        const _Float16* P = m ? WBpk : WApk;
#pragma unroll
        for (int ct = 0; ct < 4; ++ct)
#pragma unroll
            for (int s = 0; s < KS; ++s)
                bf[m][ct][s] = *(const f16x8*)(P + (((ct * KS + s) << 9) + (lane << 3)));
    }
    float bvA[4], bvB[4];
#pragma unroll
    for (int ct = 0; ct < 4; ++ct) { bvA[ct] = bA[16 * ct + rq]; bvB[ct] = bB[16 * ct + rq]; }

    const bool isb = flag[0] != 0;

    for (int t = t0; t < ntiles; t += tstride) {
        const int r0 = t << 4;
        f16x8 a[KS];
        if (isb) {
            const unsigned short* xr = (const unsigned short*)x + (size_t)(r0 + rq) * K + 8 * oct;
#pragma unroll
            for (int s = 0; s < KS; ++s) {
                u16x8 uv = *(const u16x8*)(xr + 32 * s);
                f16x8 v;
#pragma unroll
                for (int j = 0; j < 8; ++j)
                    v[j] = (_Float16)__uint_as_float(((unsigned int)uv[j]) << 16);
                a[s] = v;
            }
        } else {
            const float* xr = (const float*)x + (size_t)(r0 + rq) * K + 8 * oct;
#pragma unroll
            for (int s = 0; s < KS; ++s) {
                float4 x0 = *(const float4*)(xr + 32 * s);
                float4 x1 = *(const float4*)(xr + 32 * s + 4);
                f16x8 v;
                v[0] = (_Float16)x0.x; v[1] = (_Float16)x0.y;
                v[2] = (_Float16)x0.z; v[3] = (_Float16)x0.w;
                v[4] = (_Float16)x1.x; v[5] = (_Float16)x1.y;
                v[6] = (_Float16)x1.z; v[7] = (_Float16)x1.w;
                a[s] = v;
            }
        }

        f32x4 acc[2][4];
#pragma unroll
        for (int m = 0; m < 2; ++m)
#pragma unroll
            for (int ct = 0; ct < 4; ++ct) acc[m][ct] = (f32x4){0.f, 0.f, 0.f, 0.f};
#pragma unroll
        for (int m = 0; m < 2; ++m)
#pragma unroll
            for (int ct = 0; ct < 4; ++ct)
#pragma unroll
                for (int s = 0; s < KS; ++s)
                    acc[m][ct] = __builtin_amdgcn_mfma_f32_16x16x32_f16(a[s], bf[m][ct][s],
                                                                       acc[m][ct], 0, 0, 0);

        const int rb = r0 + (oct << 2);
        float sa[4], sb[4];
#pragma unroll
        for (int g = 0; g < 4; ++g) { sa[g] = scA[rb + g]; sb[g] = scB[rb + g]; }
#pragma unroll
        for (int ct = 0; ct < 4; ++ct)
#pragma unroll
            for (int g = 0; g < 4; ++g) {
                mA[(size_t)(rb + g) * HD + 16 * ct + rq] =
                    enc_fp8((acc[0][ct][g] + bvA[ct]) * sa[g]);
                mB[(size_t)(rb + g) * HD + 16 * ct + rq] =
                    enc_fp8((acc[1][ct][g] + bvB[ct]) * sb[g]);
            }
    }
}

__global__ __launch_bounds__(256) void gemm0_both(
    const void* __restrict__ x_user, const void* __restrict__ x_txn,
    const _Float16* __restrict__ wpk, const float* __restrict__ bcomp,
    const float* __restrict__ dinv,
    unsigned char* __restrict__ m_uu, unsigned char* __restrict__ m_ut,
    unsigned char* __restrict__ m_tt, unsigned char* __restrict__ m_tu,
    const int* __restrict__ flag) {
    int b = blockIdx.x;
    int wid = threadIdx.x >> 6;
    if (b < GMU) {
        gemm0_dev<32>(b * 4 + wid, GMU * 4, NU_ / 16, x_user,
                      wpk + WPK_G0U, wpk + WPK_G0U + 2048,
                      bcomp + 0, bcomp + 128,
                      dinv + OFF0, dinv + OFF4, m_uu, m_ut, flag);
    } else {
        gemm0_dev<64>((b - GMU) * 4 + wid, GMT * 4, NT_ / 16, x_txn,
                      wpk + WPK_G0T, wpk + WPK_G0T + 4096,
                      bcomp + 64, bcomp + 192,
                      dinv + OFF1, dinv + OFF5, m_tt, m_tu, flag);
    }
}

// ---------------- gather edge-accumulation phase (shared by plain & fused) ----------------
// Returns af[8] = relu(acc + 0.5*(ba+bb)) for the caller's dst/feature slice.
__device__ __forceinline__ void gather_phase(int d, bool valid,
                                             const unsigned char* __restrict__ msg,
                                             unsigned int offB,
                                             const int4* __restrict__ meta,
                                             const int* __restrict__ col,
                                             const float* __restrict__ ba,
                                             const float* __restrict__ bb,
                                             float* __restrict__ af) {
    const int lane = threadIdx.x & 63;
    const int grp = lane >> 3;
    const int sub = lane & 7;

    int4 mt = make_int4(0, 0, 0, 0);
    if (valid) mt = meta[d];
    const int st = mt.x;
    const int cnt = mt.y;
    const float dA = __int_as_float(mt.z);
    const float dB = __int_as_float(mt.w);
    const unsigned char* msgL = msg + (sub << 3);

    floatx2 acc[4];
#pragma unroll
    for (int q = 0; q < 4; ++q) acc[q] = (floatx2){0.f, 0.f};

    auto consume = [&](uint2 u, float s) {
        floatx2 s2; s2.x = s; s2.y = s;
#if __has_builtin(__builtin_amdgcn_cvt_pk_f32_fp8)
        acc[0] += __builtin_amdgcn_cvt_pk_f32_fp8((int)u.x, false) * s2;
        acc[1] += __builtin_amdgcn_cvt_pk_f32_fp8((int)u.x, true) * s2;
        acc[2] += __builtin_amdgcn_cvt_pk_f32_fp8((int)u.y, false) * s2;
        acc[3] += __builtin_amdgcn_cvt_pk_f32_fp8((int)u.y, true) * s2;
#else
        float f[8];
        dec4_fp8(u.x, f);
        dec4_fp8(u.y, f + 4);
        acc[0].x += f[0] * s; acc[0].y += f[1] * s;
        acc[1].x += f[2] * s; acc[1].y += f[3] * s;
        acc[2].x += f[4] * s; acc[2].y += f[5] * s;
        acc[3].x += f[6] * s; acc[3].y += f[7] * s;
#endif
    };

    if (valid) {
        uint2 uself = *(const uint2*)(msgL + ((unsigned int)d << 6));
        consume(uself, dA);
    }

    int cw = (sub < cnt) ? col[st + sub] : 0;
    int done = 0;
    while (done < cnt) {
        int rem = cnt - done;
        if (rem > 8) rem = 8;

        uint2 ub0, ub1, ub2, ub3, ub4, ub5, ub6, ub7;
        float sc0, sc1, sc2, sc3, sc4, sc5, sc6, sc7;

        auto issue = [&](int p, uint2& ub, float& sc) {
            int c = __shfl(cw, (grp << 3) + p);
            unsigned int off = ((unsigned int)c & 0x7fffffffu) + ((c < 0) ? offB : 0u);
            sc = (p < rem) ? ((c < 0) ? dB : dA) : 0.f;
            ub = *(const uint2*)(msgL + off);
        };

        issue(0, ub0, sc0);
        issue(1, ub1, sc1);
        issue(2, ub2, sc2);
        issue(3, ub3, sc3);
        issue(4, ub4, sc4);
        issue(5, ub5, sc5);
        issue(6, ub6, sc6);
        issue(7, ub7, sc7);

        int nd = done + 8;
        int cw2 = (nd + sub < cnt) ? col[st + nd + sub] : 0;

        consume(ub0, sc0);
        consume(ub1, sc1);
        consume(ub2, sc2);
        consume(ub3, sc3);
        consume(ub4, sc4);
        consume(ub5, sc5);
        consume(ub6, sc6);
        consume(ub7, sc7);

        cw = cw2;
        done = nd;
    }

    const int col0 = sub << 3;
    float4 a0 = *(const float4*)(ba + col0);
    float4 a1 = *(const float4*)(ba + col0 + 4);
    float4 c0 = *(const float4*)(bb + col0);
    float4 c1 = *(const float4*)(bb + col0 + 4);
    float av[8] = {acc[0].x, acc[0].y, acc[1].x, acc[1].y,
                   acc[2].x, acc[2].y, acc[3].x, acc[3].y};
    float bv[8] = {a0.x + c0.x, a0.y + c0.y, a0.z + c0.z, a0.w + c0.w,
                   a1.x + c1.x, a1.y + c1.y, a1.z + c1.z, a1.w + c1.w};
#pragma unroll
    for (int k = 0; k < 8; ++k)
        af[k] = fmaxf(av[k] + 0.5f * bv[k], 0.f);
}

// ---------------- plain gather (final layer): writes h f16 ----------------
__global__ __launch_bounds__(256) void gather_both(
    const unsigned char* __restrict__ msgU, const unsigned char* __restrict__ msgT,
    const int4* __restrict__ meta,
    const int* __restrict__ colU, const int* __restrict__ colT,
    const float* __restrict__ bU0, const float* __restrict__ bU1,
    const float* __restrict__ bT0, const float* __restrict__ bT1,
    _Float16* __restrict__ hu, _Float16* __restrict__ ht) {
    int b = blockIdx.x;
    const bool isU = b < GBU;
    const int blk = isU ? b : b - GBU;
    const int grp = (threadIdx.x & 63) >> 3;
    const int sub = threadIdx.x & 7;
    const int d = (blk << 5) + ((threadIdx.x >> 6) << 3) + grp;
    const int N = isU ? NU_ : NT_;
    float af[8];
    gather_phase(d, d < N,
                 isU ? msgU : msgT, (unsigned int)(isU ? NU_ : NT_) * HD,
                 isU ? meta : meta + NU_, isU ? colU : colT,
                 isU ? bU0 : bT0, isU ? bU1 : bT1, af);
    if (d < N) {
        _Float16* out = isU ? hu : ht;
        f16x8 o;
#pragma unroll
        for (int k = 0; k < 8; ++k) o[k] = (_Float16)af[k];
        *(f16x8*)(out + ((size_t)d << 6) + (sub << 3)) = o;
    }
}

// ---------------- fused gather + next-layer dual GEMM ----------------
// Block = 32 contiguous dsts. Phase1: gather -> LDS h tile. Phase2: waves 0-1 run
// the dual MFMA transform (verified fragment mapping) and emit next-layer fp8 msgs.
__global__ __launch_bounds__(256) void gather_gemm_both(
    const unsigned char* __restrict__ msgU, const unsigned char* __restrict__ msgT,
    const int4* __restrict__ meta,
    const int* __restrict__ colU, const int* __restrict__ colT,
    const float* __restrict__ bU0, const float* __restrict__ bU1,
    const float* __restrict__ bT0, const float* __restrict__ bT1,
    const _Float16* __restrict__ WUa, const _Float16* __restrict__ WUb,
    const _Float16* __restrict__ WTa, const _Float16* __restrict__ WTb,
    const float* __restrict__ dinv,
    unsigned char* __restrict__ o_uu, unsigned char* __restrict__ o_ut,
    unsigned char* __restrict__ o_tt, unsigned char* __restrict__ o_tu) {
    __shared__ _Float16 hs[32][64];
    int b = blockIdx.x;
    const bool isU = b < GBU;
    const int blk = isU ? b : b - GBU;
    const int lane = threadIdx.x & 63;
    const int grp = lane >> 3;
    const int sub = lane & 7;
    const int w = threadIdx.x >> 6;
    const int d = (blk << 5) + (w << 3) + grp;
    const int N = isU ? NU_ : NT_;

    float af[8];
    gather_phase(d, d < N,
                 isU ? msgU : msgT, (unsigned int)(isU ? NU_ : NT_) * HD,
                 isU ? meta : meta + NU_, isU ? colU : colT,
                 isU ? bU0 : bT0, isU ? bU1 : bT1, af);

    {
        const int ld = threadIdx.x >> 3;  // w*8+grp
        f16x8 o;
#pragma unroll
        for (int k = 0; k < 8; ++k) o[k] = (_Float16)af[k];
        *(f16x8*)(&hs[ld][sub << 3]) = o;
    }
    __syncthreads();

    if (w < 2) {
        const _Float16* Pa = isU ? WUa : WTa;
        const _Float16* Pb = isU ? WUb : WTb;
        unsigned char* mA = isU ? o_uu : o_tt;
        unsigned char* mB = isU ? o_ut : o_tu;
        const float* scA = dinv + (isU ? OFF0 : OFF1);
        const float* scB = dinv + (isU ? OFF4 : OFF5);
        const int rq = lane & 15;
        const int oct = lane >> 4;

        f16x8 bf[2][4][2];
#pragma unroll
        for (int m = 0; m < 2; ++m) {
            const _Float16* P = m ? Pb : Pa;
#pragma unroll
            for (int ct = 0; ct < 4; ++ct)
#pragma unroll
                for (int s = 0; s < 2; ++s)
                    bf[m][ct][s] = *(const f16x8*)(P + ((((ct << 1) + s) << 9) + (lane << 3)));
        }

        f16x8 a0 = *(const f16x8*)(&hs[16 * w + rq][8 * oct]);
        f16x8 a1 = *(const f16x8*)(&hs[16 * w + rq][32 + 8 * oct]);

        f32x4 acc[2][4];
#pragma unroll
        for (int m = 0; m < 2; ++m)
#pragma unroll
            for (int ct = 0; ct < 4; ++ct) acc[m][ct] = (f32x4){0.f, 0.f, 0.f, 0.f};
#pragma unroll
        for (int m = 0; m < 2; ++m)
#pragma unroll
            for (int ct = 0; ct < 4; ++ct) {
                acc[m][ct] = __builtin_amdgcn_mfma_f32_16x16x32_f16(a0, bf[m][ct][0],
                                                                   acc[m][ct], 0, 0, 0);
                acc[m][ct] = __builtin_amdgcn_mfma_f32_16x16x32_f16(a1, bf[m][ct][1],
                                                                   acc[m][ct], 0, 0, 0);
            }

        const int rb = (blk << 5) + 16 * w + (oct << 2);
        float sa[4], sb[4];
#pragma unroll
        for (int g = 0; g < 4; ++g) { sa[g] = scA[rb + g]; sb[g] = scB[rb + g]; }
#pragma unroll
        for (int ct = 0; ct < 4; ++ct)
#pragma unroll
            for (int g = 0; g < 4; ++g) {
                mA[(size_t)(rb + g) * HD + 16 * ct + rq] = enc_fp8(acc[0][ct][g] * sa[g]);
                mB[(size_t)(rb + g) * HD + 16 * ct + rq] = enc_fp8(acc[1][ct][g] * sb[g]);
            }
    }
}

// ---------------- readout ----------------
__global__ __launch_bounds__(256) void colmean_both(const _Float16* __restrict__ hu,
                                                    const _Float16* __restrict__ ht,
                                                    float* __restrict__ gsum) {
    const bool isU = blockIdx.x < 512;
    const _Float16* h = isU ? hu : ht;
    const int n = isU ? NU_ : NT_;
    const float scale = isU ? 0.5f / NU_ : 0.5f / NT_;
    const int blk = isU ? blockIdx.x : blockIdx.x - 512;
    const int lane = threadIdx.x & 63;
    const int w = threadIdx.x >> 6;
    float s = 0.f;
    for (int r = blk * 4 + w; r < n; r += 512 * 4)
        s += (float)h[(size_t)r * HD + lane];
    __shared__ float red[256];
    red[threadIdx.x] = s;
    __syncthreads();
    if (threadIdx.x < 64) {
        float t = red[threadIdx.x] + red[64 + threadIdx.x] + red[128 + threadIdx.x] +
                  red[192 + threadIdx.x];
        atomicAdd(&gsum[lane], t * scale);
    }
}

__global__ void head(const float* __restrict__ g, const float* __restrict__ W1,
                     const float* __restrict__ b1, const float* __restrict__ W2,
                     const float* __restrict__ b2, const int* __restrict__ flag,
                     void* __restrict__ out) {
    const int c = threadIdx.x;
    float x = b1[c];
    for (int k = 0; k < HD; ++k) x = fmaf(g[k], W1[k * HD + c], x);
    x = fmaxf(x, 0.f);
    float t = x * W2[c];
    for (int off = 32; off; off >>= 1) t += __shfl_down(t, off);
    if (c == 0) {
        float z = t + b2[0];
        float s = 1.f / (1.f + expf(-z));
        if (flag[0]) *(__hip_bfloat16*)out = __float2bfloat16(s);
        else *(float*)out = s;
    }
}

extern "C" void kernel_launch(void* const* d_in, const int* in_sizes, int n_in,
                              void* d_out, int out_size, void* d_ws, size_t ws_size,
                              hipStream_t stream) {
    const void* x_user = d_in[0];
    const void* x_txn  = d_in[1];
    const int* ei_u2u = (const int*)d_in[2];
    const int* ei_t2t = (const int*)d_in[3];
    const int* ei_u2t = (const int*)d_in[4];
    const int* ei_t2u = (const int*)d_in[5];

    // ---- workspace layout ----
    // Double-buffered fp8 message sets (fused gather reads one set, writes the other).
    float* ws = (float*)d_ws;
    _Float16* hu = (_Float16*)ws;                     // NU*64 f16 (written only by gather2)
    _Float16* ht = hu + (size_t)NU_ * HD;             // NT*64 f16
    float* dinv = (float*)(ht + (size_t)NT_ * HD);    // HTOT f32
    float* wts = dinv + HTOT;                         // 60432
    float* gsum = wts + 60432;                        // 64
    float* bcomp = gsum + 64;                         // 256
    _Float16* wpk = (_Float16*)(bcomp + 256);         // WPK_TOT f16
    unsigned char* msg0 = (unsigned char*)(wpk + WPK_TOT);  // set0: 600k rows fp8
    unsigned char* msg1 = msg0 + (size_t)(2 * NU_ + 2 * NT_) * HD;  // set1
    int* aux  = (int*)(msg1 + (size_t)(2 * NU_ + 2 * NT_) * HD);    // gcnt/gbase/bofs
    int* colU = aux + 2 * NBKT + PB1 * NBKT;          // 2M
    int* colT = colU + 2 * NE_;                       // 2M
    int4* meta = (int4*)(colT + 2 * NE_);             // RPT2
    int* dflag = (int*)(meta + RPT2);                 // 1

    int* gcnt  = aux;               // NBKT
    int* gbase = gcnt + NBKT;       // NBKT
    int* bofs  = gbase + NBKT;      // PB1*NBKT

    // msg sub-tables per set: m_uu | m_tu | m_tt | m_ut
    auto uu = [](unsigned char* s) { return s; };
    auto tu = [](unsigned char* s) { return s + (size_t)NU_ * HD; };
    auto tt = [](unsigned char* s) { return s + (size_t)(NU_ + NT_) * HD; };
    auto ut = [](unsigned char* s) { return s + (size_t)(NU_ + 2 * NT_) * HD; };

    // partition payload aliases (consumed by bucket_build before first writes)
    unsigned int* part_csr = (unsigned int*)msg1;     // 16 MB over set1
    unsigned int* part_src = (unsigned int*)hu;       // 8 MB over hu

    // fp32 weight sub-pointers
    float* W1f = wts + 56192;
    float* b1f = W1f + 4096;
    float* W2f = b1f + 64;
    float* b2f = W2f + 64;
    const float* convbf = wts + 55424;

    detect_dtype<<<1, 256, 0, stream>>>((const unsigned short*)x_user, dflag, 2048);
    {
        Ptr10 p;
        for (int k = 0; k < 10; ++k) p.p[k] = d_in[6 + k];
        cvt_weights<<<(60417 + 255) / 256, 256, 0, stream>>>(p, wts, gsum, gcnt, dflag);
    }

    fused_p1_pack<<<PB1 + PKB, 256, 0, stream>>>(ei_u2u, ei_t2t, ei_u2t, ei_t2u,
                                                 gcnt, bofs, wts, wpk, bcomp);

    p2_scatter<<<PB1, 256, 0, stream>>>(ei_u2u, ei_t2t, ei_u2t, ei_t2u,
                                        gcnt, gbase, bofs, part_csr, part_src);

    bucket_build<<<NBKT, 1024, 0, stream>>>(part_csr, part_src, gcnt, gbase,
                                            dinv, meta, colU, colT);

    // layer 0 gemm (embed folded): x -> msg set0
    gemm0_both<<<GMU + GMT, 256, 0, stream>>>(x_user, x_txn, wpk, bcomp, dinv,
                                              uu(msg0), ut(msg0), tt(msg0), tu(msg0), dflag);

    // fused gather(l) + gemm(l+1): set_in -> set_out (h never hits memory)
    for (int l = 0; l < 2; ++l) {
        unsigned char* in  = (l == 0) ? msg0 : msg1;
        unsigned char* out = (l == 0) ? msg1 : msg0;
        const float* B0   = convbf + ((size_t)l * 4 + 0) * HD;
        const float* Bt   = convbf + ((size_t)l * 4 + 1) * HD;
        const float* Bu2t = convbf + ((size_t)l * 4 + 2) * HD;
        const float* Bt2u = convbf + ((size_t)l * 4 + 3) * HD;
        const _Float16* W0n   = wpk + WPK_CONV + ((size_t)(l + 1) * 4 + 0) * 4096;
        const _Float16* Wtn   = wpk + WPK_CONV + ((size_t)(l + 1) * 4 + 1) * 4096;
        const _Float16* Wu2tn = wpk + WPK_CONV + ((size_t)(l + 1) * 4 + 2) * 4096;
        const _Float16* Wt2un = wpk + WPK_CONV + ((size_t)(l + 1) * 4 + 3) * 4096;

        gather_gemm_both<<<GBU + GBT, 256, 0, stream>>>(
            uu(in), tt(in), meta, colU, colT,
            B0, Bt2u, Bt, Bu2t,
            W0n, Wu2tn, Wtn, Wt2un, dinv,
            uu(out), ut(out), tt(out), tu(out));
    }

    // final layer: plain gather -> h (set0 holds layer-2 messages)
    {
        const float* B0   = convbf + (2 * 4 + 0) * HD;
        const float* Bt   = convbf + (2 * 4 + 1) * HD;
        const float* Bu2t = convbf + (2 * 4 + 2) * HD;
        const float* Bt2u = convbf + (2 * 4 + 3) * HD;
        gather_both<<<GBU + GBT, 256, 0, stream>>>(uu(msg0), tt(msg0),
                                                   meta, colU, colT,
                                                   B0, Bt2u, Bt, Bu2t, hu, ht);
    }

    // ---- readout ----
    colmean_both<<<1024, 256, 0, stream>>>(hu, ht, gsum);
    head<<<1, 64, 0, stream>>>(gsum, W1f, b1f, W2f, b2f, dflag, d_out);
}

// Round 12
// 552.266 us; speedup vs baseline: 3.4660x; 1.0010x over previous
//
#include <hip/hip_runtime.h>
#include <hip/hip_bf16.h>
#include <hip/hip_fp8.h>

#define NU_ 100000
#define NT_ 200000
#define NE_ 1000000
#define HD  64
#define NL  3

// dinv region offsets (node-keyed)
#define OFF0 0                   // u2u dst (NU)  [selfloop]
#define OFF1 (NU_)               // t2t dst (NT)  [selfloop]
#define OFF4 (2 * NU_ + 2 * NT_) // u2t src (NU)
#define OFF5 (3 * NU_ + 2 * NT_) // t2u src (NT)
#define HTOT (3 * NU_ + 3 * NT_) // 900k
#define RPT2 (NU_ + NT_)         // merged node count (300k)

// bucket partition (no-far-atomic CSR build)
#define PB1  512
#define BKP  2048
#define NBKC 147
#define NBKS 147
#define NBKT (NBKC + NBKS)

// packed-weight layout (f16 fragments, 512 f16 per fragment)
#define WPK_EMBU 0
#define WPK_EMBT 2048
#define WPK_CONV 6144      // 12 mats x 8 frags x 512
#define WPK_G0U  55296     // composed layer-0 user: 2 mats x 4 frags x 512
#define WPK_G0T  59392     // composed layer-0 txn: 2 mats x 8 frags x 512
#define WPK_TOT  67584
#define PK_ELEMS (WPK_TOT + 256)
#define PKB      ((PK_ELEMS + 255) / 256)

// grids
#define GMU 512
#define GMT 1024
#define GBU 3125           // NU/32 gather blocks (32 dsts per block)
#define GBT 6250           // NT/32

typedef float floatx2 __attribute__((ext_vector_type(2)));
typedef _Float16 f16x8 __attribute__((ext_vector_type(8)));
typedef float f32x4 __attribute__((ext_vector_type(4)));
typedef unsigned short u16x8 __attribute__((ext_vector_type(8)));

// ---------------- fp8 helpers ----------------
__device__ __forceinline__ unsigned char enc_fp8(float v) {
    return (unsigned char)__hip_cvt_float_to_fp8(v, __HIP_SATFINITE, __HIP_E4M3);
}

__device__ __forceinline__ float dec1_fp8(unsigned int u) {
    int e = (u >> 3) & 15;
    int m = u & 7;
    int mant = m | (e ? 8 : 0);
    if (u & 0x80) mant = -mant;
    int ex = (e ? e : 1) - 10;
    return (float)mant * __uint_as_float((unsigned int)(ex + 127) << 23);
}

__device__ __forceinline__ void dec4_fp8(unsigned int u, float* f) {
#if __has_builtin(__builtin_amdgcn_cvt_pk_f32_fp8)
    floatx2 lo = __builtin_amdgcn_cvt_pk_f32_fp8((int)u, false);
    floatx2 hi = __builtin_amdgcn_cvt_pk_f32_fp8((int)u, true);
    f[0] = lo.x; f[1] = lo.y; f[2] = hi.x; f[3] = hi.y;
#else
    f[0] = dec1_fp8(u & 0xff);
    f[1] = dec1_fp8((u >> 8) & 0xff);
    f[2] = dec1_fp8((u >> 16) & 0xff);
    f[3] = dec1_fp8((u >> 24) & 0xff);
#endif
}

// ---------------- dtype detection ----------------
__global__ void detect_dtype(const unsigned short* __restrict__ x, int* __restrict__ flag, int n) {
    __shared__ int s_big;
    if (threadIdx.x == 0) s_big = 0;
    __syncthreads();
    int big = 0;
    for (int i = threadIdx.x; i < n; i += blockDim.x) {
        float v = __uint_as_float(((unsigned int)x[i]) << 16);
        if (!(fabsf(v) < 1.0e4f)) big = 1;
    }
    if (big) atomicAdd(&s_big, 1);
    __syncthreads();
    if (threadIdx.x == 0) flag[0] = (s_big > 0) ? 0 : 1;
}

// ---------------- fused weight conversion (+ gsum/gcnt zero) ----------------
struct Ptr10 { const void* p[10]; };

__global__ void cvt_weights(Ptr10 src, float* __restrict__ dst, float* __restrict__ gsum,
                            int* __restrict__ gcnt, const int* __restrict__ flag) {
    const int c[11] = {0, 2048, 2112, 6208, 6272, 55424, 56192, 60288, 60352, 60416, 60417};
    int i = blockIdx.x * blockDim.x + threadIdx.x;
    if (i < 64) gsum[i] = 0.f;
    if (i < NBKT) gcnt[i] = 0;
    if (i >= 60417) return;
    int r = 0;
#pragma unroll
    for (int k = 1; k < 10; ++k)
        if (i >= c[k]) r = k;
    int e = i - c[r];
    if (flag[0]) {
        unsigned short u = ((const unsigned short*)src.p[r])[e];
        dst[i] = __uint_as_float(((unsigned int)u) << 16);
    } else {
        dst[i] = ((const float*)src.p[r])[e];
    }
}

// ---------------- pack weights (frag layout) + compose layer-0 (We@Wc, be@Wc) ----------------
__device__ __forceinline__ void pack_dev(int gid, const float* __restrict__ wts,
                                         _Float16* __restrict__ wpk,
                                         float* __restrict__ bcomp) {
    if (gid >= PK_ELEMS) return;
    if (gid < WPK_G0U) {
        const float* W;
        int r, KS;
        if (gid < WPK_EMBT) { W = wts; r = gid; KS = 1; }
        else if (gid < WPK_CONV) { W = wts + 2112; r = gid - WPK_EMBT; KS = 2; }
        else {
            int mat = (gid - WPK_CONV) >> 12;
            W = wts + 6272 + mat * 4096;
            r = (gid - WPK_CONV) & 4095;
            KS = 2;
        }
        int j = r & 7;
        int lane = (r >> 3) & 63;
        int f = r >> 9;
        int ct = f / KS;
        int s = f - ct * KS;
        int k = 32 * s + 8 * (lane >> 4) + j;
        int n = 16 * ct + (lane & 15);
        wpk[gid] = (_Float16)W[k * 64 + n];
    } else if (gid < WPK_TOT) {
        const float* We;
        int matc, rr, KS;
        if (gid < WPK_G0T) {
            int r = gid - WPK_G0U;
            matc = (r >> 11) ? 2 : 0;
            rr = r & 2047;
            We = wts;
            KS = 1;
        } else {
            int r = gid - WPK_G0T;
            matc = (r >> 12) ? 3 : 1;
            rr = r & 4095;
            We = wts + 2112;
            KS = 2;
        }
        const float* Wc = wts + 6272 + matc * 4096;
        int j = rr & 7;
        int lane = (rr >> 3) & 63;
        int f = rr >> 9;
        int ct = f / KS;
        int s = f - ct * KS;
        int k = 32 * s + 8 * (lane >> 4) + j;
        int n = 16 * ct + (lane & 15);
        float acc = 0.f;
#pragma unroll
        for (int q = 0; q < 64; ++q)
            acc = fmaf(We[k * 64 + q], Wc[q * 64 + n], acc);
        wpk[gid] = (_Float16)acc;
    } else {
        int q = gid - WPK_TOT;
        int mat = q >> 6;
        int n = q & 63;
        const float* be = (mat == 0 || mat == 2) ? (wts + 2048) : (wts + 6208);
        const float* Wc = wts + 6272 + mat * 4096;
        float acc = 0.f;
#pragma unroll
        for (int k = 0; k < 64; ++k)
            acc = fmaf(be[k], Wc[k * 64 + n], acc);
        bcomp[q] = acc;
    }
}

// ---------------- partition pass 1: per-block bucket counts (LDS) ----------------
__device__ __forceinline__ void p1_dev(int bid, const int* __restrict__ eu2u,
                                       const int* __restrict__ et2t,
                                       const int* __restrict__ eu2t,
                                       const int* __restrict__ et2u,
                                       int* __restrict__ gcnt, int* __restrict__ bofs) {
    __shared__ int cnt[NBKT];
    for (int j = threadIdx.x; j < NBKT; j += 256) cnt[j] = 0;
    __syncthreads();
    for (int i = bid * 256 + threadIdx.x; i < 6 * NE_; i += PB1 * 256) {
        int b;
        if (i < 4 * NE_) {
            int m;
            if (i < NE_)          m = eu2u[i + NE_];
            else if (i < 2 * NE_) m = NU_ + et2t[i];
            else if (i < 3 * NE_) m = NU_ + eu2t[i - NE_];
            else                  m = et2u[i - 2 * NE_];
            b = m >> 11;
        } else {
            int m2 = (i < 5 * NE_) ? eu2t[i - 4 * NE_] : (NU_ + et2u[i - 5 * NE_]);
            b = NBKC + (m2 >> 11);
        }
        atomicAdd(&cnt[b], 1);
    }
    __syncthreads();
    for (int j = threadIdx.x; j < NBKT; j += 256) {
        bofs[bid * NBKT + j] = atomicAdd(&gcnt[j], cnt[j]);
    }
}

// fused: p1 + weight packing/composition (independent work)
__global__ __launch_bounds__(256) void fused_p1_pack(
    const int* __restrict__ eu2u, const int* __restrict__ et2t,
    const int* __restrict__ eu2t, const int* __restrict__ et2u,
    int* __restrict__ gcnt, int* __restrict__ bofs,
    const float* __restrict__ wts, _Float16* __restrict__ wpk, float* __restrict__ bcomp) {
    int b = blockIdx.x;
    if (b < PB1) {
        p1_dev(b, eu2u, et2t, eu2t, et2u, gcnt, bofs);
    } else {
        pack_dev((b - PB1) * 256 + threadIdx.x, wts, wpk, bcomp);
    }
}

// ---------------- partition pass 2: scatter ----------------
__global__ __launch_bounds__(256) void p2_scatter(
    const int* __restrict__ eu2u, const int* __restrict__ et2t,
    const int* __restrict__ eu2t, const int* __restrict__ et2u,
    const int* __restrict__ gcnt, int* __restrict__ gbase, const int* __restrict__ bofs,
    unsigned int* __restrict__ part_csr, unsigned int* __restrict__ part_src) {
    __shared__ int gb[NBKT];
    __shared__ int lofs[NBKT];
    const int t = threadIdx.x;
    for (int j = t; j < NBKT; j += 256) { lofs[j] = 0; gb[j] = gcnt[j]; }
    __syncthreads();
    if (t == 0) {
        int s = 0;
        for (int j = 0; j < NBKC; ++j) { int c = gb[j]; gb[j] = s; s += c; }
        s = 0;
        for (int j = NBKC; j < NBKT; ++j) { int c = gb[j]; gb[j] = s; s += c; }
    }
    __syncthreads();
    const int bid = blockIdx.x;
    if (bid == 0)
        for (int j = t; j < NBKT; j += 256) gbase[j] = gb[j];
    for (int i = bid * 256 + t; i < 6 * NE_; i += PB1 * 256) {
        if (i < 4 * NE_) {
            int m; unsigned int src, tag;
            if (i < NE_)          { m = eu2u[i + NE_];        src = (unsigned int)eu2u[i];           tag = 0u; }
            else if (i < 2 * NE_) { m = NU_ + et2t[i];        src = (unsigned int)et2t[i - NE_];     tag = 0u; }
            else if (i < 3 * NE_) { m = NU_ + eu2t[i - NE_];  src = (unsigned int)eu2t[i - 2 * NE_]; tag = 1u; }
            else                  { m = et2u[i - 2 * NE_];    src = (unsigned int)et2u[i - 3 * NE_]; tag = 1u; }
            int b = m >> 11;
            int l = atomicAdd(&lofs[b], 1);
            int pos = gb[b] + bofs[bid * NBKT + b] + l;
            part_csr[pos] = (src << 12) | (tag << 11) | (unsigned int)(m & (BKP - 1));
        } else {
            int m2 = (i < 5 * NE_) ? eu2t[i - 4 * NE_] : (NU_ + et2u[i - 5 * NE_]);
            int b = NBKC + (m2 >> 11);
            int l = atomicAdd(&lofs[b], 1);
            int pos = gb[b] + bofs[bid * NBKT + b] + l;
            part_src[pos] = (unsigned int)m2;
        }
    }
}

// ---------------- bucket_build: count + scan + meta/dinv + place (single pass) ----------------
__global__ __launch_bounds__(1024) void bucket_build(
    const unsigned int* __restrict__ part_csr, const unsigned int* __restrict__ part_src,
    const int* __restrict__ gcnt, const int* __restrict__ gbase,
    float* __restrict__ dinv, int4* __restrict__ meta,
    int* __restrict__ colU, int* __restrict__ colT) {
    const int b = blockIdx.x;
    const int t = threadIdx.x;
    if (b >= NBKC) {
        __shared__ int cS[BKP];
        const int n = gcnt[b];
        const int base = gbase[b];
        for (int j = t; j < BKP; j += 1024) cS[j] = 0;
        __syncthreads();
        for (int i = t; i < n; i += 1024)
            atomicAdd(&cS[(int)(part_src[base + i] & (BKP - 1))], 1);
        __syncthreads();
        const int m0 = (b - NBKC) << 11;
        for (int j = t; j < BKP; j += 1024) {
            int m2 = m0 + j;
            if (m2 < NU_ + NT_) {
                int o = (m2 < NU_) ? (OFF4 + m2) : (OFF5 + (m2 - NU_));
                int h = cS[j];
                dinv[o] = (h > 0) ? rsqrtf((float)h) : 0.f;
            }
        }
        return;
    }
    __shared__ int cA[BKP];
    __shared__ int cB[BKP];
    __shared__ int lp[BKP];
    __shared__ int s1[1024];
    const int n = gcnt[b];
    const int base = gbase[b];
    for (int j = t; j < BKP; j += 1024) { cA[j] = 0; cB[j] = 0; }
    __syncthreads();
    for (int i = t; i < n; i += 1024) {
        unsigned int it = part_csr[base + i];
        int l = (int)(it & (BKP - 1));
        if (it & 0x800u) atomicAdd(&cB[l], 1);
        else             atomicAdd(&cA[l], 1);
    }
    __syncthreads();
    const int j0 = t << 1, j1 = j0 + 1;
    const int a0 = cA[j0] + cB[j0];
    const int a1 = cA[j1] + cB[j1];
    const int ps = a0 + a1;
    s1[t] = ps;
    __syncthreads();
    for (int off = 1; off < 1024; off <<= 1) {
        int x = (t >= off) ? s1[t - off] : 0;
        __syncthreads();
        s1[t] += x;
        __syncthreads();
    }
    const int excl = s1[t] - ps;
    lp[j0] = excl;
    lp[j1] = excl + a0;
    __syncthreads();
    const int m0 = b << 11;
    const int gb0 = gbase[b];
    for (int j = t; j < BKP; j += 1024) {
        int m = m0 + j;
        if (m < NU_ + NT_) {
            int hA = cA[j], hB = cB[j];
            float dslf = rsqrtf((float)hA + 1.0f);
            int oA = (m < NU_) ? (OFF0 + m) : (OFF1 + (m - NU_));
            dinv[oA] = dslf;
            int4 mt;
            mt.x = gb0 + lp[j] - ((m >= NU_) ? 2 * NE_ : 0);
            mt.y = hA + hB;
            mt.z = __float_as_int(0.5f * dslf);
            mt.w = __float_as_int((hB > 0) ? 0.5f * rsqrtf((float)hB) : 0.f);
            meta[m] = mt;
        }
    }
    __syncthreads();
    for (int j = t; j < BKP; j += 1024) cA[j] = 0;
    __syncthreads();
    for (int i = t; i < n; i += 1024) {
        unsigned int it = part_csr[base + i];
        int mlow = (int)(it & (BKP - 1));
        int ofs = atomicAdd(&cA[mlow], 1);
        int g = gb0 + lp[mlow] + ofs;
        int colv = (int)(((it >> 12) << 6) | ((it & 0x800u) << 20));
        int m = m0 + mlow;
        if (m < NU_) colU[g] = colv;
        else         colT[g - 2 * NE_] = colv;
    }
}

// ---------------- layer-0 GEMM: msg = (X @ W' + b') * sc  (embed folded in) ----------------
template <int K>
__device__ __forceinline__ void gemm0_dev(int t0, int tstride, int ntiles,
                                          const void* __restrict__ x,
                                          const _Float16* __restrict__ WApk,
                                          const _Float16* __restrict__ WBpk,
                                          const float* __restrict__ bA,
                                          const float* __restrict__ bB,
                                          const float* __restrict__ scA,
                                          const float* __restrict__ scB,
                                          unsigned char* __restrict__ mA,
                                          unsigned char* __restrict__ mB,
                                          const int* __restrict__ flag) {
    constexpr int KS = K / 32;
    const int lane = threadIdx.x & 63;
    const int rq = lane & 15;
    const int oct = lane >> 4;

    f16x8 bf[2][4][KS];
#pragma unroll
    for (int m = 0; m < 2; ++m) {
        const _Float16* P = m ? WBpk : WApk;
#pragma unroll
        for (int ct = 0; ct < 4; ++ct)
#pragma unroll
            for (int s = 0; s < KS; ++s)
                bf[m][ct][s] = *(const f16x8*)(P + (((ct * KS + s) << 9) + (lane << 3)));
    }
    float bvA[4], bvB[4];
#pragma unroll
    for (int ct = 0; ct < 4; ++ct) { bvA[ct] = bA[16 * ct + rq]; bvB[ct] = bB[16 * ct + rq]; }

    const bool isb = flag[0] != 0;

    for (int t = t0; t < ntiles; t += tstride) {
        const int r0 = t << 4;
        f16x8 a[KS];
        if (isb) {
            const unsigned short* xr = (const unsigned short*)x + (size_t)(r0 + rq) * K + 8 * oct;
#pragma unroll
            for (int s = 0; s < KS; ++s) {
                u16x8 uv = *(const u16x8*)(xr + 32 * s);
                f16x8 v;
#pragma unroll
                for (int j = 0; j < 8; ++j)
                    v[j] = (_Float16)__uint_as_float(((unsigned int)uv[j]) << 16);
                a[s] = v;
            }
        } else {
            const float* xr = (const float*)x + (size_t)(r0 + rq) * K + 8 * oct;
#pragma unroll
            for (int s = 0; s < KS; ++s) {
                float4 x0 = *(const float4*)(xr + 32 * s);
                float4 x1 = *(const float4*)(xr + 32 * s + 4);
                f16x8 v;
                v[0] = (_Float16)x0.x; v[1] = (_Float16)x0.y;
                v[2] = (_Float16)x0.z; v[3] = (_Float16)x0.w;
                v[4] = (_Float16)x1.x; v[5] = (_Float16)x1.y;
                v[6] = (_Float16)x1.z; v[7] = (_Float16)x1.w;
                a[s] = v;
            }
        }

        f32x4 acc[2][4];
#pragma unroll
        for (int m = 0; m < 2; ++m)
#pragma unroll
            for (int ct = 0; ct < 4; ++ct) acc[m][ct] = (f32x4){0.f, 0.f, 0.f, 0.f};
#pragma unroll
        for (int m = 0; m < 2; ++m)
#pragma unroll
            for (int ct = 0; ct < 4; ++ct)
#pragma unroll
                for (int s = 0; s < KS; ++s)
                    acc[m][ct] = __builtin_amdgcn_mfma_f32_16x16x32_f16(a[s], bf[m][ct][s],
                                                                       acc[m][ct], 0, 0, 0);

        const int rb = r0 + (oct << 2);
        float sa[4], sb[4];
#pragma unroll
        for (int g = 0; g < 4; ++g) { sa[g] = scA[rb + g]; sb[g] = scB[rb + g]; }
#pragma unroll
        for (int ct = 0; ct < 4; ++ct)
#pragma unroll
            for (int g = 0; g < 4; ++g) {
                mA[(size_t)(rb + g) * HD + 16 * ct + rq] =
                    enc_fp8((acc[0][ct][g] + bvA[ct]) * sa[g]);
                mB[(size_t)(rb + g) * HD + 16 * ct + rq] =
                    enc_fp8((acc[1][ct][g] + bvB[ct]) * sb[g]);
            }
    }
}

__global__ __launch_bounds__(256) void gemm0_both(
    const void* __restrict__ x_user, const void* __restrict__ x_txn,
    const _Float16* __restrict__ wpk, const float* __restrict__ bcomp,
    const float* __restrict__ dinv,
    unsigned char* __restrict__ m_uu, unsigned char* __restrict__ m_ut,
    unsigned char* __restrict__ m_tt, unsigned char* __restrict__ m_tu,
    const int* __restrict__ flag) {
    int b = blockIdx.x;
    int wid = threadIdx.x >> 6;
    if (b < GMU) {
        gemm0_dev<32>(b * 4 + wid, GMU * 4, NU_ / 16, x_user,
                      wpk + WPK_G0U, wpk + WPK_G0U + 2048,
                      bcomp + 0, bcomp + 128,
                      dinv + OFF0, dinv + OFF4, m_uu, m_ut, flag);
    } else {
        gemm0_dev<64>((b - GMU) * 4 + wid, GMT * 4, NT_ / 16, x_txn,
                      wpk + WPK_G0T, wpk + WPK_G0T + 4096,
                      bcomp + 64, bcomp + 192,
                      dinv + OFF1, dinv + OFF5, m_tt, m_tu, flag);
    }
}

// ---------------- gather edge-accumulation phase ----------------
__device__ __forceinline__ void gather_phase(int d, bool valid,
                                             const unsigned char* __restrict__ msg,
                                             unsigned int offB,
                                             const int4* __restrict__ meta,
                                             const int* __restrict__ col,
                                             const float* __restrict__ ba,
                                             const float* __restrict__ bb,
                                             float* __restrict__ af) {
    const int lane = threadIdx.x & 63;
    const int grp = lane >> 3;
    const int sub = lane & 7;

    int4 mt = make_int4(0, 0, 0, 0);
    if (valid) mt = meta[d];
    const int st = mt.x;
    const int cnt = mt.y;
    const float dA = __int_as_float(mt.z);
    const float dB = __int_as_float(mt.w);
    const unsigned char* msgL = msg + (sub << 3);

    floatx2 acc[4];
#pragma unroll
    for (int q = 0; q < 4; ++q) acc[q] = (floatx2){0.f, 0.f};

    auto consume = [&](uint2 u, float s) {
        floatx2 s2; s2.x = s; s2.y = s;
#if __has_builtin(__builtin_amdgcn_cvt_pk_f32_fp8)
        acc[0] += __builtin_amdgcn_cvt_pk_f32_fp8((int)u.x, false) * s2;
        acc[1] += __builtin_amdgcn_cvt_pk_f32_fp8((int)u.x, true) * s2;
        acc[2] += __builtin_amdgcn_cvt_pk_f32_fp8((int)u.y, false) * s2;
        acc[3] += __builtin_amdgcn_cvt_pk_f32_fp8((int)u.y, true) * s2;
#else
        float f[8];
        dec4_fp8(u.x, f);
        dec4_fp8(u.y, f + 4);
        acc[0].x += f[0] * s; acc[0].y += f[1] * s;
        acc[1].x += f[2] * s; acc[1].y += f[3] * s;
        acc[2].x += f[4] * s; acc[2].y += f[5] * s;
        acc[3].x += f[6] * s; acc[3].y += f[7] * s;
#endif
    };

    if (valid) {
        uint2 uself = *(const uint2*)(msgL + ((unsigned int)d << 6));
        consume(uself, dA);
    }

    int cw = (sub < cnt) ? col[st + sub] : 0;
    int done = 0;
    while (done < cnt) {
        int rem = cnt - done;
        if (rem > 8) rem = 8;

        uint2 ub0, ub1, ub2, ub3, ub4, ub5, ub6, ub7;
        float sc0, sc1, sc2, sc3, sc4, sc5, sc6, sc7;

        auto issue = [&](int p, uint2& ub, float& sc) {
            int c = __shfl(cw, (grp << 3) + p);
            unsigned int off = ((unsigned int)c & 0x7fffffffu) + ((c < 0) ? offB : 0u);
            sc = (p < rem) ? ((c < 0) ? dB : dA) : 0.f;
            ub = *(const uint2*)(msgL + off);
        };

        issue(0, ub0, sc0);
        issue(1, ub1, sc1);
        issue(2, ub2, sc2);
        issue(3, ub3, sc3);
        issue(4, ub4, sc4);
        issue(5, ub5, sc5);
        issue(6, ub6, sc6);
        issue(7, ub7, sc7);

        int nd = done + 8;
        int cw2 = (nd + sub < cnt) ? col[st + nd + sub] : 0;

        consume(ub0, sc0);
        consume(ub1, sc1);
        consume(ub2, sc2);
        consume(ub3, sc3);
        consume(ub4, sc4);
        consume(ub5, sc5);
        consume(ub6, sc6);
        consume(ub7, sc7);

        cw = cw2;
        done = nd;
    }

    const int col0 = sub << 3;
    float4 a0 = *(const float4*)(ba + col0);
    float4 a1 = *(const float4*)(ba + col0 + 4);
    float4 c0 = *(const float4*)(bb + col0);
    float4 c1 = *(const float4*)(bb + col0 + 4);
    float av[8] = {acc[0].x, acc[0].y, acc[1].x, acc[1].y,
                   acc[2].x, acc[2].y, acc[3].x, acc[3].y};
    float bv[8] = {a0.x + c0.x, a0.y + c0.y, a0.z + c0.z, a0.w + c0.w,
                   a1.x + c1.x, a1.y + c1.y, a1.z + c1.z, a1.w + c1.w};
#pragma unroll
    for (int k = 0; k < 8; ++k)
        af[k] = fmaxf(av[k] + 0.5f * bv[k], 0.f);
}

// ---------------- final gather + in-block column reduce -> partials ----------------
// Layer-2 h feeds ONLY the global column mean; never materialize h.
__global__ __launch_bounds__(256) void gather_red_both(
    const unsigned char* __restrict__ msgU, const unsigned char* __restrict__ msgT,
    const int4* __restrict__ meta,
    const int* __restrict__ colU, const int* __restrict__ colT,
    const float* __restrict__ bU0, const float* __restrict__ bU1,
    const float* __restrict__ bT0, const float* __restrict__ bT1,
    float* __restrict__ partU, float* __restrict__ partT) {
    __shared__ float hs[32][64];
    __shared__ float ps[4][64];
    int b = blockIdx.x;
    const bool isU = b < GBU;
    const int blk = isU ? b : b - GBU;
    const int grp = (threadIdx.x & 63) >> 3;
    const int sub = threadIdx.x & 7;
    const int w = threadIdx.x >> 6;
    const int d = (blk << 5) + (w << 3) + grp;
    const int N = isU ? NU_ : NT_;
    float af[8];
    gather_phase(d, d < N,
                 isU ? msgU : msgT, (unsigned int)(isU ? NU_ : NT_) * HD,
                 isU ? meta : meta + NU_, isU ? colU : colT,
                 isU ? bU0 : bT0, isU ? bU1 : bT1, af);
    {
        const int ld = threadIdx.x >> 3;
#pragma unroll
        for (int k = 0; k < 8; ++k) hs[ld][(sub << 3) + k] = (d < N) ? af[k] : 0.f;
    }
    __syncthreads();
    const int c = threadIdx.x & 63;
    const int r0 = w << 3;
    float s = 0.f;
#pragma unroll
    for (int r = 0; r < 8; ++r) s += hs[r0 + r][c];
    ps[w][c] = s;
    __syncthreads();
    if (threadIdx.x < 64) {
        float t = ps[0][c] + ps[1][c] + ps[2][c] + ps[3][c];
        (isU ? partU : partT)[(size_t)blk * 64 + c] = t;
    }
}

// ---------------- fused gather + next-layer dual GEMM (4-wave MFMA split) ----------------
__global__ __launch_bounds__(256) void gather_gemm_both(
    const unsigned char* __restrict__ msgU, const unsigned char* __restrict__ msgT,
    const int4* __restrict__ meta,
    const int* __restrict__ colU, const int* __restrict__ colT,
    const float* __restrict__ bU0, const float* __restrict__ bU1,
    const float* __restrict__ bT0, const float* __restrict__ bT1,
    const _Float16* __restrict__ WUa, const _Float16* __restrict__ WUb,
    const _Float16* __restrict__ WTa, const _Float16* __restrict__ WTb,
    const float* __restrict__ dinv,
    unsigned char* __restrict__ o_uu, unsigned char* __restrict__ o_ut,
    unsigned char* __restrict__ o_tt, unsigned char* __restrict__ o_tu) {
    __shared__ _Float16 hs[32][64];
    int b = blockIdx.x;
    const bool isU = b < GBU;
    const int blk = isU ? b : b - GBU;
    const int lane = threadIdx.x & 63;
    const int grp = lane >> 3;
    const int sub = lane & 7;
    const int w = threadIdx.x >> 6;
    const int d = (blk << 5) + (w << 3) + grp;
    const int N = isU ? NU_ : NT_;

    float af[8];
    gather_phase(d, d < N,
                 isU ? msgU : msgT, (unsigned int)(isU ? NU_ : NT_) * HD,
                 isU ? meta : meta + NU_, isU ? colU : colT,
                 isU ? bU0 : bT0, isU ? bU1 : bT1, af);

    {
        const int ld = threadIdx.x >> 3;
        f16x8 o;
#pragma unroll
        for (int k = 0; k < 8; ++k) o[k] = (_Float16)af[k];
        *(f16x8*)(&hs[ld][sub << 3]) = o;
    }
    __syncthreads();

    // wave w: row-half = w&1, matrix = w>>1 (8 MFMAs each, no idle waves)
    {
        const int half = w & 1;
        const int mi = w >> 1;
        const _Float16* P = mi ? (isU ? WUb : WTb) : (isU ? WUa : WTa);
        unsigned char* mOut = mi ? (isU ? o_ut : o_tu) : (isU ? o_uu : o_tt);
        const float* sc = dinv + (mi ? (isU ? OFF4 : OFF5) : (isU ? OFF0 : OFF1));
        const int rq = lane & 15;
        const int oct = lane >> 4;

        f16x8 bf[4][2];
#pragma unroll
        for (int ct = 0; ct < 4; ++ct)
#pragma unroll
            for (int s = 0; s < 2; ++s)
                bf[ct][s] = *(const f16x8*)(P + ((((ct << 1) + s) << 9) + (lane << 3)));

        f16x8 a0 = *(const f16x8*)(&hs[16 * half + rq][8 * oct]);
        f16x8 a1 = *(const f16x8*)(&hs[16 * half + rq][32 + 8 * oct]);

        f32x4 acc[4];
#pragma unroll
        for (int ct = 0; ct < 4; ++ct) acc[ct] = (f32x4){0.f, 0.f, 0.f, 0.f};
#pragma unroll
        for (int ct = 0; ct < 4; ++ct) {
            acc[ct] = __builtin_amdgcn_mfma_f32_16x16x32_f16(a0, bf[ct][0], acc[ct], 0, 0, 0);
            acc[ct] = __builtin_amdgcn_mfma_f32_16x16x32_f16(a1, bf[ct][1], acc[ct], 0, 0, 0);
        }

        const int rb = (blk << 5) + 16 * half + (oct << 2);
        float sv[4];
#pragma unroll
        for (int g = 0; g < 4; ++g) sv[g] = sc[rb + g];
#pragma unroll
        for (int ct = 0; ct < 4; ++ct)
#pragma unroll
            for (int g = 0; g < 4; ++g)
                mOut[(size_t)(rb + g) * HD + 16 * ct + rq] = enc_fp8(acc[ct][g] * sv[g]);
    }
}

// ---------------- readout: reduce per-block partials ----------------
__global__ __launch_bounds__(256) void colmean_small(const float* __restrict__ partU,
                                                     const float* __restrict__ partT,
                                                     float* __restrict__ gsum) {
    const bool isU = blockIdx.x < 8;
    const float* p = isU ? partU : partT;
    const int rows = isU ? GBU : GBT;
    const float scale = isU ? 0.5f / NU_ : 0.5f / NT_;
    const int blk = isU ? blockIdx.x : blockIdx.x - 8;
    const int lane = threadIdx.x & 63;
    const int wv = threadIdx.x >> 6;
    float s = 0.f;
    for (int r = blk * 4 + wv; r < rows; r += 32)
        s += p[(size_t)r * 64 + lane];
    __shared__ float red[256];
    red[threadIdx.x] = s;
    __syncthreads();
    if (threadIdx.x < 64) {
        float t = red[threadIdx.x] + red[64 + threadIdx.x] + red[128 + threadIdx.x] +
                  red[192 + threadIdx.x];
        atomicAdd(&gsum[lane], t * scale);
    }
}

__global__ void head(const float* __restrict__ g, const float* __restrict__ W1,
                     const float* __restrict__ b1, const float* __restrict__ W2,
                     const float* __restrict__ b2, const int* __restrict__ flag,
                     void* __restrict__ out) {
    const int c = threadIdx.x;
    float x = b1[c];
    for (int k = 0; k < HD; ++k) x = fmaf(g[k], W1[k * HD + c], x);
    x = fmaxf(x, 0.f);
    float t = x * W2[c];
    for (int off = 32; off; off >>= 1) t += __shfl_down(t, off);
    if (c == 0) {
        float z = t + b2[0];
        float s = 1.f / (1.f + expf(-z));
        if (flag[0]) *(__hip_bfloat16*)out = __float2bfloat16(s);
        else *(float*)out = s;
    }
}

extern "C" void kernel_launch(void* const* d_in, const int* in_sizes, int n_in,
                              void* d_out, int out_size, void* d_ws, size_t ws_size,
                              hipStream_t stream) {
    const void* x_user = d_in[0];
    const void* x_txn  = d_in[1];
    const int* ei_u2u = (const int*)d_in[2];
    const int* ei_t2t = (const int*)d_in[3];
    const int* ei_u2t = (const int*)d_in[4];
    const int* ei_t2u = (const int*)d_in[5];

    // ---- workspace layout ----
    float* ws = (float*)d_ws;
    // partials for final column-mean live in the old h region (also aliased by
    // part_src during the prologue; bucket_build consumes part_src first)
    float* partU = ws;                                // GBU*64 f32
    float* partT = partU + (size_t)GBU * 64;          // GBT*64 f32
    float* dinv = (float*)((_Float16*)ws + (size_t)RPT2 * HD);  // HTOT f32 (offset as before)
    float* wts = dinv + HTOT;                         // 60432
    float* gsum = wts + 60432;                        // 64
    float* bcomp = gsum + 64;                         // 256
    _Float16* wpk = (_Float16*)(bcomp + 256);         // WPK_TOT f16
    unsigned char* msg0 = (unsigned char*)(wpk + WPK_TOT);  // set0: 600k rows fp8
    unsigned char* msg1 = msg0 + (size_t)(2 * NU_ + 2 * NT_) * HD;  // set1
    int* aux  = (int*)(msg1 + (size_t)(2 * NU_ + 2 * NT_) * HD);    // gcnt/gbase/bofs
    int* colU = aux + 2 * NBKT + PB1 * NBKT;          // 2M
    int* colT = colU + 2 * NE_;                       // 2M
    int4* meta = (int4*)(colT + 2 * NE_);             // RPT2
    int* dflag = (int*)(meta + RPT2);                 // 1

    int* gcnt  = aux;               // NBKT
    int* gbase = gcnt + NBKT;       // NBKT
    int* bofs  = gbase + NBKT;      // PB1*NBKT

    // msg sub-tables per set: m_uu | m_tu | m_tt | m_ut
    auto uu = [](unsigned char* s) { return s; };
    auto tu = [](unsigned char* s) { return s + (size_t)NU_ * HD; };
    auto tt = [](unsigned char* s) { return s + (size_t)(NU_ + NT_) * HD; };
    auto ut = [](unsigned char* s) { return s + (size_t)(NU_ + 2 * NT_) * HD; };

    // partition payload aliases (consumed by bucket_build before first writes)
    unsigned int* part_csr = (unsigned int*)msg1;     // 16 MB over set1
    unsigned int* part_src = (unsigned int*)ws;       // 8 MB over partials region

    // fp32 weight sub-pointers
    float* W1f = wts + 56192;
    float* b1f = W1f + 4096;
    float* W2f = b1f + 64;
    float* b2f = W2f + 64;
    const float* convbf = wts + 55424;

    detect_dtype<<<1, 256, 0, stream>>>((const unsigned short*)x_user, dflag, 2048);
    {
        Ptr10 p;
        for (int k = 0; k < 10; ++k) p.p[k] = d_in[6 + k];
        cvt_weights<<<(60417 + 255) / 256, 256, 0, stream>>>(p, wts, gsum, gcnt, dflag);
    }

    fused_p1_pack<<<PB1 + PKB, 256, 0, stream>>>(ei_u2u, ei_t2t, ei_u2t, ei_t2u,
                                                 gcnt, bofs, wts, wpk, bcomp);

    p2_scatter<<<PB1, 256, 0, stream>>>(ei_u2u, ei_t2t, ei_u2t, ei_t2u,
                                        gcnt, gbase, bofs, part_csr, part_src);

    bucket_build<<<NBKT, 1024, 0, stream>>>(part_csr, part_src, gcnt, gbase,
                                            dinv, meta, colU, colT);

    // layer 0 gemm (embed folded): x -> msg set0
    gemm0_both<<<GMU + GMT, 256, 0, stream>>>(x_user, x_txn, wpk, bcomp, dinv,
                                              uu(msg0), ut(msg0), tt(msg0), tu(msg0), dflag);

    // fused gather(l) + gemm(l+1): set_in -> set_out (h never hits memory)
    for (int l = 0; l < 2; ++l) {
        unsigned char* in  = (l == 0) ? msg0 : msg1;
        unsigned char* out = (l == 0) ? msg1 : msg0;
        const float* B0   = convbf + ((size_t)l * 4 + 0) * HD;
        const float* Bt   = convbf + ((size_t)l * 4 + 1) * HD;
        const float* Bu2t = convbf + ((size_t)l * 4 + 2) * HD;
        const float* Bt2u = convbf + ((size_t)l * 4 + 3) * HD;
        const _Float16* W0n   = wpk + WPK_CONV + ((size_t)(l + 1) * 4 + 0) * 4096;
        const _Float16* Wtn   = wpk + WPK_CONV + ((size_t)(l + 1) * 4 + 1) * 4096;
        const _Float16* Wu2tn = wpk + WPK_CONV + ((size_t)(l + 1) * 4 + 2) * 4096;
        const _Float16* Wt2un = wpk + WPK_CONV + ((size_t)(l + 1) * 4 + 3) * 4096;

        gather_gemm_both<<<GBU + GBT, 256, 0, stream>>>(
            uu(in), tt(in), meta, colU, colT,
            B0, Bt2u, Bt, Bu2t,
            W0n, Wu2tn, Wtn, Wt2un, dinv,
            uu(out), ut(out), tt(out), tu(out));
    }

    // final layer: gather + in-block column reduce -> partials (h eliminated)
    {
        const float* B0   = convbf + (2 * 4 + 0) * HD;
        const float* Bt   = convbf + (2 * 4 + 1) * HD;
        const float* Bu2t = convbf + (2 * 4 + 2) * HD;
        const float* Bt2u = convbf + (2 * 4 + 3) * HD;
        gather_red_both<<<GBU + GBT, 256, 0, stream>>>(uu(msg0), tt(msg0),
                                                       meta, colU, colT,
                                                       B0, Bt2u, Bt, Bu2t, partU, partT);
    }

    // ---- readout ----
    colmean_small<<<16, 256, 0, stream>>>(partU, partT, gsum);
    head<<<1, 64, 0, stream>>>(gsum, W1f, b1f, W2f, b2f, dflag, d_out);
}